// Round 2
// baseline (273.919 us; speedup 1.0000x reference)
//
#include <hip/hip_runtime.h>
#include <cstdint>

#define NB 2
#define NSEQ 2048
#define CDIM 768
#define NH 12
#define HD 64
#define NTOK (NB*NSEQ)        // 4096
#define QKV_COLS (3*CDIM)     // 2304
#define NBLK ((NSEQ/64)*NH*NB) // 768 attn blocks

typedef short bf16x8 __attribute__((ext_vector_type(8)));
typedef short bf16x4 __attribute__((ext_vector_type(4)));
typedef float f32x4  __attribute__((ext_vector_type(4)));
typedef short short4v __attribute__((ext_vector_type(4)));
typedef unsigned int uint4v __attribute__((ext_vector_type(4)));

#define MFMA16(a,b,c) __builtin_amdgcn_mfma_f32_16x16x32_bf16(a,b,c,0,0,0)

__device__ __forceinline__ short f2b(float f) {
    uint32_t u = __builtin_bit_cast(uint32_t, f);
    u += 0x7fffu + ((u >> 16) & 1u);
    return (short)(u >> 16);
}
__device__ __forceinline__ float b2f(short s) {
    return __builtin_bit_cast(float, (uint32_t)((uint32_t)(unsigned short)s << 16));
}
__device__ __forceinline__ unsigned pack2(float a, float b) {
    unsigned ua = __builtin_bit_cast(unsigned, a) + 0x7fffu;
    unsigned ub = __builtin_bit_cast(unsigned, b) + 0x7fffu;
    return __builtin_amdgcn_perm(ub, ua, 0x07060302u);
}
__device__ __forceinline__ void gll16(const short* g, short* l) {
    __builtin_amdgcn_global_load_lds(
        (const __attribute__((address_space(1))) unsigned int*)g,
        (__attribute__((address_space(3))) unsigned int*)l, 16, 0, 0);
}

// ---------------------------------------------------------------------------
// Merged prep: x fp32->bf16 (blocks 0..3071), w_qkv transpose (..4799),
// w_proj transpose (..5375), mask int->bf16 (5376..5377).
// ---------------------------------------------------------------------------
__global__ __launch_bounds__(256) void prep_kernel(
    const float* __restrict__ x, const float* __restrict__ w_qkv,
    const float* __restrict__ w_proj, const int* __restrict__ mask,
    short* __restrict__ xb, short* __restrict__ wqt, short* __restrict__ wpt,
    short* __restrict__ maskb)
{
    __shared__ float tile[32][33];
    const int bid = blockIdx.x, t = threadIdx.x;
    if (bid < 3072) {
        int i = bid * 256 + t;
        float4 v = ((const float4*)x)[i];
        short4v o = { f2b(v.x), f2b(v.y), f2b(v.z), f2b(v.w) };
        ((short4v*)xb)[i] = o;
        return;
    }
    if (bid >= 5376) {
        int i = ((bid - 5376) << 11) + (t << 3);   // 2 blocks x 2048 values
        int4 a = *(const int4*)(mask + i);
        int4 c = *(const int4*)(mask + i + 4);
        short4v o0 = { f2b((float)a.x), f2b((float)a.y),
                       f2b((float)a.z), f2b((float)a.w) };
        short4v o1 = { f2b((float)c.x), f2b((float)c.y),
                       f2b((float)c.z), f2b((float)c.w) };
        *(short4v*)(maskb + i) = o0;
        *(short4v*)(maskb + i + 4) = o1;
        return;
    }
    const float* w; short* wt; int K, NC, n0, k0;
    if (bid < 3072 + 1728) {
        int r = bid - 3072;
        w = w_qkv; wt = wqt; K = CDIM; NC = QKV_COLS;
        n0 = (r % 72) * 32; k0 = (r / 72) * 32;
    } else {
        int r = bid - 4800;
        w = w_proj; wt = wpt; K = CDIM; NC = CDIM;
        n0 = (r % 24) * 32; k0 = (r / 24) * 32;
    }
    #pragma unroll
    for (int i = 0; i < 4; ++i) {
        int idx = t + i * 256; int r = idx >> 5, c = idx & 31;
        tile[r][c] = w[(size_t)(k0 + r) * NC + n0 + c];
    }
    __syncthreads();
    #pragma unroll
    for (int i = 0; i < 4; ++i) {
        int idx = t + i * 256; int r = idx >> 5, c = idx & 31;
        wt[(size_t)(n0 + r) * K + k0 + c] = f2b(tile[c][r]);
    }
}

// ---------------------------------------------------------------------------
// GEMM1 (m97-style). Epilogue: q is PRE-SCALED by 0.125 (softmax scale).
// ---------------------------------------------------------------------------
__global__ __launch_bounds__(256) void gemm_qkv(
    const short* __restrict__ A /*wqt[2304][768]*/,
    const short* __restrict__ B /*xb [4096][768]*/,
    short* __restrict__ qb, short* __restrict__ kb, short* __restrict__ vt)
{
    __shared__ short As[128 * 32];
    __shared__ short Bs[128 * 32];
    const int t = threadIdx.x;
    const int lane = t & 63, wid = t >> 6;
    const int quad = lane >> 4, l16 = lane & 15;
    const int wA = wid >> 1, wB = wid & 1;
    const int n0 = blockIdx.x * 128;
    const int m0 = blockIdx.y * 128;

    const int srow = wid * 16 + (lane >> 2), schunk = (lane & 3) * 8;
    const short* ag0 = A + (size_t)(n0 + srow) * CDIM + schunk;
    const short* ag1 = ag0 + (size_t)64 * CDIM;
    const short* bg0 = B + (size_t)(m0 + srow) * CDIM + schunk;
    const short* bg1 = bg0 + (size_t)64 * CDIM;
    short* asl0 = &As[(wid * 16) * 32];
    short* asl1 = &As[(wid * 16 + 64) * 32];
    short* bsl0 = &Bs[(wid * 16) * 32];
    short* bsl1 = &Bs[(wid * 16 + 64) * 32];

    f32x4 acc[4][4] = {};
    for (int k0 = 0; k0 < CDIM; k0 += 32) {
        __syncthreads();
        gll16(ag0 + k0, asl0);
        gll16(ag1 + k0, asl1);
        gll16(bg0 + k0, bsl0);
        gll16(bg1 + k0, bsl1);
        __syncthreads();
        bf16x8 af[4], bf[4];
        #pragma unroll
        for (int i = 0; i < 4; ++i)
            af[i] = *(const bf16x8*)&As[(wA*64 + i*16 + l16) * 32 + quad*8];
        #pragma unroll
        for (int j = 0; j < 4; ++j)
            bf[j] = *(const bf16x8*)&Bs[(wB*64 + j*16 + l16) * 32 + quad*8];
        #pragma unroll
        for (int i = 0; i < 4; ++i)
            #pragma unroll
            for (int j = 0; j < 4; ++j)
                acc[i][j] = MFMA16(af[i], bf[j], acc[i][j]);
    }

    const int colbase = n0 + wA * 64;
    const int s = colbase / CDIM;
    const int h = (colbase - s * CDIM) >> 6;
    const int b = m0 >> 11;
    const size_t bh = (size_t)(b * NH + h);
    const float qsc = (s == 0) ? 0.125f : 1.0f;   // fold softmax scale into q
    #pragma unroll
    for (int i = 0; i < 4; ++i) {
        const int d0 = i*16 + quad*4;
        #pragma unroll
        for (int j = 0; j < 4; ++j) {
            int tok = (m0 + wB*64 + j*16 + l16) & (NSEQ - 1);
            if (s < 2) {
                short* dst = (s == 0 ? qb : kb) + (bh * NSEQ + tok) * HD + d0;
                short4v o = { f2b(acc[i][j][0] * qsc), f2b(acc[i][j][1] * qsc),
                              f2b(acc[i][j][2] * qsc), f2b(acc[i][j][3] * qsc) };
                *(short4v*)dst = o;
            } else {
                short* dst = vt + (bh * HD + d0) * NSEQ + tok;
                #pragma unroll
                for (int r = 0; r < 4; ++r)
                    dst[(size_t)r * NSEQ] = f2b(acc[i][j][r]);
            }
        }
    }
}

// ---------------------------------------------------------------------------
// Flash attention v10: v8 structure (cooperative swizzled LDS staging, which
// IS the coalescing machine -- v9's direct-global fragment loads fractured
// into 16 L2 transactions/instr and regressed 1.8x) but LDS cut 64->52 KB so
// all 3 blocks/CU are co-resident (768 = 3x256, zero tail; v8 ran 2 rounds +
// half-empty tail at 2 blocks/CU):
//   - K double-buffered (2x16KB): needed at tile top.
//   - V single-buffered (16KB): staged at tile top, latency hides under
//     QK+exp; tile body split by a second barrier (QK/exp | sync | PV | sync).
//   - mask as bf16 in LDS (4KB), staged once -- no per-tile global loads.
// NOTE: needs ~128 VGPR/lane; launch_bounds(256,3) caps at ~168.
// ---------------------------------------------------------------------------
#define STAGE_K(KT, BUF) do {                                                    \
    short* kb_ = (BUF);                                                          \
    _Pragma("unroll")                                                            \
    for (int j = 0; j < 4; ++j)                                                  \
        gll16(kp + (size_t)((KT) + rK[j]) * HD + cK[j]*8,                        \
              kb_ + wid*2048 + j*512);                                           \
} while (0)

#define STAGE_V(KT) do {                                                         \
    _Pragma("unroll")                                                            \
    for (int j = 0; j < 4; ++j)                                                  \
        gll16(vp + (size_t)dV[j] * NSEQ + (KT) + cV[j]*8,                        \
              Vb + wid*2048 + j*512);                                            \
} while (0)

#define QKBODY(KT, KBUF) do {                                                    \
    const short* KsB_ = (KBUF);                                                  \
    short4v mi0_ = *(const short4v*)&Msk[(KT) + mbase];                          \
    short4v mi1_ = *(const short4v*)&Msk[(KT) + 64 + mbase];                     \
    bf16x8 kf00_ = *(const bf16x8*)&KsB_[krow + kc0];                            \
    bf16x8 kf01_ = *(const bf16x8*)&KsB_[krow + kc1];                            \
    bf16x8 kf10_ = *(const bf16x8*)&KsB_[4096 + krow + kc0];                     \
    bf16x8 kf11_ = *(const bf16x8*)&KsB_[4096 + krow + kc1];                     \
    f32x4 s0_[4] = {}, s1_[4] = {};                                              \
    _Pragma("unroll")                                                            \
    for (int jt = 0; jt < 4; ++jt) {                                             \
        s0_[jt] = MFMA16(kf00_, qf[jt][0], s0_[jt]);                             \
        s0_[jt] = MFMA16(kf01_, qf[jt][1], s0_[jt]);                             \
        s1_[jt] = MFMA16(kf10_, qf[jt][0], s1_[jt]);                             \
        s1_[jt] = MFMA16(kf11_, qf[jt][1], s1_[jt]);                             \
    }                                                                            \
    float4 m0_ = { b2f(mi0_[0]), b2f(mi0_[1]), b2f(mi0_[2]), b2f(mi0_[3]) };     \
    float4 m1_ = { b2f(mi1_[0]), b2f(mi1_[1]), b2f(mi1_[2]), b2f(mi1_[3]) };     \
    _Pragma("unroll")                                                            \
    for (int jt = 0; jt < 4; ++jt) {                                             \
        float e0 = __expf(s0_[jt][0]) * m0_.x;                                   \
        float e1 = __expf(s0_[jt][1]) * m0_.y;                                   \
        float e2 = __expf(s0_[jt][2]) * m0_.z;                                   \
        float e3 = __expf(s0_[jt][3]) * m0_.w;                                   \
        float f0 = __expf(s1_[jt][0]) * m1_.x;                                   \
        float f1 = __expf(s1_[jt][1]) * m1_.y;                                   \
        float f2 = __expf(s1_[jt][2]) * m1_.z;                                   \
        float f3 = __expf(s1_[jt][3]) * m1_.w;                                   \
        l[jt] += ((e0 + e1) + (e2 + e3)) + ((f0 + f1) + (f2 + f3));              \
        uint4v pk_ = { pack2(e0, e1), pack2(e2, e3),                             \
                       pack2(f0, f1), pack2(f2, f3) };                           \
        pb[jt] = __builtin_bit_cast(bf16x8, pk_);                                \
    }                                                                            \
} while (0)

#define PVBODY() do {                                                            \
    _Pragma("unroll")                                                            \
    for (int it = 0; it < 4; ++it) {                                             \
        const int vrow_ = (it*16 + l16) * 128;                                   \
        bf16x4 lo_ = *(const bf16x4*)&Vb[vrow_ + vposl + vsub];                  \
        bf16x4 hi_ = *(const bf16x4*)&Vb[vrow_ + vposh + vsub];                  \
        bf16x8 vf_ = __builtin_shufflevector(lo_, hi_, 0,1,2,3,4,5,6,7);         \
        _Pragma("unroll")                                                        \
        for (int jt = 0; jt < 4; ++jt)                                           \
            o_acc[it][jt] = MFMA16(vf_, pb[jt], o_acc[it][jt]);                  \
    }                                                                            \
} while (0)

__global__ __launch_bounds__(256, 3) void attn_kernel(
    const short* __restrict__ qb, const short* __restrict__ kb,
    const short* __restrict__ vt, const short* __restrict__ maskb,
    short* __restrict__ ao)
{
    __shared__ __align__(16) short Kb[2][8192];   // K tiles [128][64], dbuf
    __shared__ __align__(16) short Vb[8192];      // V tile  [64][128], single
    __shared__ __align__(16) short Msk[2048];     // bf16 mask row, this b
    float (*Ob)[68] = (float(*)[68])Kb;           // epilogue alias (18.4<32KB)
    float (*lsum)[64] = (float(*)[64])((char*)Kb + 17408);

    const int t = threadIdx.x;
    const int lane = t & 63, wid = t >> 6;
    const int quad = lane >> 4, l16 = lane & 15;
    // XCD swizzle: XCD = id%8 owns bh in {xcd, xcd+8, xcd+16}
    const int id = blockIdx.x;
    const int idx = id >> 3;
    const int bh = (id & 7) + ((idx % 3) << 3);
    const int q0 = (idx / 3) << 6;
    const int b = bh / NH, h = bh - b * NH;
    const size_t hoff = (size_t)bh * NSEQ * HD;
    const short* qp = qb + hoff;     // [N][64]  (q pre-scaled by 0.125)
    const short* kp = kb + hoff;     // [N][64]
    const short* vp = vt + hoff;     // [64][N]
    const int mbase = wid * 16 + quad * 4;

    int rK[4], cK[4], dV[4], cV[4];
    #pragma unroll
    for (int j = 0; j < 4; ++j) {
        int o = wid * 4096 + j * 1024 + lane * 16;
        rK[j] = o >> 7;
        cK[j] = ((o >> 4) & 7) ^ (rK[j] & 7);
        dV[j] = o >> 8;
        cV[j] = ((o >> 4) & 15) ^ (dV[j] & 15);
    }
    const int r7 = l16 & 7;
    const int krow = (wid * 16 + l16) * 64;
    const int kc0 = ((quad     ^ r7) << 3);
    const int kc1 = (((quad+4) ^ r7) << 3);
    const int vposl = ((wid*2 + (quad >> 1)) ^ l16) << 3;
    const int vposh = (((8 + wid*2 + (quad >> 1)) ^ l16) << 3);
    const int vsub = (quad & 1) * 4;

    bf16x8 qf[4][2];
    #pragma unroll
    for (int jt = 0; jt < 4; ++jt) {
        const short* qr = qp + (size_t)(q0 + jt*16 + l16) * HD + quad*8;
        qf[jt][0] = *(const bf16x8*)qr;
        qf[jt][1] = *(const bf16x8*)(qr + 32);
    }

    f32x4 o_acc[4][4] = {};
    float l[4] = {0.f, 0.f, 0.f, 0.f};
    bf16x8 pb[4];

    // Prologue: K tile 0 + mask row, one barrier.
    STAGE_K(0, Kb[0]);
    gll16(maskb + b * NSEQ + t * 8, Msk + wid * 512);
    __syncthreads();

    for (int kt = 0; kt < NSEQ; kt += 256) {
        STAGE_V(kt);
        STAGE_K(kt + 128, Kb[1]);
        QKBODY(kt, Kb[0]);
        __syncthreads();          // V(kt) staged + all QK reads of Kb[0] done
        PVBODY();
        __syncthreads();          // PV reads of Vb done -> safe to overwrite

        STAGE_V(kt + 128);
        STAGE_K((kt + 256) & (NSEQ - 1), Kb[0]);
        QKBODY(kt + 128, Kb[1]);
        __syncthreads();
        PVBODY();
        __syncthreads();
    }

    #pragma unroll
    for (int jt = 0; jt < 4; ++jt) {
        l[jt] += __shfl_xor(l[jt], 16);
        l[jt] += __shfl_xor(l[jt], 32);
        if (quad == 0) lsum[wid][jt*16 + l16] = l[jt];
    }
    for (int w = 0; w < 4; ++w) {
        __syncthreads();
        if (wid == w) {
            #pragma unroll
            for (int it = 0; it < 4; ++it)
                #pragma unroll
                for (int jt = 0; jt < 4; ++jt)
                    #pragma unroll
                    for (int r = 0; r < 4; ++r) {
                        if (w == 0)
                            Ob[it*16 + quad*4 + r][jt*16 + l16] = o_acc[it][jt][r];
                        else
                            Ob[it*16 + quad*4 + r][jt*16 + l16] += o_acc[it][jt][r];
                    }
        }
    }
    __syncthreads();

    {
        const int ql = t >> 2, dc = (t & 3) * 16;
        float inv = 1.0f / (((lsum[0][ql] + lsum[1][ql]) +
                             (lsum[2][ql] + lsum[3][ql])));
        bf16x8 o8a, o8b;
        #pragma unroll
        for (int d = 0; d < 8; ++d) o8a[d] = f2b(Ob[dc + d][ql] * inv);
        #pragma unroll
        for (int d = 0; d < 8; ++d) o8b[d] = f2b(Ob[dc + 8 + d][ql] * inv);
        int tok = b * NSEQ + q0 + ql;
        short* dst = ao + (size_t)tok * CDIM + h * HD + dc;
        *(bf16x8*)dst = o8a;
        *(bf16x8*)(dst + 8) = o8b;
    }
}

// ---------------------------------------------------------------------------
// GEMM2 (m97-style, round-8 verbatim)
// ---------------------------------------------------------------------------
__global__ __launch_bounds__(256) void gemm_proj(
    const short* __restrict__ A /*wpt[768][768]*/,
    const short* __restrict__ B /*ao [4096][768]*/,
    const float* __restrict__ bias, float* __restrict__ out)
{
    __shared__ short As[128 * 32];
    __shared__ short Bs[128 * 32];
    const int t = threadIdx.x;
    const int lane = t & 63, wid = t >> 6;
    const int quad = lane >> 4, l16 = lane & 15;
    const int wA = wid >> 1, wB = wid & 1;
    const int n0 = blockIdx.x * 128;
    const int m0 = blockIdx.y * 128;

    const int srow = wid * 16 + (lane >> 2), schunk = (lane & 3) * 8;
    const short* ag0 = A + (size_t)(n0 + srow) * CDIM + schunk;
    const short* ag1 = ag0 + (size_t)64 * CDIM;
    const short* bg0 = B + (size_t)(m0 + srow) * CDIM + schunk;
    const short* bg1 = bg0 + (size_t)64 * CDIM;
    short* asl0 = &As[(wid * 16) * 32];
    short* asl1 = &As[(wid * 16 + 64) * 32];
    short* bsl0 = &Bs[(wid * 16) * 32];
    short* bsl1 = &Bs[(wid * 16 + 64) * 32];

    f32x4 acc[4][4] = {};
    for (int k0 = 0; k0 < CDIM; k0 += 32) {
        __syncthreads();
        gll16(ag0 + k0, asl0);
        gll16(ag1 + k0, asl1);
        gll16(bg0 + k0, bsl0);
        gll16(bg1 + k0, bsl1);
        __syncthreads();
        bf16x8 af[4], bf[4];
        #pragma unroll
        for (int i = 0; i < 4; ++i)
            af[i] = *(const bf16x8*)&As[(wA*64 + i*16 + l16) * 32 + quad*8];
        #pragma unroll
        for (int j = 0; j < 4; ++j)
            bf[j] = *(const bf16x8*)&Bs[(wB*64 + j*16 + l16) * 32 + quad*8];
        #pragma unroll
        for (int i = 0; i < 4; ++i)
            #pragma unroll
            for (int j = 0; j < 4; ++j)
                acc[i][j] = MFMA16(af[i], bf[j], acc[i][j]);
    }

    #pragma unroll
    for (int i = 0; i < 4; ++i) {
        int col0 = n0 + wA*64 + i*16 + quad*4;
        float4 bias4 = *(const float4*)&bias[col0];
        #pragma unroll
        for (int j = 0; j < 4; ++j) {
            int tok = m0 + wB*64 + j*16 + l16;
            float4 o = { acc[i][j][0] + bias4.x, acc[i][j][1] + bias4.y,
                         acc[i][j][2] + bias4.z, acc[i][j][3] + bias4.w };
            *(float4*)(out + (size_t)tok * CDIM + col0) = o;
        }
    }
}

extern "C" void kernel_launch(void* const* d_in, const int* in_sizes, int n_in,
                              void* d_out, int out_size, void* d_ws, size_t ws_size,
                              hipStream_t stream)
{
    const float* x      = (const float*)d_in[0];
    const int*   mask   = (const int*)d_in[1];
    const float* w_qkv  = (const float*)d_in[2];
    const float* w_proj = (const float*)d_in[3];
    const float* b_proj = (const float*)d_in[4];
    float* out = (float*)d_out;

    const size_t SZ = (size_t)NTOK * CDIM;       // 3,145,728
    short* xb  = (short*)d_ws;                   // [4096][768]
    short* wqt = xb  + SZ;                       // [2304][768]
    short* wpt = wqt + (size_t)QKV_COLS * CDIM;  // [768][768]
    short* qb  = wpt + (size_t)CDIM * CDIM;      // [BH][N][64]  (pre-scaled q)
    short* kb  = qb  + SZ;                       // [BH][N][64]
    short* vt  = kb  + SZ;                       // [BH][64][N]
    short* ao  = vt  + SZ;                       // [4096][768]
    short* maskb = ao + SZ;                      // [B][N] bf16 mask

    dim3 blk(256);
    prep_kernel<<<dim3(5378), blk, 0, stream>>>(x, w_qkv, w_proj, mask,
                                                xb, wqt, wpt, maskb);
    gemm_qkv<<<dim3(QKV_COLS/128, NTOK/128), blk, 0, stream>>>(wqt, xb, qb, kb, vt);
    attn_kernel<<<dim3(NBLK), blk, 0, stream>>>(qb, kb, vt, maskb, ao);
    gemm_proj<<<dim3(CDIM/128, NTOK/128), blk, 0, stream>>>(wpt, ao, b_proj, out);
}

// Round 3
// 174.990 us; speedup vs baseline: 1.5653x; 1.5653x over previous
//
#include <hip/hip_runtime.h>
#include <cstdint>

#define NB 2
#define NSEQ 2048
#define CDIM 768
#define NH 12
#define HD 64
#define NTOK (NB*NSEQ)        // 4096
#define QKV_COLS (3*CDIM)     // 2304
#define NBLK ((NSEQ/64)*NH*NB) // 768 attn blocks

typedef short bf16x8 __attribute__((ext_vector_type(8)));
typedef short bf16x4 __attribute__((ext_vector_type(4)));
typedef float f32x4  __attribute__((ext_vector_type(4)));
typedef short short4v __attribute__((ext_vector_type(4)));
typedef unsigned int uint4v __attribute__((ext_vector_type(4)));

#define MFMA16(a,b,c) __builtin_amdgcn_mfma_f32_16x16x32_bf16(a,b,c,0,0,0)

__device__ __forceinline__ short f2b(float f) {
    uint32_t u = __builtin_bit_cast(uint32_t, f);
    u += 0x7fffu + ((u >> 16) & 1u);
    return (short)(u >> 16);
}
__device__ __forceinline__ float b2f(short s) {
    return __builtin_bit_cast(float, (uint32_t)((uint32_t)(unsigned short)s << 16));
}
__device__ __forceinline__ unsigned pack2(float a, float b) {
    unsigned ua = __builtin_bit_cast(unsigned, a) + 0x7fffu;
    unsigned ub = __builtin_bit_cast(unsigned, b) + 0x7fffu;
    return __builtin_amdgcn_perm(ub, ua, 0x07060302u);
}
__device__ __forceinline__ void gll16(const short* g, short* l) {
    __builtin_amdgcn_global_load_lds(
        (const __attribute__((address_space(1))) unsigned int*)g,
        (__attribute__((address_space(3))) unsigned int*)l, 16, 0, 0);
}

// ---------------------------------------------------------------------------
// Merged prep: x fp32->bf16 (blocks 0..3071), w_qkv transpose (..4799),
// w_proj transpose (..5375), mask int->bf16 (5376..5377).
// ---------------------------------------------------------------------------
__global__ __launch_bounds__(256) void prep_kernel(
    const float* __restrict__ x, const float* __restrict__ w_qkv,
    const float* __restrict__ w_proj, const int* __restrict__ mask,
    short* __restrict__ xb, short* __restrict__ wqt, short* __restrict__ wpt,
    short* __restrict__ maskb)
{
    __shared__ float tile[32][33];
    const int bid = blockIdx.x, t = threadIdx.x;
    if (bid < 3072) {
        int i = bid * 256 + t;
        float4 v = ((const float4*)x)[i];
        short4v o = { f2b(v.x), f2b(v.y), f2b(v.z), f2b(v.w) };
        ((short4v*)xb)[i] = o;
        return;
    }
    if (bid >= 5376) {
        int i = ((bid - 5376) << 11) + (t << 3);   // 2 blocks x 2048 values
        int4 a = *(const int4*)(mask + i);
        int4 c = *(const int4*)(mask + i + 4);
        short4v o0 = { f2b((float)a.x), f2b((float)a.y),
                       f2b((float)a.z), f2b((float)a.w) };
        short4v o1 = { f2b((float)c.x), f2b((float)c.y),
                       f2b((float)c.z), f2b((float)c.w) };
        *(short4v*)(maskb + i) = o0;
        *(short4v*)(maskb + i + 4) = o1;
        return;
    }
    const float* w; short* wt; int K, NC, n0, k0;
    if (bid < 3072 + 1728) {
        int r = bid - 3072;
        w = w_qkv; wt = wqt; K = CDIM; NC = QKV_COLS;
        n0 = (r % 72) * 32; k0 = (r / 72) * 32;
    } else {
        int r = bid - 4800;
        w = w_proj; wt = wpt; K = CDIM; NC = CDIM;
        n0 = (r % 24) * 32; k0 = (r / 24) * 32;
    }
    #pragma unroll
    for (int i = 0; i < 4; ++i) {
        int idx = t + i * 256; int r = idx >> 5, c = idx & 31;
        tile[r][c] = w[(size_t)(k0 + r) * NC + n0 + c];
    }
    __syncthreads();
    #pragma unroll
    for (int i = 0; i < 4; ++i) {
        int idx = t + i * 256; int r = idx >> 5, c = idx & 31;
        wt[(size_t)(n0 + r) * K + k0 + c] = f2b(tile[c][r]);
    }
}

// ---------------------------------------------------------------------------
// GEMM1 (m97-style). Epilogue: q is PRE-SCALED by 0.125 (softmax scale).
// ---------------------------------------------------------------------------
__global__ __launch_bounds__(256) void gemm_qkv(
    const short* __restrict__ A /*wqt[2304][768]*/,
    const short* __restrict__ B /*xb [4096][768]*/,
    short* __restrict__ qb, short* __restrict__ kb, short* __restrict__ vt)
{
    __shared__ short As[128 * 32];
    __shared__ short Bs[128 * 32];
    const int t = threadIdx.x;
    const int lane = t & 63, wid = t >> 6;
    const int quad = lane >> 4, l16 = lane & 15;
    const int wA = wid >> 1, wB = wid & 1;
    const int n0 = blockIdx.x * 128;
    const int m0 = blockIdx.y * 128;

    const int srow = wid * 16 + (lane >> 2), schunk = (lane & 3) * 8;
    const short* ag0 = A + (size_t)(n0 + srow) * CDIM + schunk;
    const short* ag1 = ag0 + (size_t)64 * CDIM;
    const short* bg0 = B + (size_t)(m0 + srow) * CDIM + schunk;
    const short* bg1 = bg0 + (size_t)64 * CDIM;
    short* asl0 = &As[(wid * 16) * 32];
    short* asl1 = &As[(wid * 16 + 64) * 32];
    short* bsl0 = &Bs[(wid * 16) * 32];
    short* bsl1 = &Bs[(wid * 16 + 64) * 32];

    f32x4 acc[4][4] = {};
    for (int k0 = 0; k0 < CDIM; k0 += 32) {
        __syncthreads();
        gll16(ag0 + k0, asl0);
        gll16(ag1 + k0, asl1);
        gll16(bg0 + k0, bsl0);
        gll16(bg1 + k0, bsl1);
        __syncthreads();
        bf16x8 af[4], bf[4];
        #pragma unroll
        for (int i = 0; i < 4; ++i)
            af[i] = *(const bf16x8*)&As[(wA*64 + i*16 + l16) * 32 + quad*8];
        #pragma unroll
        for (int j = 0; j < 4; ++j)
            bf[j] = *(const bf16x8*)&Bs[(wB*64 + j*16 + l16) * 32 + quad*8];
        #pragma unroll
        for (int i = 0; i < 4; ++i)
            #pragma unroll
            for (int j = 0; j < 4; ++j)
                acc[i][j] = MFMA16(af[i], bf[j], acc[i][j]);
    }

    const int colbase = n0 + wA * 64;
    const int s = colbase / CDIM;
    const int h = (colbase - s * CDIM) >> 6;
    const int b = m0 >> 11;
    const size_t bh = (size_t)(b * NH + h);
    const float qsc = (s == 0) ? 0.125f : 1.0f;   // fold softmax scale into q
    #pragma unroll
    for (int i = 0; i < 4; ++i) {
        const int d0 = i*16 + quad*4;
        #pragma unroll
        for (int j = 0; j < 4; ++j) {
            int tok = (m0 + wB*64 + j*16 + l16) & (NSEQ - 1);
            if (s < 2) {
                short* dst = (s == 0 ? qb : kb) + (bh * NSEQ + tok) * HD + d0;
                short4v o = { f2b(acc[i][j][0] * qsc), f2b(acc[i][j][1] * qsc),
                              f2b(acc[i][j][2] * qsc), f2b(acc[i][j][3] * qsc) };
                *(short4v*)dst = o;
            } else {
                short* dst = vt + (bh * HD + d0) * NSEQ + tok;
                #pragma unroll
                for (int r = 0; r < 4; ++r)
                    dst[(size_t)r * NSEQ] = f2b(acc[i][j][r]);
            }
        }
    }
}

// ---------------------------------------------------------------------------
// Flash attention v11 = v10 structure with the ONE-TOKEN fix: back to
// __launch_bounds__(256, 2). Round-2's (256,3) capped the unified
// VGPR+AGPR budget at ~170 and the allocator left only 84 arch VGPRs ->
// 600 MB/dispatch scratch spill (WRITE_SIZE 306 MB), dur 157us.
// With (256,2) the kernel compiles to ~128 VGPR (v8-measured, same macros);
// occupancy = min(LDS: 160/52 -> 3 blocks/CU, VGPR: 512/128 -> 4) = 3
// blocks/CU, all 768 blocks co-resident (768 = 3x256, zero tail).
//   - K double-buffered (2x16KB): needed at tile top.
//   - V single-buffered (16KB): staged at tile top, latency hides under
//     QK+exp; tile body split by a second barrier (QK/exp | sync | PV | sync).
//   - mask as bf16 in LDS (4KB), staged once -- no per-tile global loads.
// ---------------------------------------------------------------------------
#define STAGE_K(KT, BUF) do {                                                    \
    short* kb_ = (BUF);                                                          \
    _Pragma("unroll")                                                            \
    for (int j = 0; j < 4; ++j)                                                  \
        gll16(kp + (size_t)((KT) + rK[j]) * HD + cK[j]*8,                        \
              kb_ + wid*2048 + j*512);                                           \
} while (0)

#define STAGE_V(KT) do {                                                         \
    _Pragma("unroll")                                                            \
    for (int j = 0; j < 4; ++j)                                                  \
        gll16(vp + (size_t)dV[j] * NSEQ + (KT) + cV[j]*8,                        \
              Vb + wid*2048 + j*512);                                            \
} while (0)

#define QKBODY(KT, KBUF) do {                                                    \
    const short* KsB_ = (KBUF);                                                  \
    short4v mi0_ = *(const short4v*)&Msk[(KT) + mbase];                          \
    short4v mi1_ = *(const short4v*)&Msk[(KT) + 64 + mbase];                     \
    bf16x8 kf00_ = *(const bf16x8*)&KsB_[krow + kc0];                            \
    bf16x8 kf01_ = *(const bf16x8*)&KsB_[krow + kc1];                            \
    bf16x8 kf10_ = *(const bf16x8*)&KsB_[4096 + krow + kc0];                     \
    bf16x8 kf11_ = *(const bf16x8*)&KsB_[4096 + krow + kc1];                     \
    f32x4 s0_[4] = {}, s1_[4] = {};                                              \
    _Pragma("unroll")                                                            \
    for (int jt = 0; jt < 4; ++jt) {                                             \
        s0_[jt] = MFMA16(kf00_, qf[jt][0], s0_[jt]);                             \
        s0_[jt] = MFMA16(kf01_, qf[jt][1], s0_[jt]);                             \
        s1_[jt] = MFMA16(kf10_, qf[jt][0], s1_[jt]);                             \
        s1_[jt] = MFMA16(kf11_, qf[jt][1], s1_[jt]);                             \
    }                                                                            \
    float4 m0_ = { b2f(mi0_[0]), b2f(mi0_[1]), b2f(mi0_[2]), b2f(mi0_[3]) };     \
    float4 m1_ = { b2f(mi1_[0]), b2f(mi1_[1]), b2f(mi1_[2]), b2f(mi1_[3]) };     \
    _Pragma("unroll")                                                            \
    for (int jt = 0; jt < 4; ++jt) {                                             \
        float e0 = __expf(s0_[jt][0]) * m0_.x;                                   \
        float e1 = __expf(s0_[jt][1]) * m0_.y;                                   \
        float e2 = __expf(s0_[jt][2]) * m0_.z;                                   \
        float e3 = __expf(s0_[jt][3]) * m0_.w;                                   \
        float f0 = __expf(s1_[jt][0]) * m1_.x;                                   \
        float f1 = __expf(s1_[jt][1]) * m1_.y;                                   \
        float f2 = __expf(s1_[jt][2]) * m1_.z;                                   \
        float f3 = __expf(s1_[jt][3]) * m1_.w;                                   \
        l[jt] += ((e0 + e1) + (e2 + e3)) + ((f0 + f1) + (f2 + f3));              \
        uint4v pk_ = { pack2(e0, e1), pack2(e2, e3),                             \
                       pack2(f0, f1), pack2(f2, f3) };                           \
        pb[jt] = __builtin_bit_cast(bf16x8, pk_);                                \
    }                                                                            \
} while (0)

#define PVBODY() do {                                                            \
    _Pragma("unroll")                                                            \
    for (int it = 0; it < 4; ++it) {                                             \
        const int vrow_ = (it*16 + l16) * 128;                                   \
        bf16x4 lo_ = *(const bf16x4*)&Vb[vrow_ + vposl + vsub];                  \
        bf16x4 hi_ = *(const bf16x4*)&Vb[vrow_ + vposh + vsub];                  \
        bf16x8 vf_ = __builtin_shufflevector(lo_, hi_, 0,1,2,3,4,5,6,7);         \
        _Pragma("unroll")                                                        \
        for (int jt = 0; jt < 4; ++jt)                                           \
            o_acc[it][jt] = MFMA16(vf_, pb[jt], o_acc[it][jt]);                  \
    }                                                                            \
} while (0)

__global__ __launch_bounds__(256, 2) void attn_kernel(
    const short* __restrict__ qb, const short* __restrict__ kb,
    const short* __restrict__ vt, const short* __restrict__ maskb,
    short* __restrict__ ao)
{
    __shared__ __align__(16) short Kb[2][8192];   // K tiles [128][64], dbuf
    __shared__ __align__(16) short Vb[8192];      // V tile  [64][128], single
    __shared__ __align__(16) short Msk[2048];     // bf16 mask row, this b
    float (*Ob)[68] = (float(*)[68])Kb;           // epilogue alias (18.4<32KB)
    float (*lsum)[64] = (float(*)[64])((char*)Kb + 17408);

    const int t = threadIdx.x;
    const int lane = t & 63, wid = t >> 6;
    const int quad = lane >> 4, l16 = lane & 15;
    // XCD swizzle: XCD = id%8 owns bh in {xcd, xcd+8, xcd+16}
    const int id = blockIdx.x;
    const int idx = id >> 3;
    const int bh = (id & 7) + ((idx % 3) << 3);
    const int q0 = (idx / 3) << 6;
    const int b = bh / NH, h = bh - b * NH;
    const size_t hoff = (size_t)bh * NSEQ * HD;
    const short* qp = qb + hoff;     // [N][64]  (q pre-scaled by 0.125)
    const short* kp = kb + hoff;     // [N][64]
    const short* vp = vt + hoff;     // [64][N]
    const int mbase = wid * 16 + quad * 4;

    int rK[4], cK[4], dV[4], cV[4];
    #pragma unroll
    for (int j = 0; j < 4; ++j) {
        int o = wid * 4096 + j * 1024 + lane * 16;
        rK[j] = o >> 7;
        cK[j] = ((o >> 4) & 7) ^ (rK[j] & 7);
        dV[j] = o >> 8;
        cV[j] = ((o >> 4) & 15) ^ (dV[j] & 15);
    }
    const int r7 = l16 & 7;
    const int krow = (wid * 16 + l16) * 64;
    const int kc0 = ((quad     ^ r7) << 3);
    const int kc1 = (((quad+4) ^ r7) << 3);
    const int vposl = ((wid*2 + (quad >> 1)) ^ l16) << 3;
    const int vposh = (((8 + wid*2 + (quad >> 1)) ^ l16) << 3);
    const int vsub = (quad & 1) * 4;

    bf16x8 qf[4][2];
    #pragma unroll
    for (int jt = 0; jt < 4; ++jt) {
        const short* qr = qp + (size_t)(q0 + jt*16 + l16) * HD + quad*8;
        qf[jt][0] = *(const bf16x8*)qr;
        qf[jt][1] = *(const bf16x8*)(qr + 32);
    }

    f32x4 o_acc[4][4] = {};
    float l[4] = {0.f, 0.f, 0.f, 0.f};
    bf16x8 pb[4];

    // Prologue: K tile 0 + mask row, one barrier.
    STAGE_K(0, Kb[0]);
    gll16(maskb + b * NSEQ + t * 8, Msk + wid * 512);
    __syncthreads();

    for (int kt = 0; kt < NSEQ; kt += 256) {
        STAGE_V(kt);
        STAGE_K(kt + 128, Kb[1]);
        QKBODY(kt, Kb[0]);
        __syncthreads();          // V(kt) staged + all QK reads of Kb[0] done
        PVBODY();
        __syncthreads();          // PV reads of Vb done -> safe to overwrite

        STAGE_V(kt + 128);
        STAGE_K((kt + 256) & (NSEQ - 1), Kb[0]);
        QKBODY(kt + 128, Kb[1]);
        __syncthreads();
        PVBODY();
        __syncthreads();
    }

    #pragma unroll
    for (int jt = 0; jt < 4; ++jt) {
        l[jt] += __shfl_xor(l[jt], 16);
        l[jt] += __shfl_xor(l[jt], 32);
        if (quad == 0) lsum[wid][jt*16 + l16] = l[jt];
    }
    for (int w = 0; w < 4; ++w) {
        __syncthreads();
        if (wid == w) {
            #pragma unroll
            for (int it = 0; it < 4; ++it)
                #pragma unroll
                for (int jt = 0; jt < 4; ++jt)
                    #pragma unroll
                    for (int r = 0; r < 4; ++r) {
                        if (w == 0)
                            Ob[it*16 + quad*4 + r][jt*16 + l16] = o_acc[it][jt][r];
                        else
                            Ob[it*16 + quad*4 + r][jt*16 + l16] += o_acc[it][jt][r];
                    }
        }
    }
    __syncthreads();

    {
        const int ql = t >> 2, dc = (t & 3) * 16;
        float inv = 1.0f / (((lsum[0][ql] + lsum[1][ql]) +
                             (lsum[2][ql] + lsum[3][ql])));
        bf16x8 o8a, o8b;
        #pragma unroll
        for (int d = 0; d < 8; ++d) o8a[d] = f2b(Ob[dc + d][ql] * inv);
        #pragma unroll
        for (int d = 0; d < 8; ++d) o8b[d] = f2b(Ob[dc + 8 + d][ql] * inv);
        int tok = b * NSEQ + q0 + ql;
        short* dst = ao + (size_t)tok * CDIM + h * HD + dc;
        *(bf16x8*)dst = o8a;
        *(bf16x8*)(dst + 8) = o8b;
    }
}

// ---------------------------------------------------------------------------
// GEMM2 (m97-style, round-8 verbatim)
// ---------------------------------------------------------------------------
__global__ __launch_bounds__(256) void gemm_proj(
    const short* __restrict__ A /*wpt[768][768]*/,
    const short* __restrict__ B /*ao [4096][768]*/,
    const float* __restrict__ bias, float* __restrict__ out)
{
    __shared__ short As[128 * 32];
    __shared__ short Bs[128 * 32];
    const int t = threadIdx.x;
    const int lane = t & 63, wid = t >> 6;
    const int quad = lane >> 4, l16 = lane & 15;
    const int wA = wid >> 1, wB = wid & 1;
    const int n0 = blockIdx.x * 128;
    const int m0 = blockIdx.y * 128;

    const int srow = wid * 16 + (lane >> 2), schunk = (lane & 3) * 8;
    const short* ag0 = A + (size_t)(n0 + srow) * CDIM + schunk;
    const short* ag1 = ag0 + (size_t)64 * CDIM;
    const short* bg0 = B + (size_t)(m0 + srow) * CDIM + schunk;
    const short* bg1 = bg0 + (size_t)64 * CDIM;
    short* asl0 = &As[(wid * 16) * 32];
    short* asl1 = &As[(wid * 16 + 64) * 32];
    short* bsl0 = &Bs[(wid * 16) * 32];
    short* bsl1 = &Bs[(wid * 16 + 64) * 32];

    f32x4 acc[4][4] = {};
    for (int k0 = 0; k0 < CDIM; k0 += 32) {
        __syncthreads();
        gll16(ag0 + k0, asl0);
        gll16(ag1 + k0, asl1);
        gll16(bg0 + k0, bsl0);
        gll16(bg1 + k0, bsl1);
        __syncthreads();
        bf16x8 af[4], bf[4];
        #pragma unroll
        for (int i = 0; i < 4; ++i)
            af[i] = *(const bf16x8*)&As[(wA*64 + i*16 + l16) * 32 + quad*8];
        #pragma unroll
        for (int j = 0; j < 4; ++j)
            bf[j] = *(const bf16x8*)&Bs[(wB*64 + j*16 + l16) * 32 + quad*8];
        #pragma unroll
        for (int i = 0; i < 4; ++i)
            #pragma unroll
            for (int j = 0; j < 4; ++j)
                acc[i][j] = MFMA16(af[i], bf[j], acc[i][j]);
    }

    #pragma unroll
    for (int i = 0; i < 4; ++i) {
        int col0 = n0 + wA*64 + i*16 + quad*4;
        float4 bias4 = *(const float4*)&bias[col0];
        #pragma unroll
        for (int j = 0; j < 4; ++j) {
            int tok = m0 + wB*64 + j*16 + l16;
            float4 o = { acc[i][j][0] + bias4.x, acc[i][j][1] + bias4.y,
                         acc[i][j][2] + bias4.z, acc[i][j][3] + bias4.w };
            *(float4*)(out + (size_t)tok * CDIM + col0) = o;
        }
    }
}

extern "C" void kernel_launch(void* const* d_in, const int* in_sizes, int n_in,
                              void* d_out, int out_size, void* d_ws, size_t ws_size,
                              hipStream_t stream)
{
    const float* x      = (const float*)d_in[0];
    const int*   mask   = (const int*)d_in[1];
    const float* w_qkv  = (const float*)d_in[2];
    const float* w_proj = (const float*)d_in[3];
    const float* b_proj = (const float*)d_in[4];
    float* out = (float*)d_out;

    const size_t SZ = (size_t)NTOK * CDIM;       // 3,145,728
    short* xb  = (short*)d_ws;                   // [4096][768]
    short* wqt = xb  + SZ;                       // [2304][768]
    short* wpt = wqt + (size_t)QKV_COLS * CDIM;  // [768][768]
    short* qb  = wpt + (size_t)CDIM * CDIM;      // [BH][N][64]  (pre-scaled q)
    short* kb  = qb  + SZ;                       // [BH][N][64]
    short* vt  = kb  + SZ;                       // [BH][64][N]
    short* ao  = vt  + SZ;                       // [4096][768]
    short* maskb = ao + SZ;                      // [B][N] bf16 mask

    dim3 blk(256);
    prep_kernel<<<dim3(5378), blk, 0, stream>>>(x, w_qkv, w_proj, mask,
                                                xb, wqt, wpt, maskb);
    gemm_qkv<<<dim3(QKV_COLS/128, NTOK/128), blk, 0, stream>>>(wqt, xb, qb, kb, vt);
    attn_kernel<<<dim3(NBLK), blk, 0, stream>>>(qb, kb, vt, maskb, ao);
    gemm_proj<<<dim3(CDIM/128, NTOK/128), blk, 0, stream>>>(wpt, ao, b_proj, out);
}

// Round 4
// 174.715 us; speedup vs baseline: 1.5678x; 1.0016x over previous
//
#include <hip/hip_runtime.h>
#include <cstdint>

#define NB 2
#define NSEQ 2048
#define CDIM 768
#define NH 12
#define HD 64
#define NTOK (NB*NSEQ)        // 4096
#define QKV_COLS (3*CDIM)     // 2304
#define NBLK ((NSEQ/64)*NH*NB) // 768 attn blocks

typedef short bf16x8 __attribute__((ext_vector_type(8)));
typedef short bf16x4 __attribute__((ext_vector_type(4)));
typedef float f32x4  __attribute__((ext_vector_type(4)));
typedef short short4v __attribute__((ext_vector_type(4)));
typedef unsigned int uint4v __attribute__((ext_vector_type(4)));

#define MFMA16(a,b,c) __builtin_amdgcn_mfma_f32_16x16x32_bf16(a,b,c,0,0,0)

__device__ __forceinline__ short f2b(float f) {
    uint32_t u = __builtin_bit_cast(uint32_t, f);
    u += 0x7fffu + ((u >> 16) & 1u);
    return (short)(u >> 16);
}
__device__ __forceinline__ float b2f(short s) {
    return __builtin_bit_cast(float, (uint32_t)((uint32_t)(unsigned short)s << 16));
}
__device__ __forceinline__ unsigned pack2(float a, float b) {
    unsigned ua = __builtin_bit_cast(unsigned, a) + 0x7fffu;
    unsigned ub = __builtin_bit_cast(unsigned, b) + 0x7fffu;
    return __builtin_amdgcn_perm(ub, ua, 0x07060302u);
}
__device__ __forceinline__ void gll16(const short* g, short* l) {
    __builtin_amdgcn_global_load_lds(
        (const __attribute__((address_space(1))) unsigned int*)g,
        (__attribute__((address_space(3))) unsigned int*)l, 16, 0, 0);
}

// ---------------------------------------------------------------------------
// Merged prep: x fp32->bf16 (blocks 0..3071), w_qkv transpose (..4799),
// w_proj transpose (..5375), mask int->bf16 (5376..5377).
// ---------------------------------------------------------------------------
__global__ __launch_bounds__(256) void prep_kernel(
    const float* __restrict__ x, const float* __restrict__ w_qkv,
    const float* __restrict__ w_proj, const int* __restrict__ mask,
    short* __restrict__ xb, short* __restrict__ wqt, short* __restrict__ wpt,
    short* __restrict__ maskb)
{
    __shared__ float tile[32][33];
    const int bid = blockIdx.x, t = threadIdx.x;
    if (bid < 3072) {
        int i = bid * 256 + t;
        float4 v = ((const float4*)x)[i];
        short4v o = { f2b(v.x), f2b(v.y), f2b(v.z), f2b(v.w) };
        ((short4v*)xb)[i] = o;
        return;
    }
    if (bid >= 5376) {
        int i = ((bid - 5376) << 11) + (t << 3);   // 2 blocks x 2048 values
        int4 a = *(const int4*)(mask + i);
        int4 c = *(const int4*)(mask + i + 4);
        short4v o0 = { f2b((float)a.x), f2b((float)a.y),
                       f2b((float)a.z), f2b((float)a.w) };
        short4v o1 = { f2b((float)c.x), f2b((float)c.y),
                       f2b((float)c.z), f2b((float)c.w) };
        *(short4v*)(maskb + i) = o0;
        *(short4v*)(maskb + i + 4) = o1;
        return;
    }
    const float* w; short* wt; int K, NC, n0, k0;
    if (bid < 3072 + 1728) {
        int r = bid - 3072;
        w = w_qkv; wt = wqt; K = CDIM; NC = QKV_COLS;
        n0 = (r % 72) * 32; k0 = (r / 72) * 32;
    } else {
        int r = bid - 4800;
        w = w_proj; wt = wpt; K = CDIM; NC = CDIM;
        n0 = (r % 24) * 32; k0 = (r / 24) * 32;
    }
    #pragma unroll
    for (int i = 0; i < 4; ++i) {
        int idx = t + i * 256; int r = idx >> 5, c = idx & 31;
        tile[r][c] = w[(size_t)(k0 + r) * NC + n0 + c];
    }
    __syncthreads();
    #pragma unroll
    for (int i = 0; i < 4; ++i) {
        int idx = t + i * 256; int r = idx >> 5, c = idx & 31;
        wt[(size_t)(n0 + r) * K + k0 + c] = f2b(tile[c][r]);
    }
}

// ---------------------------------------------------------------------------
// GEMM1 (m97-style). Epilogue: q is PRE-SCALED by 0.125 (softmax scale).
// ---------------------------------------------------------------------------
__global__ __launch_bounds__(256) void gemm_qkv(
    const short* __restrict__ A /*wqt[2304][768]*/,
    const short* __restrict__ B /*xb [4096][768]*/,
    short* __restrict__ qb, short* __restrict__ kb, short* __restrict__ vt)
{
    __shared__ short As[128 * 32];
    __shared__ short Bs[128 * 32];
    const int t = threadIdx.x;
    const int lane = t & 63, wid = t >> 6;
    const int quad = lane >> 4, l16 = lane & 15;
    const int wA = wid >> 1, wB = wid & 1;
    const int n0 = blockIdx.x * 128;
    const int m0 = blockIdx.y * 128;

    const int srow = wid * 16 + (lane >> 2), schunk = (lane & 3) * 8;
    const short* ag0 = A + (size_t)(n0 + srow) * CDIM + schunk;
    const short* ag1 = ag0 + (size_t)64 * CDIM;
    const short* bg0 = B + (size_t)(m0 + srow) * CDIM + schunk;
    const short* bg1 = bg0 + (size_t)64 * CDIM;
    short* asl0 = &As[(wid * 16) * 32];
    short* asl1 = &As[(wid * 16 + 64) * 32];
    short* bsl0 = &Bs[(wid * 16) * 32];
    short* bsl1 = &Bs[(wid * 16 + 64) * 32];

    f32x4 acc[4][4] = {};
    for (int k0 = 0; k0 < CDIM; k0 += 32) {
        __syncthreads();
        gll16(ag0 + k0, asl0);
        gll16(ag1 + k0, asl1);
        gll16(bg0 + k0, bsl0);
        gll16(bg1 + k0, bsl1);
        __syncthreads();
        bf16x8 af[4], bf[4];
        #pragma unroll
        for (int i = 0; i < 4; ++i)
            af[i] = *(const bf16x8*)&As[(wA*64 + i*16 + l16) * 32 + quad*8];
        #pragma unroll
        for (int j = 0; j < 4; ++j)
            bf[j] = *(const bf16x8*)&Bs[(wB*64 + j*16 + l16) * 32 + quad*8];
        #pragma unroll
        for (int i = 0; i < 4; ++i)
            #pragma unroll
            for (int j = 0; j < 4; ++j)
                acc[i][j] = MFMA16(af[i], bf[j], acc[i][j]);
    }

    const int colbase = n0 + wA * 64;
    const int s = colbase / CDIM;
    const int h = (colbase - s * CDIM) >> 6;
    const int b = m0 >> 11;
    const size_t bh = (size_t)(b * NH + h);
    const float qsc = (s == 0) ? 0.125f : 1.0f;   // fold softmax scale into q
    #pragma unroll
    for (int i = 0; i < 4; ++i) {
        const int d0 = i*16 + quad*4;
        #pragma unroll
        for (int j = 0; j < 4; ++j) {
            int tok = (m0 + wB*64 + j*16 + l16) & (NSEQ - 1);
            if (s < 2) {
                short* dst = (s == 0 ? qb : kb) + (bh * NSEQ + tok) * HD + d0;
                short4v o = { f2b(acc[i][j][0] * qsc), f2b(acc[i][j][1] * qsc),
                              f2b(acc[i][j][2] * qsc), f2b(acc[i][j][3] * qsc) };
                *(short4v*)dst = o;
            } else {
                short* dst = vt + (bh * HD + d0) * NSEQ + tok;
                #pragma unroll
                for (int r = 0; r < 4; ++r)
                    dst[(size_t)r * NSEQ] = f2b(acc[i][j][r]);
            }
        }
    }
}

// ---------------------------------------------------------------------------
// Flash attention v12: Q-SPLIT work decomposition to cut per-wave register
// state. Diagnosis chain: (256,3) budget=170 regs spilled catastrophically
// (round 2) => true state ~192-200 (o_acc 64 + qf 32 + pb 16 + ...) => HW
// caps at 2 waves/SIMD = 2 blocks/CU regardless of LDS => rounds 0/3 both
// ~60us at identical ~16% occupancy.
// Q-split: each wave owns 16 q-rows x ALL 128 keys of the tile (was: 64 q x
// private 32 keys). o_acc 64->16 regs, qf 32->8, l[4]->l, pb stays 16.
// MFMA/exp counts per wave UNCHANGED; LDS reads x4 (that's what staging is
// for; same conflict-free swizzle). Cross-wave O reduction + its 5 barriers
// DELETED (output rows are wave-private). State ~130 => fits (256,3)'s 170
// budget without spill => 3 waves/SIMD; LDS 52KB => 3 blocks/CU; 768=3x256
// co-resident, zero tail.
// ---------------------------------------------------------------------------
#define STAGE_K(KT, BUF) do {                                                    \
    short* kb_ = (BUF);                                                          \
    _Pragma("unroll")                                                            \
    for (int j = 0; j < 4; ++j)                                                  \
        gll16(kp + (size_t)((KT) + rK[j]) * HD + cK[j]*8,                        \
              kb_ + wid*2048 + j*512);                                           \
} while (0)

#define STAGE_V(KT) do {                                                         \
    _Pragma("unroll")                                                            \
    for (int j = 0; j < 4; ++j)                                                  \
        gll16(vp + (size_t)dV[j] * NSEQ + (KT) + cV[j]*8,                        \
              Vb + wid*2048 + j*512);                                            \
} while (0)

// Per 128-key tile: wave computes S^T for all 128 keys x its 16 q rows.
// ks pairs key-subtiles (ks, ks+4) -> pb[ks] is the 32-key-deep B fragment.
#define QKBODY(KT, KBUF) do {                                                    \
    const short* KsB_ = (KBUF);                                                  \
    _Pragma("unroll")                                                            \
    for (int ks = 0; ks < 4; ++ks) {                                             \
        short4v mi0_ = *(const short4v*)&Msk[(KT) + ks*16 + qrow4];              \
        short4v mi1_ = *(const short4v*)&Msk[(KT) + 64 + ks*16 + qrow4];         \
        const int kro_ = (ks*16 + l16) * 64;                                     \
        bf16x8 kf00_ = *(const bf16x8*)&KsB_[kro_ + kc0];                        \
        bf16x8 kf01_ = *(const bf16x8*)&KsB_[kro_ + kc1];                        \
        bf16x8 kf10_ = *(const bf16x8*)&KsB_[4096 + kro_ + kc0];                 \
        bf16x8 kf11_ = *(const bf16x8*)&KsB_[4096 + kro_ + kc1];                 \
        f32x4 s0_ = {}, s1_ = {};                                                \
        s0_ = MFMA16(kf00_, qf0, s0_);                                           \
        s0_ = MFMA16(kf01_, qf1, s0_);                                           \
        s1_ = MFMA16(kf10_, qf0, s1_);                                           \
        s1_ = MFMA16(kf11_, qf1, s1_);                                           \
        float e0 = __expf(s0_[0]) * b2f(mi0_[0]);                                \
        float e1 = __expf(s0_[1]) * b2f(mi0_[1]);                                \
        float e2 = __expf(s0_[2]) * b2f(mi0_[2]);                                \
        float e3 = __expf(s0_[3]) * b2f(mi0_[3]);                                \
        float f0 = __expf(s1_[0]) * b2f(mi1_[0]);                                \
        float f1 = __expf(s1_[1]) * b2f(mi1_[1]);                                \
        float f2 = __expf(s1_[2]) * b2f(mi1_[2]);                                \
        float f3 = __expf(s1_[3]) * b2f(mi1_[3]);                                \
        l += ((e0 + e1) + (e2 + e3)) + ((f0 + f1) + (f2 + f3));                  \
        uint4v pk_ = { pack2(e0, e1), pack2(e2, e3),                             \
                       pack2(f0, f1), pack2(f2, f3) };                           \
        pb[ks] = __builtin_bit_cast(bf16x8, pk_);                                \
    }                                                                            \
} while (0)

// PV: o_acc[it] (d = it*16..+15, wave's 16 q) accumulates over 4 ks pairs.
#define PVBODY() do {                                                            \
    _Pragma("unroll")                                                            \
    for (int it = 0; it < 4; ++it) {                                             \
        const int vrow_ = (it*16 + l16) * 128;                                   \
        _Pragma("unroll")                                                        \
        for (int ks = 0; ks < 4; ++ks) {                                         \
            const int gl_ = (((ks*2 + qh) ^ l16) << 3) + vsub;                   \
            const int gh_ = (((8 + ks*2 + qh) ^ l16) << 3) + vsub;               \
            bf16x4 lo_ = *(const bf16x4*)&Vb[vrow_ + gl_];                       \
            bf16x4 hi_ = *(const bf16x4*)&Vb[vrow_ + gh_];                       \
            bf16x8 vf_ = __builtin_shufflevector(lo_, hi_, 0,1,2,3,4,5,6,7);     \
            o_acc[it] = MFMA16(vf_, pb[ks], o_acc[it]);                          \
        }                                                                        \
    }                                                                            \
} while (0)

__global__ __launch_bounds__(256, 3) void attn_kernel(
    const short* __restrict__ qb, const short* __restrict__ kb,
    const short* __restrict__ vt, const short* __restrict__ maskb,
    short* __restrict__ ao)
{
    __shared__ __align__(16) short Kb[2][8192];   // K tiles [128][64], dbuf
    __shared__ __align__(16) short Vb[8192];      // V tile  [64][128], single
    __shared__ __align__(16) short Msk[2048];     // bf16 mask row, this b

    const int t = threadIdx.x;
    const int lane = t & 63, wid = t >> 6;
    const int quad = lane >> 4, l16 = lane & 15;
    // XCD swizzle: XCD = id%8 owns bh in {xcd, xcd+8, xcd+16}
    const int id = blockIdx.x;
    const int idx = id >> 3;
    const int bh = (id & 7) + ((idx % 3) << 3);
    const int q0 = (idx / 3) << 6;
    const int b = bh / NH, h = bh - b * NH;
    const size_t hoff = (size_t)bh * NSEQ * HD;
    const short* qp = qb + hoff;     // [N][64]  (q pre-scaled by 0.125)
    const short* kp = kb + hoff;     // [N][64]
    const short* vp = vt + hoff;     // [64][N]
    const int qrow4 = quad * 4;

    int rK[4], cK[4], dV[4], cV[4];
    #pragma unroll
    for (int j = 0; j < 4; ++j) {
        int o = wid * 4096 + j * 1024 + lane * 16;
        rK[j] = o >> 7;
        cK[j] = ((o >> 4) & 7) ^ (rK[j] & 7);
        dV[j] = o >> 8;
        cV[j] = ((o >> 4) & 15) ^ (dV[j] & 15);
    }
    const int r7 = l16 & 7;
    const int kc0 = ((quad     ^ r7) << 3);
    const int kc1 = (((quad+4) ^ r7) << 3);
    const int qh = quad >> 1;
    const int vsub = (quad & 1) * 4;

    // Wave's 16 q rows: q0 + wid*16 + l16
    bf16x8 qf0, qf1;
    {
        const short* qr = qp + (size_t)(q0 + wid*16 + l16) * HD + quad*8;
        qf0 = *(const bf16x8*)qr;
        qf1 = *(const bf16x8*)(qr + 32);
    }

    f32x4 o_acc[4] = {};
    float l = 0.f;
    bf16x8 pb[4];

    // Prologue: K tile 0 + mask row, one barrier.
    STAGE_K(0, Kb[0]);
    gll16(maskb + b * NSEQ + t * 8, Msk + wid * 512);
    __syncthreads();

    for (int kt = 0; kt < NSEQ; kt += 256) {
        STAGE_V(kt);
        STAGE_K(kt + 128, Kb[1]);
        QKBODY(kt, Kb[0]);
        __syncthreads();          // V(kt) staged + all QK reads of Kb[0] done
        PVBODY();
        __syncthreads();          // PV reads of Vb done -> safe to overwrite

        STAGE_V(kt + 128);
        STAGE_K((kt + 256) & (NSEQ - 1), Kb[0]);
        QKBODY(kt + 128, Kb[1]);
        __syncthreads();
        PVBODY();
        __syncthreads();
    }

    // Epilogue: wave-private. l reduce across quads (key-dim), then store.
    l += __shfl_xor(l, 16);
    l += __shfl_xor(l, 32);
    const float inv = 1.0f / l;

    const int tok = b * NSEQ + q0 + wid*16 + l16;
    short* dst = ao + (size_t)tok * CDIM + h * HD + qrow4;
    #pragma unroll
    for (int it = 0; it < 4; ++it) {
        short4v o = { f2b(o_acc[it][0] * inv), f2b(o_acc[it][1] * inv),
                      f2b(o_acc[it][2] * inv), f2b(o_acc[it][3] * inv) };
        *(short4v*)(dst + it*16) = o;
    }
}

// ---------------------------------------------------------------------------
// GEMM2 (m97-style, round-8 verbatim)
// ---------------------------------------------------------------------------
__global__ __launch_bounds__(256) void gemm_proj(
    const short* __restrict__ A /*wpt[768][768]*/,
    const short* __restrict__ B /*ao [4096][768]*/,
    const float* __restrict__ bias, float* __restrict__ out)
{
    __shared__ short As[128 * 32];
    __shared__ short Bs[128 * 32];
    const int t = threadIdx.x;
    const int lane = t & 63, wid = t >> 6;
    const int quad = lane >> 4, l16 = lane & 15;
    const int wA = wid >> 1, wB = wid & 1;
    const int n0 = blockIdx.x * 128;
    const int m0 = blockIdx.y * 128;

    const int srow = wid * 16 + (lane >> 2), schunk = (lane & 3) * 8;
    const short* ag0 = A + (size_t)(n0 + srow) * CDIM + schunk;
    const short* ag1 = ag0 + (size_t)64 * CDIM;
    const short* bg0 = B + (size_t)(m0 + srow) * CDIM + schunk;
    const short* bg1 = bg0 + (size_t)64 * CDIM;
    short* asl0 = &As[(wid * 16) * 32];
    short* asl1 = &As[(wid * 16 + 64) * 32];
    short* bsl0 = &Bs[(wid * 16) * 32];
    short* bsl1 = &Bs[(wid * 16 + 64) * 32];

    f32x4 acc[4][4] = {};
    for (int k0 = 0; k0 < CDIM; k0 += 32) {
        __syncthreads();
        gll16(ag0 + k0, asl0);
        gll16(ag1 + k0, asl1);
        gll16(bg0 + k0, bsl0);
        gll16(bg1 + k0, bsl1);
        __syncthreads();
        bf16x8 af[4], bf[4];
        #pragma unroll
        for (int i = 0; i < 4; ++i)
            af[i] = *(const bf16x8*)&As[(wA*64 + i*16 + l16) * 32 + quad*8];
        #pragma unroll
        for (int j = 0; j < 4; ++j)
            bf[j] = *(const bf16x8*)&Bs[(wB*64 + j*16 + l16) * 32 + quad*8];
        #pragma unroll
        for (int i = 0; i < 4; ++i)
            #pragma unroll
            for (int j = 0; j < 4; ++j)
                acc[i][j] = MFMA16(af[i], bf[j], acc[i][j]);
    }

    #pragma unroll
    for (int i = 0; i < 4; ++i) {
        int col0 = n0 + wA*64 + i*16 + quad*4;
        float4 bias4 = *(const float4*)&bias[col0];
        #pragma unroll
        for (int j = 0; j < 4; ++j) {
            int tok = m0 + wB*64 + j*16 + l16;
            float4 o = { acc[i][j][0] + bias4.x, acc[i][j][1] + bias4.y,
                         acc[i][j][2] + bias4.z, acc[i][j][3] + bias4.w };
            *(float4*)(out + (size_t)tok * CDIM + col0) = o;
        }
    }
}

extern "C" void kernel_launch(void* const* d_in, const int* in_sizes, int n_in,
                              void* d_out, int out_size, void* d_ws, size_t ws_size,
                              hipStream_t stream)
{
    const float* x      = (const float*)d_in[0];
    const int*   mask   = (const int*)d_in[1];
    const float* w_qkv  = (const float*)d_in[2];
    const float* w_proj = (const float*)d_in[3];
    const float* b_proj = (const float*)d_in[4];
    float* out = (float*)d_out;

    const size_t SZ = (size_t)NTOK * CDIM;       // 3,145,728
    short* xb  = (short*)d_ws;                   // [4096][768]
    short* wqt = xb  + SZ;                       // [2304][768]
    short* wpt = wqt + (size_t)QKV_COLS * CDIM;  // [768][768]
    short* qb  = wpt + (size_t)CDIM * CDIM;      // [BH][N][64]  (pre-scaled q)
    short* kb  = qb  + SZ;                       // [BH][N][64]
    short* vt  = kb  + SZ;                       // [BH][64][N]
    short* ao  = vt  + SZ;                       // [4096][768]
    short* maskb = ao + SZ;                      // [B][N] bf16 mask

    dim3 blk(256);
    prep_kernel<<<dim3(5378), blk, 0, stream>>>(x, w_qkv, w_proj, mask,
                                                xb, wqt, wpt, maskb);
    gemm_qkv<<<dim3(QKV_COLS/128, NTOK/128), blk, 0, stream>>>(wqt, xb, qb, kb, vt);
    attn_kernel<<<dim3(NBLK), blk, 0, stream>>>(qb, kb, vt, maskb, ao);
    gemm_proj<<<dim3(CDIM/128, NTOK/128), blk, 0, stream>>>(wpt, ao, b_proj, out);
}

// Round 5
// 167.561 us; speedup vs baseline: 1.6347x; 1.0427x over previous
//
#include <hip/hip_runtime.h>
#include <cstdint>

#define NB 2
#define NSEQ 2048
#define CDIM 768
#define NH 12
#define HD 64
#define NTOK (NB*NSEQ)        // 4096
#define QKV_COLS (3*CDIM)     // 2304
#define NBLK ((NSEQ/64)*NH*NB) // 768 attn blocks

typedef short bf16x8 __attribute__((ext_vector_type(8)));
typedef short bf16x4 __attribute__((ext_vector_type(4)));
typedef float f32x4  __attribute__((ext_vector_type(4)));
typedef short short4v __attribute__((ext_vector_type(4)));
typedef unsigned int uint4v __attribute__((ext_vector_type(4)));

#define MFMA16(a,b,c) __builtin_amdgcn_mfma_f32_16x16x32_bf16(a,b,c,0,0,0)

__device__ __forceinline__ short f2b(float f) {
    uint32_t u = __builtin_bit_cast(uint32_t, f);
    u += 0x7fffu + ((u >> 16) & 1u);
    return (short)(u >> 16);
}
__device__ __forceinline__ float b2f(short s) {
    return __builtin_bit_cast(float, (uint32_t)((uint32_t)(unsigned short)s << 16));
}
__device__ __forceinline__ unsigned pack2(float a, float b) {
    unsigned ua = __builtin_bit_cast(unsigned, a) + 0x7fffu;
    unsigned ub = __builtin_bit_cast(unsigned, b) + 0x7fffu;
    return __builtin_amdgcn_perm(ub, ua, 0x07060302u);
}
// 2^x on the trans pipe; q is pre-scaled by 0.125*log2(e) so exp2(s)==exp(qk/8).
__device__ __forceinline__ float fexp2(float x) {
#if __has_builtin(__builtin_amdgcn_exp2f)
    return __builtin_amdgcn_exp2f(x);
#else
    return __expf(x * 0.69314718055994531f);
#endif
}
__device__ __forceinline__ void gll16(const short* g, short* l) {
    __builtin_amdgcn_global_load_lds(
        (const __attribute__((address_space(1))) unsigned int*)g,
        (__attribute__((address_space(3))) unsigned int*)l, 16, 0, 0);
}

// ---------------------------------------------------------------------------
// Merged prep: x fp32->bf16 (blocks 0..3071), w_qkv transpose (..4799),
// w_proj transpose (..5375), mask int->bf16 LOG2-BIAS (5376..5377):
//   attend -> 0.0, masked -> -16384.0 (bf16 0xC680). exp2(s-16384) == +0
//   exactly, so masked keys contribute exactly 0 (matches exp(s)*0).
// ---------------------------------------------------------------------------
__global__ __launch_bounds__(256) void prep_kernel(
    const float* __restrict__ x, const float* __restrict__ w_qkv,
    const float* __restrict__ w_proj, const int* __restrict__ mask,
    short* __restrict__ xb, short* __restrict__ wqt, short* __restrict__ wpt,
    short* __restrict__ maskb)
{
    __shared__ float tile[32][33];
    const int bid = blockIdx.x, t = threadIdx.x;
    if (bid < 3072) {
        int i = bid * 256 + t;
        float4 v = ((const float4*)x)[i];
        short4v o = { f2b(v.x), f2b(v.y), f2b(v.z), f2b(v.w) };
        ((short4v*)xb)[i] = o;
        return;
    }
    if (bid >= 5376) {
        int i = ((bid - 5376) << 11) + (t << 3);   // 2 blocks x 2048 values
        int4 a = *(const int4*)(mask + i);
        int4 c = *(const int4*)(mask + i + 4);
        const short NEG = (short)0xC680;           // bf16 -16384.0
        short4v o0 = { a.x ? (short)0 : NEG, a.y ? (short)0 : NEG,
                       a.z ? (short)0 : NEG, a.w ? (short)0 : NEG };
        short4v o1 = { c.x ? (short)0 : NEG, c.y ? (short)0 : NEG,
                       c.z ? (short)0 : NEG, c.w ? (short)0 : NEG };
        *(short4v*)(maskb + i) = o0;
        *(short4v*)(maskb + i + 4) = o1;
        return;
    }
    const float* w; short* wt; int K, NC, n0, k0;
    if (bid < 3072 + 1728) {
        int r = bid - 3072;
        w = w_qkv; wt = wqt; K = CDIM; NC = QKV_COLS;
        n0 = (r % 72) * 32; k0 = (r / 72) * 32;
    } else {
        int r = bid - 4800;
        w = w_proj; wt = wpt; K = CDIM; NC = CDIM;
        n0 = (r % 24) * 32; k0 = (r / 24) * 32;
    }
    #pragma unroll
    for (int i = 0; i < 4; ++i) {
        int idx = t + i * 256; int r = idx >> 5, c = idx & 31;
        tile[r][c] = w[(size_t)(k0 + r) * NC + n0 + c];
    }
    __syncthreads();
    #pragma unroll
    for (int i = 0; i < 4; ++i) {
        int idx = t + i * 256; int r = idx >> 5, c = idx & 31;
        wt[(size_t)(n0 + r) * K + k0 + c] = f2b(tile[c][r]);
    }
}

// ---------------------------------------------------------------------------
// GEMM1 (m97-style). Epilogue: q is PRE-SCALED by 0.125*log2(e) so the attn
// kernel can use raw v_exp (2^x) with no per-element multiply.
// ---------------------------------------------------------------------------
__global__ __launch_bounds__(256) void gemm_qkv(
    const short* __restrict__ A /*wqt[2304][768]*/,
    const short* __restrict__ B /*xb [4096][768]*/,
    short* __restrict__ qb, short* __restrict__ kb, short* __restrict__ vt)
{
    __shared__ short As[128 * 32];
    __shared__ short Bs[128 * 32];
    const int t = threadIdx.x;
    const int lane = t & 63, wid = t >> 6;
    const int quad = lane >> 4, l16 = lane & 15;
    const int wA = wid >> 1, wB = wid & 1;
    const int n0 = blockIdx.x * 128;
    const int m0 = blockIdx.y * 128;

    const int srow = wid * 16 + (lane >> 2), schunk = (lane & 3) * 8;
    const short* ag0 = A + (size_t)(n0 + srow) * CDIM + schunk;
    const short* ag1 = ag0 + (size_t)64 * CDIM;
    const short* bg0 = B + (size_t)(m0 + srow) * CDIM + schunk;
    const short* bg1 = bg0 + (size_t)64 * CDIM;
    short* asl0 = &As[(wid * 16) * 32];
    short* asl1 = &As[(wid * 16 + 64) * 32];
    short* bsl0 = &Bs[(wid * 16) * 32];
    short* bsl1 = &Bs[(wid * 16 + 64) * 32];

    f32x4 acc[4][4] = {};
    for (int k0 = 0; k0 < CDIM; k0 += 32) {
        __syncthreads();
        gll16(ag0 + k0, asl0);
        gll16(ag1 + k0, asl1);
        gll16(bg0 + k0, bsl0);
        gll16(bg1 + k0, bsl1);
        __syncthreads();
        bf16x8 af[4], bf[4];
        #pragma unroll
        for (int i = 0; i < 4; ++i)
            af[i] = *(const bf16x8*)&As[(wA*64 + i*16 + l16) * 32 + quad*8];
        #pragma unroll
        for (int j = 0; j < 4; ++j)
            bf[j] = *(const bf16x8*)&Bs[(wB*64 + j*16 + l16) * 32 + quad*8];
        #pragma unroll
        for (int i = 0; i < 4; ++i)
            #pragma unroll
            for (int j = 0; j < 4; ++j)
                acc[i][j] = MFMA16(af[i], bf[j], acc[i][j]);
    }

    const int colbase = n0 + wA * 64;
    const int s = colbase / CDIM;
    const int h = (colbase - s * CDIM) >> 6;
    const int b = m0 >> 11;
    const size_t bh = (size_t)(b * NH + h);
    // fold softmax scale AND log2(e) into q: exp(qk/8) == exp2(qk*qsc)
    const float qsc = (s == 0) ? 0.18033688011112042f : 1.0f;
    #pragma unroll
    for (int i = 0; i < 4; ++i) {
        const int d0 = i*16 + quad*4;
        #pragma unroll
        for (int j = 0; j < 4; ++j) {
            int tok = (m0 + wB*64 + j*16 + l16) & (NSEQ - 1);
            if (s < 2) {
                short* dst = (s == 0 ? qb : kb) + (bh * NSEQ + tok) * HD + d0;
                short4v o = { f2b(acc[i][j][0] * qsc), f2b(acc[i][j][1] * qsc),
                              f2b(acc[i][j][2] * qsc), f2b(acc[i][j][3] * qsc) };
                *(short4v*)dst = o;
            } else {
                short* dst = vt + (bh * HD + d0) * NSEQ + tok;
                #pragma unroll
                for (int r = 0; r < 4; ++r)
                    dst[(size_t)r * NSEQ] = f2b(acc[i][j][r]);
            }
        }
    }
}

// ---------------------------------------------------------------------------
// Flash attention v13 = v12 (q-split, 3 blocks/CU) + softmax VALU cut:
//  1. exp2-fold: q pre-scaled by 0.125*log2e -> raw v_exp, no mul (saves
//     32 v_mul/tile/wave).
//  2. mask as additive log2-bias, injected via MFMA C-INIT (the matrix op
//     adds it for free): masked keys -> exp2(s-16384) == +0 exactly.
//     Saves 32 mask-muls/tile/wave; also kills the inf*0=NaN hazard.
//  3. l-sum via ones-MFMA: lacc = MFMA(ones, pb[ks], lacc) -> C[m][q] =
//     sum_k P[k][q] (all rows identical). 4 MFMA/tile (pipe 17% busy)
//     replace 28 serial VALU adds + the epilogue shuffle pair. Denominator
//     now sums the SAME bf16-rounded P used by PV (consistent rounding).
// QKBODY VALU: ~204 -> ~112 ops/tile/wave. LDS read pattern untouched
// (round-6 candidate if dur doesn't follow VALUBusy down: 2x2 hybrid split
// to halve the 4x K/V read replication q-split introduced).
// ---------------------------------------------------------------------------
#define STAGE_K(KT, BUF) do {                                                    \
    short* kb_ = (BUF);                                                          \
    _Pragma("unroll")                                                            \
    for (int j = 0; j < 4; ++j)                                                  \
        gll16(kp + (size_t)((KT) + rK[j]) * HD + cK[j]*8,                        \
              kb_ + wid*2048 + j*512);                                           \
} while (0)

#define STAGE_V(KT) do {                                                         \
    _Pragma("unroll")                                                            \
    for (int j = 0; j < 4; ++j)                                                  \
        gll16(vp + (size_t)dV[j] * NSEQ + (KT) + cV[j]*8,                        \
              Vb + wid*2048 + j*512);                                            \
} while (0)

// Per 128-key tile: wave computes S^T for all 128 keys x its 16 q rows.
// S accumulator is INITIALIZED with the mask log2-bias (keys = C rows).
#define QKBODY(KT, KBUF) do {                                                    \
    const short* KsB_ = (KBUF);                                                  \
    _Pragma("unroll")                                                            \
    for (int ks = 0; ks < 4; ++ks) {                                             \
        short4v mi0_ = *(const short4v*)&Msk[(KT) + ks*16 + qrow4];              \
        short4v mi1_ = *(const short4v*)&Msk[(KT) + 64 + ks*16 + qrow4];         \
        const int kro_ = (ks*16 + l16) * 64;                                     \
        bf16x8 kf00_ = *(const bf16x8*)&KsB_[kro_ + kc0];                        \
        bf16x8 kf01_ = *(const bf16x8*)&KsB_[kro_ + kc1];                        \
        bf16x8 kf10_ = *(const bf16x8*)&KsB_[4096 + kro_ + kc0];                 \
        bf16x8 kf11_ = *(const bf16x8*)&KsB_[4096 + kro_ + kc1];                 \
        f32x4 s0_ = { b2f(mi0_[0]), b2f(mi0_[1]),                                \
                      b2f(mi0_[2]), b2f(mi0_[3]) };                              \
        f32x4 s1_ = { b2f(mi1_[0]), b2f(mi1_[1]),                                \
                      b2f(mi1_[2]), b2f(mi1_[3]) };                              \
        s0_ = MFMA16(kf00_, qf0, s0_);                                           \
        s0_ = MFMA16(kf01_, qf1, s0_);                                           \
        s1_ = MFMA16(kf10_, qf0, s1_);                                           \
        s1_ = MFMA16(kf11_, qf1, s1_);                                           \
        float e0 = fexp2(s0_[0]);                                                \
        float e1 = fexp2(s0_[1]);                                                \
        float e2 = fexp2(s0_[2]);                                                \
        float e3 = fexp2(s0_[3]);                                                \
        float f0 = fexp2(s1_[0]);                                                \
        float f1 = fexp2(s1_[1]);                                                \
        float f2 = fexp2(s1_[2]);                                                \
        float f3 = fexp2(s1_[3]);                                                \
        uint4v pk_ = { pack2(e0, e1), pack2(e2, e3),                             \
                       pack2(f0, f1), pack2(f2, f3) };                           \
        pb[ks] = __builtin_bit_cast(bf16x8, pk_);                                \
    }                                                                            \
} while (0)

// PV + denominator: lacc rows all equal sum_k P[k][q] (ones A-fragment).
#define PVBODY() do {                                                            \
    _Pragma("unroll")                                                            \
    for (int ks = 0; ks < 4; ++ks)                                               \
        lacc = MFMA16(onesv, pb[ks], lacc);                                      \
    _Pragma("unroll")                                                            \
    for (int it = 0; it < 4; ++it) {                                             \
        const int vrow_ = (it*16 + l16) * 128;                                   \
        _Pragma("unroll")                                                        \
        for (int ks = 0; ks < 4; ++ks) {                                         \
            const int gl_ = (((ks*2 + qh) ^ l16) << 3) + vsub;                   \
            const int gh_ = (((8 + ks*2 + qh) ^ l16) << 3) + vsub;               \
            bf16x4 lo_ = *(const bf16x4*)&Vb[vrow_ + gl_];                       \
            bf16x4 hi_ = *(const bf16x4*)&Vb[vrow_ + gh_];                       \
            bf16x8 vf_ = __builtin_shufflevector(lo_, hi_, 0,1,2,3,4,5,6,7);     \
            o_acc[it] = MFMA16(vf_, pb[ks], o_acc[it]);                          \
        }                                                                        \
    }                                                                            \
} while (0)

__global__ __launch_bounds__(256, 3) void attn_kernel(
    const short* __restrict__ qb, const short* __restrict__ kb,
    const short* __restrict__ vt, const short* __restrict__ maskb,
    short* __restrict__ ao)
{
    __shared__ __align__(16) short Kb[2][8192];   // K tiles [128][64], dbuf
    __shared__ __align__(16) short Vb[8192];      // V tile  [64][128], single
    __shared__ __align__(16) short Msk[2048];     // bf16 log2-bias, this b

    const int t = threadIdx.x;
    const int lane = t & 63, wid = t >> 6;
    const int quad = lane >> 4, l16 = lane & 15;
    // XCD swizzle: XCD = id%8 owns bh in {xcd, xcd+8, xcd+16}
    const int id = blockIdx.x;
    const int idx = id >> 3;
    const int bh = (id & 7) + ((idx % 3) << 3);
    const int q0 = (idx / 3) << 6;
    const int b = bh / NH, h = bh - b * NH;
    const size_t hoff = (size_t)bh * NSEQ * HD;
    const short* qp = qb + hoff;     // [N][64]  (q pre-scaled by 0.125*log2e)
    const short* kp = kb + hoff;     // [N][64]
    const short* vp = vt + hoff;     // [64][N]
    const int qrow4 = quad * 4;

    int rK[4], cK[4], dV[4], cV[4];
    #pragma unroll
    for (int j = 0; j < 4; ++j) {
        int o = wid * 4096 + j * 1024 + lane * 16;
        rK[j] = o >> 7;
        cK[j] = ((o >> 4) & 7) ^ (rK[j] & 7);
        dV[j] = o >> 8;
        cV[j] = ((o >> 4) & 15) ^ (dV[j] & 15);
    }
    const int r7 = l16 & 7;
    const int kc0 = ((quad     ^ r7) << 3);
    const int kc1 = (((quad+4) ^ r7) << 3);
    const int qh = quad >> 1;
    const int vsub = (quad & 1) * 4;

    // Wave's 16 q rows: q0 + wid*16 + l16
    bf16x8 qf0, qf1;
    {
        const short* qr = qp + (size_t)(q0 + wid*16 + l16) * HD + quad*8;
        qf0 = *(const bf16x8*)qr;
        qf1 = *(const bf16x8*)(qr + 32);
    }

    const short one_ = (short)0x3F80;             // bf16 1.0
    const bf16x8 onesv = { one_, one_, one_, one_, one_, one_, one_, one_ };

    f32x4 o_acc[4] = {};
    f32x4 lacc = {};
    bf16x8 pb[4];

    // Prologue: K tile 0 + mask row, one barrier.
    STAGE_K(0, Kb[0]);
    gll16(maskb + b * NSEQ + t * 8, Msk + wid * 512);
    __syncthreads();

    for (int kt = 0; kt < NSEQ; kt += 256) {
        STAGE_V(kt);
        STAGE_K(kt + 128, Kb[1]);
        QKBODY(kt, Kb[0]);
        __syncthreads();          // V(kt) staged + all QK reads of Kb[0] done
        PVBODY();
        __syncthreads();          // PV reads of Vb done -> safe to overwrite

        STAGE_V(kt + 128);
        STAGE_K((kt + 256) & (NSEQ - 1), Kb[0]);
        QKBODY(kt + 128, Kb[1]);
        __syncthreads();
        PVBODY();
        __syncthreads();
    }

    // Epilogue: wave-private; lacc rows identical => no cross-lane reduce.
    const float inv = 1.0f / lacc[0];

    const int tok = b * NSEQ + q0 + wid*16 + l16;
    short* dst = ao + (size_t)tok * CDIM + h * HD + qrow4;
    #pragma unroll
    for (int it = 0; it < 4; ++it) {
        short4v o = { f2b(o_acc[it][0] * inv), f2b(o_acc[it][1] * inv),
                      f2b(o_acc[it][2] * inv), f2b(o_acc[it][3] * inv) };
        *(short4v*)(dst + it*16) = o;
    }
}

// ---------------------------------------------------------------------------
// GEMM2 (m97-style, round-8 verbatim)
// ---------------------------------------------------------------------------
__global__ __launch_bounds__(256) void gemm_proj(
    const short* __restrict__ A /*wpt[768][768]*/,
    const short* __restrict__ B /*ao [4096][768]*/,
    const float* __restrict__ bias, float* __restrict__ out)
{
    __shared__ short As[128 * 32];
    __shared__ short Bs[128 * 32];
    const int t = threadIdx.x;
    const int lane = t & 63, wid = t >> 6;
    const int quad = lane >> 4, l16 = lane & 15;
    const int wA = wid >> 1, wB = wid & 1;
    const int n0 = blockIdx.x * 128;
    const int m0 = blockIdx.y * 128;

    const int srow = wid * 16 + (lane >> 2), schunk = (lane & 3) * 8;
    const short* ag0 = A + (size_t)(n0 + srow) * CDIM + schunk;
    const short* ag1 = ag0 + (size_t)64 * CDIM;
    const short* bg0 = B + (size_t)(m0 + srow) * CDIM + schunk;
    const short* bg1 = bg0 + (size_t)64 * CDIM;
    short* asl0 = &As[(wid * 16) * 32];
    short* asl1 = &As[(wid * 16 + 64) * 32];
    short* bsl0 = &Bs[(wid * 16) * 32];
    short* bsl1 = &Bs[(wid * 16 + 64) * 32];

    f32x4 acc[4][4] = {};
    for (int k0 = 0; k0 < CDIM; k0 += 32) {
        __syncthreads();
        gll16(ag0 + k0, asl0);
        gll16(ag1 + k0, asl1);
        gll16(bg0 + k0, bsl0);
        gll16(bg1 + k0, bsl1);
        __syncthreads();
        bf16x8 af[4], bf[4];
        #pragma unroll
        for (int i = 0; i < 4; ++i)
            af[i] = *(const bf16x8*)&As[(wA*64 + i*16 + l16) * 32 + quad*8];
        #pragma unroll
        for (int j = 0; j < 4; ++j)
            bf[j] = *(const bf16x8*)&Bs[(wB*64 + j*16 + l16) * 32 + quad*8];
        #pragma unroll
        for (int i = 0; i < 4; ++i)
            #pragma unroll
            for (int j = 0; j < 4; ++j)
                acc[i][j] = MFMA16(af[i], bf[j], acc[i][j]);
    }

    #pragma unroll
    for (int i = 0; i < 4; ++i) {
        int col0 = n0 + wA*64 + i*16 + quad*4;
        float4 bias4 = *(const float4*)&bias[col0];
        #pragma unroll
        for (int j = 0; j < 4; ++j) {
            int tok = m0 + wB*64 + j*16 + l16;
            float4 o = { acc[i][j][0] + bias4.x, acc[i][j][1] + bias4.y,
                         acc[i][j][2] + bias4.z, acc[i][j][3] + bias4.w };
            *(float4*)(out + (size_t)tok * CDIM + col0) = o;
        }
    }
}

extern "C" void kernel_launch(void* const* d_in, const int* in_sizes, int n_in,
                              void* d_out, int out_size, void* d_ws, size_t ws_size,
                              hipStream_t stream)
{
    const float* x      = (const float*)d_in[0];
    const int*   mask   = (const int*)d_in[1];
    const float* w_qkv  = (const float*)d_in[2];
    const float* w_proj = (const float*)d_in[3];
    const float* b_proj = (const float*)d_in[4];
    float* out = (float*)d_out;

    const size_t SZ = (size_t)NTOK * CDIM;       // 3,145,728
    short* xb  = (short*)d_ws;                   // [4096][768]
    short* wqt = xb  + SZ;                       // [2304][768]
    short* wpt = wqt + (size_t)QKV_COLS * CDIM;  // [768][768]
    short* qb  = wpt + (size_t)CDIM * CDIM;      // [BH][N][64]  (pre-scaled q)
    short* kb  = qb  + SZ;                       // [BH][N][64]
    short* vt  = kb  + SZ;                       // [BH][64][N]
    short* ao  = vt  + SZ;                       // [4096][768]
    short* maskb = ao + SZ;                      // [B][N] bf16 log2-bias

    dim3 blk(256);
    prep_kernel<<<dim3(5378), blk, 0, stream>>>(x, w_qkv, w_proj, mask,
                                                xb, wqt, wpt, maskb);
    gemm_qkv<<<dim3(QKV_COLS/128, NTOK/128), blk, 0, stream>>>(wqt, xb, qb, kb, vt);
    attn_kernel<<<dim3(NBLK), blk, 0, stream>>>(qb, kb, vt, maskb, ao);
    gemm_proj<<<dim3(CDIM/128, NTOK/128), blk, 0, stream>>>(wpt, ao, b_proj, out);
}

// Round 6
// 159.651 us; speedup vs baseline: 1.7157x; 1.0495x over previous
//
#include <hip/hip_runtime.h>
#include <cstdint>

#define NB 2
#define NSEQ 2048
#define CDIM 768
#define NH 12
#define HD 64
#define NTOK (NB*NSEQ)        // 4096
#define QKV_COLS (3*CDIM)     // 2304
#define NBLK ((NSEQ/64)*NH*NB) // 768 attn blocks

typedef short bf16x8 __attribute__((ext_vector_type(8)));
typedef short bf16x4 __attribute__((ext_vector_type(4)));
typedef float f32x4  __attribute__((ext_vector_type(4)));
typedef short short4v __attribute__((ext_vector_type(4)));
typedef unsigned int uint4v __attribute__((ext_vector_type(4)));

#define MFMA16(a,b,c) __builtin_amdgcn_mfma_f32_16x16x32_bf16(a,b,c,0,0,0)

__device__ __forceinline__ short f2b(float f) {
    uint32_t u = __builtin_bit_cast(uint32_t, f);
    u += 0x7fffu + ((u >> 16) & 1u);
    return (short)(u >> 16);
}
__device__ __forceinline__ float b2f(short s) {
    return __builtin_bit_cast(float, (uint32_t)((uint32_t)(unsigned short)s << 16));
}
__device__ __forceinline__ unsigned pack2(float a, float b) {
    unsigned ua = __builtin_bit_cast(unsigned, a) + 0x7fffu;
    unsigned ub = __builtin_bit_cast(unsigned, b) + 0x7fffu;
    return __builtin_amdgcn_perm(ub, ua, 0x07060302u);
}
// 2^x on the trans pipe; q is pre-scaled by 0.125*log2(e) so exp2(s)==exp(qk/8).
__device__ __forceinline__ float fexp2(float x) {
#if __has_builtin(__builtin_amdgcn_exp2f)
    return __builtin_amdgcn_exp2f(x);
#else
    return __expf(x * 0.69314718055994531f);
#endif
}
__device__ __forceinline__ void gll16(const short* g, short* l) {
    __builtin_amdgcn_global_load_lds(
        (const __attribute__((address_space(1))) unsigned int*)g,
        (__attribute__((address_space(3))) unsigned int*)l, 16, 0, 0);
}

// ---------------------------------------------------------------------------
// Merged prep: x fp32->bf16 (blocks 0..3071), w_qkv transpose (..4799),
// w_proj transpose (..5375), mask int->bf16 LOG2-BIAS (5376..5377):
//   attend -> 0.0, masked -> -16384.0 (bf16 0xC680). exp2(s-16384) == +0
//   exactly, so masked keys contribute exactly 0 (matches exp(s)*0).
// ---------------------------------------------------------------------------
__global__ __launch_bounds__(256) void prep_kernel(
    const float* __restrict__ x, const float* __restrict__ w_qkv,
    const float* __restrict__ w_proj, const int* __restrict__ mask,
    short* __restrict__ xb, short* __restrict__ wqt, short* __restrict__ wpt,
    short* __restrict__ maskb)
{
    __shared__ float tile[32][33];
    const int bid = blockIdx.x, t = threadIdx.x;
    if (bid < 3072) {
        int i = bid * 256 + t;
        float4 v = ((const float4*)x)[i];
        short4v o = { f2b(v.x), f2b(v.y), f2b(v.z), f2b(v.w) };
        ((short4v*)xb)[i] = o;
        return;
    }
    if (bid >= 5376) {
        int i = ((bid - 5376) << 11) + (t << 3);   // 2 blocks x 2048 values
        int4 a = *(const int4*)(mask + i);
        int4 c = *(const int4*)(mask + i + 4);
        const short NEG = (short)0xC680;           // bf16 -16384.0
        short4v o0 = { a.x ? (short)0 : NEG, a.y ? (short)0 : NEG,
                       a.z ? (short)0 : NEG, a.w ? (short)0 : NEG };
        short4v o1 = { c.x ? (short)0 : NEG, c.y ? (short)0 : NEG,
                       c.z ? (short)0 : NEG, c.w ? (short)0 : NEG };
        *(short4v*)(maskb + i) = o0;
        *(short4v*)(maskb + i + 4) = o1;
        return;
    }
    const float* w; short* wt; int K, NC, n0, k0;
    if (bid < 3072 + 1728) {
        int r = bid - 3072;
        w = w_qkv; wt = wqt; K = CDIM; NC = QKV_COLS;
        n0 = (r % 72) * 32; k0 = (r / 72) * 32;
    } else {
        int r = bid - 4800;
        w = w_proj; wt = wpt; K = CDIM; NC = CDIM;
        n0 = (r % 24) * 32; k0 = (r / 24) * 32;
    }
    #pragma unroll
    for (int i = 0; i < 4; ++i) {
        int idx = t + i * 256; int r = idx >> 5, c = idx & 31;
        tile[r][c] = w[(size_t)(k0 + r) * NC + n0 + c];
    }
    __syncthreads();
    #pragma unroll
    for (int i = 0; i < 4; ++i) {
        int idx = t + i * 256; int r = idx >> 5, c = idx & 31;
        wt[(size_t)(n0 + r) * K + k0 + c] = f2b(tile[c][r]);
    }
}

// ---------------------------------------------------------------------------
// GEMM1 (m97-style). Epilogue: q is PRE-SCALED by 0.125*log2(e) so the attn
// kernel can use raw v_exp (2^x) with no per-element multiply.
// ---------------------------------------------------------------------------
__global__ __launch_bounds__(256) void gemm_qkv(
    const short* __restrict__ A /*wqt[2304][768]*/,
    const short* __restrict__ B /*xb [4096][768]*/,
    short* __restrict__ qb, short* __restrict__ kb, short* __restrict__ vt)
{
    __shared__ short As[128 * 32];
    __shared__ short Bs[128 * 32];
    const int t = threadIdx.x;
    const int lane = t & 63, wid = t >> 6;
    const int quad = lane >> 4, l16 = lane & 15;
    const int wA = wid >> 1, wB = wid & 1;
    const int n0 = blockIdx.x * 128;
    const int m0 = blockIdx.y * 128;

    const int srow = wid * 16 + (lane >> 2), schunk = (lane & 3) * 8;
    const short* ag0 = A + (size_t)(n0 + srow) * CDIM + schunk;
    const short* ag1 = ag0 + (size_t)64 * CDIM;
    const short* bg0 = B + (size_t)(m0 + srow) * CDIM + schunk;
    const short* bg1 = bg0 + (size_t)64 * CDIM;
    short* asl0 = &As[(wid * 16) * 32];
    short* asl1 = &As[(wid * 16 + 64) * 32];
    short* bsl0 = &Bs[(wid * 16) * 32];
    short* bsl1 = &Bs[(wid * 16 + 64) * 32];

    f32x4 acc[4][4] = {};
    for (int k0 = 0; k0 < CDIM; k0 += 32) {
        __syncthreads();
        gll16(ag0 + k0, asl0);
        gll16(ag1 + k0, asl1);
        gll16(bg0 + k0, bsl0);
        gll16(bg1 + k0, bsl1);
        __syncthreads();
        bf16x8 af[4], bf[4];
        #pragma unroll
        for (int i = 0; i < 4; ++i)
            af[i] = *(const bf16x8*)&As[(wA*64 + i*16 + l16) * 32 + quad*8];
        #pragma unroll
        for (int j = 0; j < 4; ++j)
            bf[j] = *(const bf16x8*)&Bs[(wB*64 + j*16 + l16) * 32 + quad*8];
        #pragma unroll
        for (int i = 0; i < 4; ++i)
            #pragma unroll
            for (int j = 0; j < 4; ++j)
                acc[i][j] = MFMA16(af[i], bf[j], acc[i][j]);
    }

    const int colbase = n0 + wA * 64;
    const int s = colbase / CDIM;
    const int h = (colbase - s * CDIM) >> 6;
    const int b = m0 >> 11;
    const size_t bh = (size_t)(b * NH + h);
    // fold softmax scale AND log2(e) into q: exp(qk/8) == exp2(qk*qsc)
    const float qsc = (s == 0) ? 0.18033688011112042f : 1.0f;
    #pragma unroll
    for (int i = 0; i < 4; ++i) {
        const int d0 = i*16 + quad*4;
        #pragma unroll
        for (int j = 0; j < 4; ++j) {
            int tok = (m0 + wB*64 + j*16 + l16) & (NSEQ - 1);
            if (s < 2) {
                short* dst = (s == 0 ? qb : kb) + (bh * NSEQ + tok) * HD + d0;
                short4v o = { f2b(acc[i][j][0] * qsc), f2b(acc[i][j][1] * qsc),
                              f2b(acc[i][j][2] * qsc), f2b(acc[i][j][3] * qsc) };
                *(short4v*)dst = o;
            } else {
                short* dst = vt + (bh * HD + d0) * NSEQ + tok;
                #pragma unroll
                for (int r = 0; r < 4; ++r)
                    dst[(size_t)r * NSEQ] = f2b(acc[i][j][r]);
            }
        }
    }
}

// ---------------------------------------------------------------------------
// Flash attention v14 = v13 + 2x2 HYBRID work split. Round-5 PMC showed the
// LDS read pipe is the critical path (~37us of 53us: 6.9MB reads/CU at 128B/
// cyc + 6.29M conflict-cycles) -- a direct consequence of v12's q-split 4x
// K/V read replication. Hybrid: wave (qg=wid>>1, kg=wid&1) owns 32 q-rows x
// 64 keys. Per wave per tile: K reads 16->8 b128, V 32->16 b64, mask 8->4;
// MFMA (16 QK + 16 PV + 4 lsum) and exp (32) UNCHANGED. Cost: +32 VGPR
// (o_acc[2][4], qf[2][2]; ~110 total, fits 170 budget at 3/SIMD) and a
// one-shot cross-wave combine (kg=1 -> LDS -> kg=0 adds, normalizes, stores).
// Also: skip the wasted wrap-around STAGE_K on the last iteration.
// ---------------------------------------------------------------------------
#define STAGE_K(KT, BUF) do {                                                    \
    short* kb_ = (BUF);                                                          \
    _Pragma("unroll")                                                            \
    for (int j = 0; j < 4; ++j)                                                  \
        gll16(kp + (size_t)((KT) + rK[j]) * HD + cK[j]*8,                        \
              kb_ + wid*2048 + j*512);                                           \
} while (0)

#define STAGE_V(KT) do {                                                         \
    _Pragma("unroll")                                                            \
    for (int j = 0; j < 4; ++j)                                                  \
        gll16(vp + (size_t)dV[j] * NSEQ + (KT) + cV[j]*8,                        \
              Vb + wid*2048 + j*512);                                            \
} while (0)

// Wave computes S^T for its 64 keys (kg half, subtiles paired ks/ks+2 i.e.
// rows +0/+32) x its 32 q rows (jq=0,1). S-acc INITIALIZED with mask bias.
#define QKBODY(KT, KBUF) do {                                                    \
    const short* KsB_ = (KBUF) + kg*4096;                                        \
    _Pragma("unroll")                                                            \
    for (int ks = 0; ks < 2; ++ks) {                                             \
        short4v mi0_ = *(const short4v*)&Msk[(KT) + kg*64 + ks*16 + qrow4];      \
        short4v mi1_ = *(const short4v*)&Msk[(KT) + kg*64 + 32 + ks*16 + qrow4]; \
        const int kro_ = (ks*16 + l16) * 64;                                     \
        bf16x8 kf00_ = *(const bf16x8*)&KsB_[kro_ + kc0];                        \
        bf16x8 kf01_ = *(const bf16x8*)&KsB_[kro_ + kc1];                        \
        bf16x8 kf10_ = *(const bf16x8*)&KsB_[2048 + kro_ + kc0];                 \
        bf16x8 kf11_ = *(const bf16x8*)&KsB_[2048 + kro_ + kc1];                 \
        f32x4 m0v_ = { b2f(mi0_[0]), b2f(mi0_[1]),                               \
                       b2f(mi0_[2]), b2f(mi0_[3]) };                             \
        f32x4 m1v_ = { b2f(mi1_[0]), b2f(mi1_[1]),                               \
                       b2f(mi1_[2]), b2f(mi1_[3]) };                             \
        _Pragma("unroll")                                                        \
        for (int jq = 0; jq < 2; ++jq) {                                         \
            f32x4 s0_ = m0v_, s1_ = m1v_;                                        \
            s0_ = MFMA16(kf00_, qf[jq][0], s0_);                                 \
            s0_ = MFMA16(kf01_, qf[jq][1], s0_);                                 \
            s1_ = MFMA16(kf10_, qf[jq][0], s1_);                                 \
            s1_ = MFMA16(kf11_, qf[jq][1], s1_);                                 \
            float e0 = fexp2(s0_[0]);                                            \
            float e1 = fexp2(s0_[1]);                                            \
            float e2 = fexp2(s0_[2]);                                            \
            float e3 = fexp2(s0_[3]);                                            \
            float f0 = fexp2(s1_[0]);                                            \
            float f1 = fexp2(s1_[1]);                                            \
            float f2 = fexp2(s1_[2]);                                            \
            float f3 = fexp2(s1_[3]);                                            \
            uint4v pk_ = { pack2(e0, e1), pack2(e2, e3),                         \
                           pack2(f0, f1), pack2(f2, f3) };                       \
            pb[jq][ks] = __builtin_bit_cast(bf16x8, pk_);                        \
        }                                                                        \
    }                                                                            \
} while (0)

// PV + denominator over the wave's 64 keys. V fragments shared by both jq.
#define PVBODY() do {                                                            \
    _Pragma("unroll")                                                            \
    for (int ks = 0; ks < 2; ++ks) {                                             \
        lacc[0] = MFMA16(onesv, pb[0][ks], lacc[0]);                             \
        lacc[1] = MFMA16(onesv, pb[1][ks], lacc[1]);                             \
    }                                                                            \
    _Pragma("unroll")                                                            \
    for (int it = 0; it < 4; ++it) {                                             \
        const int vrow_ = (it*16 + l16) * 128;                                   \
        _Pragma("unroll")                                                        \
        for (int ks = 0; ks < 2; ++ks) {                                         \
            const int gl_ = (((kg*8 + ks*2 + qh) ^ l16) << 3) + vsub;            \
            const int gh_ = (((kg*8 + 4 + ks*2 + qh) ^ l16) << 3) + vsub;        \
            bf16x4 lo_ = *(const bf16x4*)&Vb[vrow_ + gl_];                       \
            bf16x4 hi_ = *(const bf16x4*)&Vb[vrow_ + gh_];                       \
            bf16x8 vf_ = __builtin_shufflevector(lo_, hi_, 0,1,2,3,4,5,6,7);     \
            o_acc[0][it] = MFMA16(vf_, pb[0][ks], o_acc[0][it]);                 \
            o_acc[1][it] = MFMA16(vf_, pb[1][ks], o_acc[1][it]);                 \
        }                                                                        \
    }                                                                            \
} while (0)

__global__ __launch_bounds__(256, 3) void attn_kernel(
    const short* __restrict__ qb, const short* __restrict__ kb,
    const short* __restrict__ vt, const short* __restrict__ maskb,
    short* __restrict__ ao)
{
    __shared__ __align__(16) short Kb[2][8192];   // K tiles [128][64], dbuf
    __shared__ __align__(16) short Vb[8192];      // V tile  [64][128], single
    __shared__ __align__(16) short Msk[2048];     // bf16 log2-bias, this b

    const int t = threadIdx.x;
    const int lane = t & 63, wid = t >> 6;
    const int quad = lane >> 4, l16 = lane & 15;
    const int qg = wid >> 1, kg = wid & 1;        // 2x2 hybrid split
    // XCD swizzle: XCD = id%8 owns bh in {xcd, xcd+8, xcd+16}
    const int id = blockIdx.x;
    const int idx = id >> 3;
    const int bh = (id & 7) + ((idx % 3) << 3);
    const int q0 = (idx / 3) << 6;
    const int b = bh / NH, h = bh - b * NH;
    const size_t hoff = (size_t)bh * NSEQ * HD;
    const short* qp = qb + hoff;     // [N][64]  (q pre-scaled by 0.125*log2e)
    const short* kp = kb + hoff;     // [N][64]
    const short* vp = vt + hoff;     // [64][N]
    const int qrow4 = quad * 4;

    int rK[4], cK[4], dV[4], cV[4];
    #pragma unroll
    for (int j = 0; j < 4; ++j) {
        int o = wid * 4096 + j * 1024 + lane * 16;
        rK[j] = o >> 7;
        cK[j] = ((o >> 4) & 7) ^ (rK[j] & 7);
        dV[j] = o >> 8;
        cV[j] = ((o >> 4) & 15) ^ (dV[j] & 15);
    }
    const int r7 = l16 & 7;
    const int kc0 = ((quad     ^ r7) << 3);
    const int kc1 = (((quad+4) ^ r7) << 3);
    const int qh = quad >> 1;
    const int vsub = (quad & 1) * 4;

    // Wave's 32 q rows: q0 + qg*32 + jq*16 + l16
    bf16x8 qf[2][2];
    {
        const short* qr = qp + (size_t)(q0 + qg*32 + l16) * HD + quad*8;
        qf[0][0] = *(const bf16x8*)qr;
        qf[0][1] = *(const bf16x8*)(qr + 32);
        qf[1][0] = *(const bf16x8*)(qr + 16*HD);
        qf[1][1] = *(const bf16x8*)(qr + 16*HD + 32);
    }

    const short one_ = (short)0x3F80;             // bf16 1.0
    const bf16x8 onesv = { one_, one_, one_, one_, one_, one_, one_, one_ };

    f32x4 o_acc[2][4] = {};
    f32x4 lacc[2] = {};
    bf16x8 pb[2][2];

    // Prologue: K tile 0 + mask row, one barrier.
    STAGE_K(0, Kb[0]);
    gll16(maskb + b * NSEQ + t * 8, Msk + wid * 512);
    __syncthreads();

    for (int kt = 0; kt < NSEQ; kt += 256) {
        STAGE_V(kt);
        STAGE_K(kt + 128, Kb[1]);
        QKBODY(kt, Kb[0]);
        __syncthreads();          // V(kt) staged + all QK reads of Kb[0] done
        PVBODY();
        __syncthreads();          // PV reads of Vb done -> safe to overwrite

        STAGE_V(kt + 128);
        if (kt + 256 < NSEQ) STAGE_K(kt + 256, Kb[0]);
        QKBODY(kt + 128, Kb[1]);
        __syncthreads();
        PVBODY();
        __syncthreads();
    }

    // Epilogue: combine kg=0/kg=1 partials (disjoint key halves) via LDS.
    // After the final barrier no staging is in flight; Kb is free scratch.
    f32x4* red = (f32x4*)Kb;
    const int rbase = (qg*64 + lane) * 9;
    if (kg == 1) {
        #pragma unroll
        for (int jq = 0; jq < 2; ++jq)
            #pragma unroll
            for (int it = 0; it < 4; ++it)
                red[rbase + jq*4 + it] = o_acc[jq][it];
        f32x4 lv = { lacc[0][0], lacc[1][0], 0.f, 0.f };
        red[rbase + 8] = lv;
    }
    __syncthreads();
    if (kg == 0) {
        f32x4 lv = red[rbase + 8];
        const float inv0 = 1.0f / (lacc[0][0] + lv[0]);
        const float inv1 = 1.0f / (lacc[1][0] + lv[1]);
        #pragma unroll
        for (int jq = 0; jq < 2; ++jq) {
            const float inv = jq ? inv1 : inv0;
            const int tok = b * NSEQ + q0 + qg*32 + jq*16 + l16;
            short* dst = ao + (size_t)tok * CDIM + h * HD + qrow4;
            #pragma unroll
            for (int it = 0; it < 4; ++it) {
                f32x4 o_ = o_acc[jq][it];
                f32x4 r_ = red[rbase + jq*4 + it];
                short4v o = { f2b((o_[0] + r_[0]) * inv),
                              f2b((o_[1] + r_[1]) * inv),
                              f2b((o_[2] + r_[2]) * inv),
                              f2b((o_[3] + r_[3]) * inv) };
                *(short4v*)(dst + it*16) = o;
            }
        }
    }
}

// ---------------------------------------------------------------------------
// GEMM2 (m97-style, round-8 verbatim)
// ---------------------------------------------------------------------------
__global__ __launch_bounds__(256) void gemm_proj(
    const short* __restrict__ A /*wpt[768][768]*/,
    const short* __restrict__ B /*ao [4096][768]*/,
    const float* __restrict__ bias, float* __restrict__ out)
{
    __shared__ short As[128 * 32];
    __shared__ short Bs[128 * 32];
    const int t = threadIdx.x;
    const int lane = t & 63, wid = t >> 6;
    const int quad = lane >> 4, l16 = lane & 15;
    const int wA = wid >> 1, wB = wid & 1;
    const int n0 = blockIdx.x * 128;
    const int m0 = blockIdx.y * 128;

    const int srow = wid * 16 + (lane >> 2), schunk = (lane & 3) * 8;
    const short* ag0 = A + (size_t)(n0 + srow) * CDIM + schunk;
    const short* ag1 = ag0 + (size_t)64 * CDIM;
    const short* bg0 = B + (size_t)(m0 + srow) * CDIM + schunk;
    const short* bg1 = bg0 + (size_t)64 * CDIM;
    short* asl0 = &As[(wid * 16) * 32];
    short* asl1 = &As[(wid * 16 + 64) * 32];
    short* bsl0 = &Bs[(wid * 16) * 32];
    short* bsl1 = &Bs[(wid * 16 + 64) * 32];

    f32x4 acc[4][4] = {};
    for (int k0 = 0; k0 < CDIM; k0 += 32) {
        __syncthreads();
        gll16(ag0 + k0, asl0);
        gll16(ag1 + k0, asl1);
        gll16(bg0 + k0, bsl0);
        gll16(bg1 + k0, bsl1);
        __syncthreads();
        bf16x8 af[4], bf[4];
        #pragma unroll
        for (int i = 0; i < 4; ++i)
            af[i] = *(const bf16x8*)&As[(wA*64 + i*16 + l16) * 32 + quad*8];
        #pragma unroll
        for (int j = 0; j < 4; ++j)
            bf[j] = *(const bf16x8*)&Bs[(wB*64 + j*16 + l16) * 32 + quad*8];
        #pragma unroll
        for (int i = 0; i < 4; ++i)
            #pragma unroll
            for (int j = 0; j < 4; ++j)
                acc[i][j] = MFMA16(af[i], bf[j], acc[i][j]);
    }

    #pragma unroll
    for (int i = 0; i < 4; ++i) {
        int col0 = n0 + wA*64 + i*16 + quad*4;
        float4 bias4 = *(const float4*)&bias[col0];
        #pragma unroll
        for (int j = 0; j < 4; ++j) {
            int tok = m0 + wB*64 + j*16 + l16;
            float4 o = { acc[i][j][0] + bias4.x, acc[i][j][1] + bias4.y,
                         acc[i][j][2] + bias4.z, acc[i][j][3] + bias4.w };
            *(float4*)(out + (size_t)tok * CDIM + col0) = o;
        }
    }
}

extern "C" void kernel_launch(void* const* d_in, const int* in_sizes, int n_in,
                              void* d_out, int out_size, void* d_ws, size_t ws_size,
                              hipStream_t stream)
{
    const float* x      = (const float*)d_in[0];
    const int*   mask   = (const int*)d_in[1];
    const float* w_qkv  = (const float*)d_in[2];
    const float* w_proj = (const float*)d_in[3];
    const float* b_proj = (const float*)d_in[4];
    float* out = (float*)d_out;

    const size_t SZ = (size_t)NTOK * CDIM;       // 3,145,728
    short* xb  = (short*)d_ws;                   // [4096][768]
    short* wqt = xb  + SZ;                       // [2304][768]
    short* wpt = wqt + (size_t)QKV_COLS * CDIM;  // [768][768]
    short* qb  = wpt + (size_t)CDIM * CDIM;      // [BH][N][64]  (pre-scaled q)
    short* kb  = qb  + SZ;                       // [BH][N][64]
    short* vt  = kb  + SZ;                       // [BH][64][N]
    short* ao  = vt  + SZ;                       // [4096][768]
    short* maskb = ao + SZ;                      // [B][N] bf16 log2-bias

    dim3 blk(256);
    prep_kernel<<<dim3(5378), blk, 0, stream>>>(x, w_qkv, w_proj, mask,
                                                xb, wqt, wpt, maskb);
    gemm_qkv<<<dim3(QKV_COLS/128, NTOK/128), blk, 0, stream>>>(wqt, xb, qb, kb, vt);
    attn_kernel<<<dim3(NBLK), blk, 0, stream>>>(qb, kb, vt, maskb, ao);
    gemm_proj<<<dim3(CDIM/128, NTOK/128), blk, 0, stream>>>(wpt, ao, b_proj, out);
}

// Round 7
// 158.950 us; speedup vs baseline: 1.7233x; 1.0044x over previous
//
#include <hip/hip_runtime.h>
#include <cstdint>

#define NB 2
#define NSEQ 2048
#define CDIM 768
#define NH 12
#define HD 64
#define NTOK (NB*NSEQ)        // 4096
#define QKV_COLS (3*CDIM)     // 2304
#define NBLK ((NSEQ/64)*NH*NB) // 768 attn blocks

typedef short bf16x8 __attribute__((ext_vector_type(8)));
typedef short bf16x4 __attribute__((ext_vector_type(4)));
typedef float f32x4  __attribute__((ext_vector_type(4)));
typedef short short4v __attribute__((ext_vector_type(4)));
typedef unsigned int uint4v __attribute__((ext_vector_type(4)));

#define MFMA16(a,b,c) __builtin_amdgcn_mfma_f32_16x16x32_bf16(a,b,c,0,0,0)

__device__ __forceinline__ short f2b(float f) {
    uint32_t u = __builtin_bit_cast(uint32_t, f);
    u += 0x7fffu + ((u >> 16) & 1u);
    return (short)(u >> 16);
}
__device__ __forceinline__ float b2f(short s) {
    return __builtin_bit_cast(float, (uint32_t)((uint32_t)(unsigned short)s << 16));
}
__device__ __forceinline__ unsigned pack2(float a, float b) {
    unsigned ua = __builtin_bit_cast(unsigned, a) + 0x7fffu;
    unsigned ub = __builtin_bit_cast(unsigned, b) + 0x7fffu;
    return __builtin_amdgcn_perm(ub, ua, 0x07060302u);
}
// 2^x on the trans pipe; q is pre-scaled by 0.125*log2(e) so exp2(s)==exp(qk/8).
__device__ __forceinline__ float fexp2(float x) {
#if __has_builtin(__builtin_amdgcn_exp2f)
    return __builtin_amdgcn_exp2f(x);
#else
    return __expf(x * 0.69314718055994531f);
#endif
}
__device__ __forceinline__ void gll16(const short* g, short* l) {
    __builtin_amdgcn_global_load_lds(
        (const __attribute__((address_space(1))) unsigned int*)g,
        (__attribute__((address_space(3))) unsigned int*)l, 16, 0, 0);
}

// ---------------------------------------------------------------------------
// Merged prep: x fp32->bf16 (blocks 0..3071), w_qkv transpose (..4799),
// w_proj transpose (..5375), mask int->bf16 LOG2-BIAS (5376..5377):
//   attend -> 0.0, masked -> -16384.0 (bf16 0xC680). exp2(s-16384) == +0
//   exactly, so masked keys contribute exactly 0 (matches exp(s)*0).
// ---------------------------------------------------------------------------
__global__ __launch_bounds__(256) void prep_kernel(
    const float* __restrict__ x, const float* __restrict__ w_qkv,
    const float* __restrict__ w_proj, const int* __restrict__ mask,
    short* __restrict__ xb, short* __restrict__ wqt, short* __restrict__ wpt,
    short* __restrict__ maskb)
{
    __shared__ float tile[32][33];
    const int bid = blockIdx.x, t = threadIdx.x;
    if (bid < 3072) {
        int i = bid * 256 + t;
        float4 v = ((const float4*)x)[i];
        short4v o = { f2b(v.x), f2b(v.y), f2b(v.z), f2b(v.w) };
        ((short4v*)xb)[i] = o;
        return;
    }
    if (bid >= 5376) {
        int i = ((bid - 5376) << 11) + (t << 3);   // 2 blocks x 2048 values
        int4 a = *(const int4*)(mask + i);
        int4 c = *(const int4*)(mask + i + 4);
        const short NEG = (short)0xC680;           // bf16 -16384.0
        short4v o0 = { a.x ? (short)0 : NEG, a.y ? (short)0 : NEG,
                       a.z ? (short)0 : NEG, a.w ? (short)0 : NEG };
        short4v o1 = { c.x ? (short)0 : NEG, c.y ? (short)0 : NEG,
                       c.z ? (short)0 : NEG, c.w ? (short)0 : NEG };
        *(short4v*)(maskb + i) = o0;
        *(short4v*)(maskb + i + 4) = o1;
        return;
    }
    const float* w; short* wt; int K, NC, n0, k0;
    if (bid < 3072 + 1728) {
        int r = bid - 3072;
        w = w_qkv; wt = wqt; K = CDIM; NC = QKV_COLS;
        n0 = (r % 72) * 32; k0 = (r / 72) * 32;
    } else {
        int r = bid - 4800;
        w = w_proj; wt = wpt; K = CDIM; NC = CDIM;
        n0 = (r % 24) * 32; k0 = (r / 24) * 32;
    }
    #pragma unroll
    for (int i = 0; i < 4; ++i) {
        int idx = t + i * 256; int r = idx >> 5, c = idx & 31;
        tile[r][c] = w[(size_t)(k0 + r) * NC + n0 + c];
    }
    __syncthreads();
    #pragma unroll
    for (int i = 0; i < 4; ++i) {
        int idx = t + i * 256; int r = idx >> 5, c = idx & 31;
        wt[(size_t)(n0 + r) * K + k0 + c] = f2b(tile[c][r]);
    }
}

// ---------------------------------------------------------------------------
// GEMM1 (m97-style). Epilogue: q is PRE-SCALED by 0.125*log2(e) so the attn
// kernel can use raw v_exp (2^x) with no per-element multiply.
// ---------------------------------------------------------------------------
__global__ __launch_bounds__(256) void gemm_qkv(
    const short* __restrict__ A /*wqt[2304][768]*/,
    const short* __restrict__ B /*xb [4096][768]*/,
    short* __restrict__ qb, short* __restrict__ kb, short* __restrict__ vt)
{
    __shared__ short As[128 * 32];
    __shared__ short Bs[128 * 32];
    const int t = threadIdx.x;
    const int lane = t & 63, wid = t >> 6;
    const int quad = lane >> 4, l16 = lane & 15;
    const int wA = wid >> 1, wB = wid & 1;
    const int n0 = blockIdx.x * 128;
    const int m0 = blockIdx.y * 128;

    const int srow = wid * 16 + (lane >> 2), schunk = (lane & 3) * 8;
    const short* ag0 = A + (size_t)(n0 + srow) * CDIM + schunk;
    const short* ag1 = ag0 + (size_t)64 * CDIM;
    const short* bg0 = B + (size_t)(m0 + srow) * CDIM + schunk;
    const short* bg1 = bg0 + (size_t)64 * CDIM;
    short* asl0 = &As[(wid * 16) * 32];
    short* asl1 = &As[(wid * 16 + 64) * 32];
    short* bsl0 = &Bs[(wid * 16) * 32];
    short* bsl1 = &Bs[(wid * 16 + 64) * 32];

    f32x4 acc[4][4] = {};
    for (int k0 = 0; k0 < CDIM; k0 += 32) {
        __syncthreads();
        gll16(ag0 + k0, asl0);
        gll16(ag1 + k0, asl1);
        gll16(bg0 + k0, bsl0);
        gll16(bg1 + k0, bsl1);
        __syncthreads();
        bf16x8 af[4], bf[4];
        #pragma unroll
        for (int i = 0; i < 4; ++i)
            af[i] = *(const bf16x8*)&As[(wA*64 + i*16 + l16) * 32 + quad*8];
        #pragma unroll
        for (int j = 0; j < 4; ++j)
            bf[j] = *(const bf16x8*)&Bs[(wB*64 + j*16 + l16) * 32 + quad*8];
        #pragma unroll
        for (int i = 0; i < 4; ++i)
            #pragma unroll
            for (int j = 0; j < 4; ++j)
                acc[i][j] = MFMA16(af[i], bf[j], acc[i][j]);
    }

    const int colbase = n0 + wA * 64;
    const int s = colbase / CDIM;
    const int h = (colbase - s * CDIM) >> 6;
    const int b = m0 >> 11;
    const size_t bh = (size_t)(b * NH + h);
    // fold softmax scale AND log2(e) into q: exp(qk/8) == exp2(qk*qsc)
    const float qsc = (s == 0) ? 0.18033688011112042f : 1.0f;
    #pragma unroll
    for (int i = 0; i < 4; ++i) {
        const int d0 = i*16 + quad*4;
        #pragma unroll
        for (int j = 0; j < 4; ++j) {
            int tok = (m0 + wB*64 + j*16 + l16) & (NSEQ - 1);
            if (s < 2) {
                short* dst = (s == 0 ? qb : kb) + (bh * NSEQ + tok) * HD + d0;
                short4v o = { f2b(acc[i][j][0] * qsc), f2b(acc[i][j][1] * qsc),
                              f2b(acc[i][j][2] * qsc), f2b(acc[i][j][3] * qsc) };
                *(short4v*)dst = o;
            } else {
                short* dst = vt + (bh * HD + d0) * NSEQ + tok;
                #pragma unroll
                for (int r = 0; r < 4; ++r)
                    dst[(size_t)r * NSEQ] = f2b(acc[i][j][r]);
            }
        }
    }
}

// ---------------------------------------------------------------------------
// Flash attention v15 = v14 (2x2 hybrid split, 3 blocks/CU) + COUNTED-VMCNT
// barriers (T4). The compiler's __syncthreads emits s_waitcnt vmcnt(0),
// forcing the NEXT tile's K-prefetch (issued just before QKBODY, ~0 slack)
// to land before PV starts -- the classic barrier-drain tax. New scheme:
//   barrier A (pre-PV):  s_waitcnt vmcnt(4) -> V(cur) landed (oldest 4),
//                        K(next) keeps floating across the barrier.
//   barrier B (post-PV): s_waitcnt vmcnt(0) -> K(next) landed, but it now
//                        had QK+PV (a full half-tile) to land => ~0 stall.
//                        Also the cross-wave guarantee next QKBODY needs.
// sched_barrier(0) pins STAGE_V-before-STAGE_K issue order (vmcnt counts
// depend on it); "memory" clobbers stop LDS-read hoisting across raw
// barriers. STAGE_K is UNCONDITIONAL (wraparound) so per-wave outstanding
// counts stay uniform (a skipped last STAGE_K would turn vmcnt(4) into a
// no-op and race on the final V tile). Epilogue red-scratch in Kb is safe:
// barrier B' carries vmcnt(0), so wraparound staging lands before overwrite.
// T5: setprio(1) around PVBODY's MFMA cluster (waves now desync -> the
// scheduler has something to arbitrate; attn +4-7% per m191).
// ---------------------------------------------------------------------------
#define STAGE_K(KT, BUF) do {                                                    \
    short* kb_ = (BUF);                                                          \
    _Pragma("unroll")                                                            \
    for (int j = 0; j < 4; ++j)                                                  \
        gll16(kp + (size_t)((KT) + rK[j]) * HD + cK[j]*8,                        \
              kb_ + wid*2048 + j*512);                                           \
} while (0)

#define STAGE_V(KT) do {                                                         \
    _Pragma("unroll")                                                            \
    for (int j = 0; j < 4; ++j)                                                  \
        gll16(vp + (size_t)dV[j] * NSEQ + (KT) + cV[j]*8,                        \
              Vb + wid*2048 + j*512);                                            \
} while (0)

// Wave computes S^T for its 64 keys (kg half, subtiles paired ks/ks+2 i.e.
// rows +0/+32) x its 32 q rows (jq=0,1). S-acc INITIALIZED with mask bias.
#define QKBODY(KT, KBUF) do {                                                    \
    const short* KsB_ = (KBUF) + kg*4096;                                        \
    _Pragma("unroll")                                                            \
    for (int ks = 0; ks < 2; ++ks) {                                             \
        short4v mi0_ = *(const short4v*)&Msk[(KT) + kg*64 + ks*16 + qrow4];      \
        short4v mi1_ = *(const short4v*)&Msk[(KT) + kg*64 + 32 + ks*16 + qrow4]; \
        const int kro_ = (ks*16 + l16) * 64;                                     \
        bf16x8 kf00_ = *(const bf16x8*)&KsB_[kro_ + kc0];                        \
        bf16x8 kf01_ = *(const bf16x8*)&KsB_[kro_ + kc1];                        \
        bf16x8 kf10_ = *(const bf16x8*)&KsB_[2048 + kro_ + kc0];                 \
        bf16x8 kf11_ = *(const bf16x8*)&KsB_[2048 + kro_ + kc1];                 \
        f32x4 m0v_ = { b2f(mi0_[0]), b2f(mi0_[1]),                               \
                       b2f(mi0_[2]), b2f(mi0_[3]) };                             \
        f32x4 m1v_ = { b2f(mi1_[0]), b2f(mi1_[1]),                               \
                       b2f(mi1_[2]), b2f(mi1_[3]) };                             \
        _Pragma("unroll")                                                        \
        for (int jq = 0; jq < 2; ++jq) {                                         \
            f32x4 s0_ = m0v_, s1_ = m1v_;                                        \
            s0_ = MFMA16(kf00_, qf[jq][0], s0_);                                 \
            s0_ = MFMA16(kf01_, qf[jq][1], s0_);                                 \
            s1_ = MFMA16(kf10_, qf[jq][0], s1_);                                 \
            s1_ = MFMA16(kf11_, qf[jq][1], s1_);                                 \
            float e0 = fexp2(s0_[0]);                                            \
            float e1 = fexp2(s0_[1]);                                            \
            float e2 = fexp2(s0_[2]);                                            \
            float e3 = fexp2(s0_[3]);                                            \
            float f0 = fexp2(s1_[0]);                                            \
            float f1 = fexp2(s1_[1]);                                            \
            float f2 = fexp2(s1_[2]);                                            \
            float f3 = fexp2(s1_[3]);                                            \
            uint4v pk_ = { pack2(e0, e1), pack2(e2, e3),                         \
                           pack2(f0, f1), pack2(f2, f3) };                       \
            pb[jq][ks] = __builtin_bit_cast(bf16x8, pk_);                        \
        }                                                                        \
    }                                                                            \
} while (0)

// PV + denominator over the wave's 64 keys. V fragments shared by both jq.
#define PVBODY() do {                                                            \
    _Pragma("unroll")                                                            \
    for (int ks = 0; ks < 2; ++ks) {                                             \
        lacc[0] = MFMA16(onesv, pb[0][ks], lacc[0]);                             \
        lacc[1] = MFMA16(onesv, pb[1][ks], lacc[1]);                             \
    }                                                                            \
    _Pragma("unroll")                                                            \
    for (int it = 0; it < 4; ++it) {                                             \
        const int vrow_ = (it*16 + l16) * 128;                                   \
        _Pragma("unroll")                                                        \
        for (int ks = 0; ks < 2; ++ks) {                                         \
            const int gl_ = (((kg*8 + ks*2 + qh) ^ l16) << 3) + vsub;            \
            const int gh_ = (((kg*8 + 4 + ks*2 + qh) ^ l16) << 3) + vsub;        \
            bf16x4 lo_ = *(const bf16x4*)&Vb[vrow_ + gl_];                       \
            bf16x4 hi_ = *(const bf16x4*)&Vb[vrow_ + gh_];                       \
            bf16x8 vf_ = __builtin_shufflevector(lo_, hi_, 0,1,2,3,4,5,6,7);     \
            o_acc[0][it] = MFMA16(vf_, pb[0][ks], o_acc[0][it]);                 \
            o_acc[1][it] = MFMA16(vf_, pb[1][ks], o_acc[1][it]);                 \
        }                                                                        \
    }                                                                            \
} while (0)

#define WAITV_BAR() do {                                                         \
    asm volatile("s_waitcnt vmcnt(4)" ::: "memory");                             \
    __builtin_amdgcn_sched_barrier(0);                                           \
    __builtin_amdgcn_s_barrier();                                                \
} while (0)

#define WAITK_BAR() do {                                                         \
    asm volatile("s_waitcnt vmcnt(0)" ::: "memory");                             \
    __builtin_amdgcn_sched_barrier(0);                                           \
    __builtin_amdgcn_s_barrier();                                                \
} while (0)

__global__ __launch_bounds__(256, 3) void attn_kernel(
    const short* __restrict__ qb, const short* __restrict__ kb,
    const short* __restrict__ vt, const short* __restrict__ maskb,
    short* __restrict__ ao)
{
    __shared__ __align__(16) short Kb[2][8192];   // K tiles [128][64], dbuf
    __shared__ __align__(16) short Vb[8192];      // V tile  [64][128], single
    __shared__ __align__(16) short Msk[2048];     // bf16 log2-bias, this b

    const int t = threadIdx.x;
    const int lane = t & 63, wid = t >> 6;
    const int quad = lane >> 4, l16 = lane & 15;
    const int qg = wid >> 1, kg = wid & 1;        // 2x2 hybrid split
    // XCD swizzle: XCD = id%8 owns bh in {xcd, xcd+8, xcd+16}
    const int id = blockIdx.x;
    const int idx = id >> 3;
    const int bh = (id & 7) + ((idx % 3) << 3);
    const int q0 = (idx / 3) << 6;
    const int b = bh / NH, h = bh - b * NH;
    const size_t hoff = (size_t)bh * NSEQ * HD;
    const short* qp = qb + hoff;     // [N][64]  (q pre-scaled by 0.125*log2e)
    const short* kp = kb + hoff;     // [N][64]
    const short* vp = vt + hoff;     // [64][N]
    const int qrow4 = quad * 4;

    int rK[4], cK[4], dV[4], cV[4];
    #pragma unroll
    for (int j = 0; j < 4; ++j) {
        int o = wid * 4096 + j * 1024 + lane * 16;
        rK[j] = o >> 7;
        cK[j] = ((o >> 4) & 7) ^ (rK[j] & 7);
        dV[j] = o >> 8;
        cV[j] = ((o >> 4) & 15) ^ (dV[j] & 15);
    }
    const int r7 = l16 & 7;
    const int kc0 = ((quad     ^ r7) << 3);
    const int kc1 = (((quad+4) ^ r7) << 3);
    const int qh = quad >> 1;
    const int vsub = (quad & 1) * 4;

    // Wave's 32 q rows: q0 + qg*32 + jq*16 + l16
    bf16x8 qf[2][2];
    {
        const short* qr = qp + (size_t)(q0 + qg*32 + l16) * HD + quad*8;
        qf[0][0] = *(const bf16x8*)qr;
        qf[0][1] = *(const bf16x8*)(qr + 32);
        qf[1][0] = *(const bf16x8*)(qr + 16*HD);
        qf[1][1] = *(const bf16x8*)(qr + 16*HD + 32);
    }

    const short one_ = (short)0x3F80;             // bf16 1.0
    const bf16x8 onesv = { one_, one_, one_, one_, one_, one_, one_, one_ };

    f32x4 o_acc[2][4] = {};
    f32x4 lacc[2] = {};
    bf16x8 pb[2][2];

    // Prologue: K tile 0 + mask row; __syncthreads drains vmcnt(0).
    STAGE_K(0, Kb[0]);
    gll16(maskb + b * NSEQ + t * 8, Msk + wid * 512);
    __syncthreads();

    for (int kt = 0; kt < NSEQ; kt += 256) {
        STAGE_V(kt);
        __builtin_amdgcn_sched_barrier(0);
        STAGE_K(kt + 128, Kb[1]);
        __builtin_amdgcn_sched_barrier(0);
        QKBODY(kt, Kb[0]);
        WAITV_BAR();              // A: V(kt) visible; K(kt+128) floats
        __builtin_amdgcn_s_setprio(1);
        PVBODY();
        __builtin_amdgcn_s_setprio(0);
        WAITK_BAR();              // B: K(kt+128) visible; Vb free

        STAGE_V(kt + 128);
        __builtin_amdgcn_sched_barrier(0);
        STAGE_K((kt + 256) & (NSEQ - 1), Kb[0]);
        __builtin_amdgcn_sched_barrier(0);
        QKBODY(kt + 128, Kb[1]);
        WAITV_BAR();              // A'
        __builtin_amdgcn_s_setprio(1);
        PVBODY();
        __builtin_amdgcn_s_setprio(0);
        WAITK_BAR();              // B'
    }

    // Epilogue: combine kg=0/kg=1 partials (disjoint key halves) via LDS.
    // Barrier B' carried vmcnt(0) -> wraparound staging landed; Kb is free.
    f32x4* red = (f32x4*)Kb;
    const int rbase = (qg*64 + lane) * 9;
    if (kg == 1) {
        #pragma unroll
        for (int jq = 0; jq < 2; ++jq)
            #pragma unroll
            for (int it = 0; it < 4; ++it)
                red[rbase + jq*4 + it] = o_acc[jq][it];
        f32x4 lv = { lacc[0][0], lacc[1][0], 0.f, 0.f };
        red[rbase + 8] = lv;
    }
    __syncthreads();
    if (kg == 0) {
        f32x4 lv = red[rbase + 8];
        const float inv0 = 1.0f / (lacc[0][0] + lv[0]);
        const float inv1 = 1.0f / (lacc[1][0] + lv[1]);
        #pragma unroll
        for (int jq = 0; jq < 2; ++jq) {
            const float inv = jq ? inv1 : inv0;
            const int tok = b * NSEQ + q0 + qg*32 + jq*16 + l16;
            short* dst = ao + (size_t)tok * CDIM + h * HD + qrow4;
            #pragma unroll
            for (int it = 0; it < 4; ++it) {
                f32x4 o_ = o_acc[jq][it];
                f32x4 r_ = red[rbase + jq*4 + it];
                short4v o = { f2b((o_[0] + r_[0]) * inv),
                              f2b((o_[1] + r_[1]) * inv),
                              f2b((o_[2] + r_[2]) * inv),
                              f2b((o_[3] + r_[3]) * inv) };
                *(short4v*)(dst + it*16) = o;
            }
        }
    }
}

// ---------------------------------------------------------------------------
// GEMM2 (m97-style, round-8 verbatim)
// ---------------------------------------------------------------------------
__global__ __launch_bounds__(256) void gemm_proj(
    const short* __restrict__ A /*wpt[768][768]*/,
    const short* __restrict__ B /*ao [4096][768]*/,
    const float* __restrict__ bias, float* __restrict__ out)
{
    __shared__ short As[128 * 32];
    __shared__ short Bs[128 * 32];
    const int t = threadIdx.x;
    const int lane = t & 63, wid = t >> 6;
    const int quad = lane >> 4, l16 = lane & 15;
    const int wA = wid >> 1, wB = wid & 1;
    const int n0 = blockIdx.x * 128;
    const int m0 = blockIdx.y * 128;

    const int srow = wid * 16 + (lane >> 2), schunk = (lane & 3) * 8;
    const short* ag0 = A + (size_t)(n0 + srow) * CDIM + schunk;
    const short* ag1 = ag0 + (size_t)64 * CDIM;
    const short* bg0 = B + (size_t)(m0 + srow) * CDIM + schunk;
    const short* bg1 = bg0 + (size_t)64 * CDIM;
    short* asl0 = &As[(wid * 16) * 32];
    short* asl1 = &As[(wid * 16 + 64) * 32];
    short* bsl0 = &Bs[(wid * 16) * 32];
    short* bsl1 = &Bs[(wid * 16 + 64) * 32];

    f32x4 acc[4][4] = {};
    for (int k0 = 0; k0 < CDIM; k0 += 32) {
        __syncthreads();
        gll16(ag0 + k0, asl0);
        gll16(ag1 + k0, asl1);
        gll16(bg0 + k0, bsl0);
        gll16(bg1 + k0, bsl1);
        __syncthreads();
        bf16x8 af[4], bf[4];
        #pragma unroll
        for (int i = 0; i < 4; ++i)
            af[i] = *(const bf16x8*)&As[(wA*64 + i*16 + l16) * 32 + quad*8];
        #pragma unroll
        for (int j = 0; j < 4; ++j)
            bf[j] = *(const bf16x8*)&Bs[(wB*64 + j*16 + l16) * 32 + quad*8];
        #pragma unroll
        for (int i = 0; i < 4; ++i)
            #pragma unroll
            for (int j = 0; j < 4; ++j)
                acc[i][j] = MFMA16(af[i], bf[j], acc[i][j]);
    }

    #pragma unroll
    for (int i = 0; i < 4; ++i) {
        int col0 = n0 + wA*64 + i*16 + quad*4;
        float4 bias4 = *(const float4*)&bias[col0];
        #pragma unroll
        for (int j = 0; j < 4; ++j) {
            int tok = m0 + wB*64 + j*16 + l16;
            float4 o = { acc[i][j][0] + bias4.x, acc[i][j][1] + bias4.y,
                         acc[i][j][2] + bias4.z, acc[i][j][3] + bias4.w };
            *(float4*)(out + (size_t)tok * CDIM + col0) = o;
        }
    }
}

extern "C" void kernel_launch(void* const* d_in, const int* in_sizes, int n_in,
                              void* d_out, int out_size, void* d_ws, size_t ws_size,
                              hipStream_t stream)
{
    const float* x      = (const float*)d_in[0];
    const int*   mask   = (const int*)d_in[1];
    const float* w_qkv  = (const float*)d_in[2];
    const float* w_proj = (const float*)d_in[3];
    const float* b_proj = (const float*)d_in[4];
    float* out = (float*)d_out;

    const size_t SZ = (size_t)NTOK * CDIM;       // 3,145,728
    short* xb  = (short*)d_ws;                   // [4096][768]
    short* wqt = xb  + SZ;                       // [2304][768]
    short* wpt = wqt + (size_t)QKV_COLS * CDIM;  // [768][768]
    short* qb  = wpt + (size_t)CDIM * CDIM;      // [BH][N][64]  (pre-scaled q)
    short* kb  = qb  + SZ;                       // [BH][N][64]
    short* vt  = kb  + SZ;                       // [BH][64][N]
    short* ao  = vt  + SZ;                       // [4096][768]
    short* maskb = ao + SZ;                      // [B][N] bf16 log2-bias

    dim3 blk(256);
    prep_kernel<<<dim3(5378), blk, 0, stream>>>(x, w_qkv, w_proj, mask,
                                                xb, wqt, wpt, maskb);
    gemm_qkv<<<dim3(QKV_COLS/128, NTOK/128), blk, 0, stream>>>(wqt, xb, qb, kb, vt);
    attn_kernel<<<dim3(NBLK), blk, 0, stream>>>(qb, kb, vt, maskb, ao);
    gemm_proj<<<dim3(CDIM/128, NTOK/128), blk, 0, stream>>>(wpt, ao, b_proj, out);
}

// Round 9
// 158.578 us; speedup vs baseline: 1.7273x; 1.0023x over previous
//
#include <hip/hip_runtime.h>
#include <cstdint>

#define NB 2
#define NSEQ 2048
#define CDIM 768
#define NH 12
#define HD 64
#define NTOK (NB*NSEQ)        // 4096
#define QKV_COLS (3*CDIM)     // 2304
#define NBLK ((NSEQ/64)*NH*NB) // 768 attn blocks

typedef short bf16x8 __attribute__((ext_vector_type(8)));
typedef short bf16x4 __attribute__((ext_vector_type(4)));
typedef float f32x4  __attribute__((ext_vector_type(4)));
typedef short short4v __attribute__((ext_vector_type(4)));
typedef unsigned int uint4v __attribute__((ext_vector_type(4)));

#define MFMA16(a,b,c) __builtin_amdgcn_mfma_f32_16x16x32_bf16(a,b,c,0,0,0)

__device__ __forceinline__ short f2b(float f) {
    uint32_t u = __builtin_bit_cast(uint32_t, f);
    u += 0x7fffu + ((u >> 16) & 1u);
    return (short)(u >> 16);
}
__device__ __forceinline__ float b2f(short s) {
    return __builtin_bit_cast(float, (uint32_t)((uint32_t)(unsigned short)s << 16));
}
__device__ __forceinline__ unsigned pack2(float a, float b) {
    unsigned ua = __builtin_bit_cast(unsigned, a) + 0x7fffu;
    unsigned ub = __builtin_bit_cast(unsigned, b) + 0x7fffu;
    return __builtin_amdgcn_perm(ub, ua, 0x07060302u);
}
// 2^x on the trans pipe; q is pre-scaled by 0.125*log2(e) so exp2(s)==exp(qk/8).
__device__ __forceinline__ float fexp2(float x) {
#if __has_builtin(__builtin_amdgcn_exp2f)
    return __builtin_amdgcn_exp2f(x);
#else
    return __expf(x * 0.69314718055994531f);
#endif
}
__device__ __forceinline__ void gll16(const short* g, short* l) {
    __builtin_amdgcn_global_load_lds(
        (const __attribute__((address_space(1))) unsigned int*)g,
        (__attribute__((address_space(3))) unsigned int*)l, 16, 0, 0);
}

// ---------------------------------------------------------------------------
// Merged prep: x fp32->bf16 (blocks 0..3071), w_qkv transpose (..4799),
// w_proj transpose (..5375), mask int->bf16 LOG2-BIAS (5376..5377).
// Transpose tile reads/writes vectorized (float4 in, short4 out).
// ---------------------------------------------------------------------------
__global__ __launch_bounds__(256) void prep_kernel(
    const float* __restrict__ x, const float* __restrict__ w_qkv,
    const float* __restrict__ w_proj, const int* __restrict__ mask,
    short* __restrict__ xb, short* __restrict__ wqt, short* __restrict__ wpt,
    short* __restrict__ maskb)
{
    __shared__ float tile[32][33];
    const int bid = blockIdx.x, t = threadIdx.x;
    if (bid < 3072) {
        int i = bid * 256 + t;
        float4 v = ((const float4*)x)[i];
        short4v o = { f2b(v.x), f2b(v.y), f2b(v.z), f2b(v.w) };
        ((short4v*)xb)[i] = o;
        return;
    }
    if (bid >= 5376) {
        int i = ((bid - 5376) << 11) + (t << 3);   // 2 blocks x 2048 values
        int4 a = *(const int4*)(mask + i);
        int4 c = *(const int4*)(mask + i + 4);
        const short NEG = (short)0xC680;           // bf16 -16384.0
        short4v o0 = { a.x ? (short)0 : NEG, a.y ? (short)0 : NEG,
                       a.z ? (short)0 : NEG, a.w ? (short)0 : NEG };
        short4v o1 = { c.x ? (short)0 : NEG, c.y ? (short)0 : NEG,
                       c.z ? (short)0 : NEG, c.w ? (short)0 : NEG };
        *(short4v*)(maskb + i) = o0;
        *(short4v*)(maskb + i + 4) = o1;
        return;
    }
    const float* w; short* wt; int K, NC, n0, k0;
    if (bid < 3072 + 1728) {
        int r = bid - 3072;
        w = w_qkv; wt = wqt; K = CDIM; NC = QKV_COLS;
        n0 = (r % 72) * 32; k0 = (r / 72) * 32;
    } else {
        int r = bid - 4800;
        w = w_proj; wt = wpt; K = CDIM; NC = CDIM;
        n0 = (r % 24) * 32; k0 = (r / 24) * 32;
    }
    const int r = t >> 3, c4 = (t & 7) * 4;
    {
        float4 v = *(const float4*)&w[(size_t)(k0 + r) * NC + n0 + c4];
        tile[r][c4 + 0] = v.x; tile[r][c4 + 1] = v.y;
        tile[r][c4 + 2] = v.z; tile[r][c4 + 3] = v.w;
    }
    __syncthreads();
    {
        short4v o = { f2b(tile[c4 + 0][r]), f2b(tile[c4 + 1][r]),
                      f2b(tile[c4 + 2][r]), f2b(tile[c4 + 3][r]) };
        *(short4v*)&wt[(size_t)(n0 + r) * K + k0 + c4] = o;
    }
}

// ---------------------------------------------------------------------------
// GEMM K-loop: DOUBLE-BUFFERED staging, ONE barrier per K-step.
// Old m97 loop (barrier; stage; barrier) drained vmcnt(0) immediately after
// issuing the loads -- full L2/HBM latency exposed per K-step. gemm_proj has
// 192 blocks = 0.75 blocks/CU (no cross-block TLP on most CUs), gemm_qkv
// 2.25/CU, so the exposure is naked. New: STAGE(next, buf^1) issued BEFORE
// compute(cur); the end-of-step __syncthreads (vmcnt(0)+lgkmcnt(0)+barrier)
// then has the whole MFMA phase as slack. Plain __syncthreads (HW-proven
// path) -- raw-asm equivalent removed after the round-8 infra failure left
// it unverified. sched_barrier(0) pins STAGE-before-compute issue order.
// LDS 16->32 KB (still >=4 blocks/CU by LDS).
// ---------------------------------------------------------------------------
#define GSTAGE(K0V, B) do {                                                      \
    gll16(ag0 + (K0V), As + (B)*4096 + (wid*16)*32);                             \
    gll16(ag1 + (K0V), As + (B)*4096 + (wid*16 + 64)*32);                        \
    gll16(bg0 + (K0V), Bs + (B)*4096 + (wid*16)*32);                             \
    gll16(bg1 + (K0V), Bs + (B)*4096 + (wid*16 + 64)*32);                        \
} while (0)

// ---------------------------------------------------------------------------
// GEMM1. Epilogue: q is PRE-SCALED by 0.125*log2(e) (exp2-fold).
// ---------------------------------------------------------------------------
__global__ __launch_bounds__(256) void gemm_qkv(
    const short* __restrict__ A /*wqt[2304][768]*/,
    const short* __restrict__ B /*xb [4096][768]*/,
    short* __restrict__ qb, short* __restrict__ kb, short* __restrict__ vt)
{
    __shared__ short As[2 * 4096];
    __shared__ short Bs[2 * 4096];
    const int t = threadIdx.x;
    const int lane = t & 63, wid = t >> 6;
    const int quad = lane >> 4, l16 = lane & 15;
    const int wA = wid >> 1, wB = wid & 1;
    const int n0 = blockIdx.x * 128;
    const int m0 = blockIdx.y * 128;

    const int srow = wid * 16 + (lane >> 2), schunk = (lane & 3) * 8;
    const short* ag0 = A + (size_t)(n0 + srow) * CDIM + schunk;
    const short* ag1 = ag0 + (size_t)64 * CDIM;
    const short* bg0 = B + (size_t)(m0 + srow) * CDIM + schunk;
    const short* bg1 = bg0 + (size_t)64 * CDIM;

    f32x4 acc[4][4] = {};
    GSTAGE(0, 0);
    __syncthreads();
    int buf = 0;
    for (int k0 = 0; k0 < CDIM; k0 += 32) {
        if (k0 + 32 < CDIM) GSTAGE(k0 + 32, buf ^ 1);
        __builtin_amdgcn_sched_barrier(0);
        const short* As_ = As + buf * 4096;
        const short* Bs_ = Bs + buf * 4096;
        bf16x8 af[4], bf[4];
        #pragma unroll
        for (int i = 0; i < 4; ++i)
            af[i] = *(const bf16x8*)&As_[(wA*64 + i*16 + l16) * 32 + quad*8];
        #pragma unroll
        for (int j = 0; j < 4; ++j)
            bf[j] = *(const bf16x8*)&Bs_[(wB*64 + j*16 + l16) * 32 + quad*8];
        #pragma unroll
        for (int i = 0; i < 4; ++i)
            #pragma unroll
            for (int j = 0; j < 4; ++j)
                acc[i][j] = MFMA16(af[i], bf[j], acc[i][j]);
        __syncthreads();          // stage(next) had the whole MFMA phase
        buf ^= 1;
    }

    const int colbase = n0 + wA * 64;
    const int s = colbase / CDIM;
    const int h = (colbase - s * CDIM) >> 6;
    const int b = m0 >> 11;
    const size_t bh = (size_t)(b * NH + h);
    // fold softmax scale AND log2(e) into q: exp(qk/8) == exp2(qk*qsc)
    const float qsc = (s == 0) ? 0.18033688011112042f : 1.0f;
    #pragma unroll
    for (int i = 0; i < 4; ++i) {
        const int d0 = i*16 + quad*4;
        #pragma unroll
        for (int j = 0; j < 4; ++j) {
            int tok = (m0 + wB*64 + j*16 + l16) & (NSEQ - 1);
            if (s < 2) {
                short* dst = (s == 0 ? qb : kb) + (bh * NSEQ + tok) * HD + d0;
                short4v o = { f2b(acc[i][j][0] * qsc), f2b(acc[i][j][1] * qsc),
                              f2b(acc[i][j][2] * qsc), f2b(acc[i][j][3] * qsc) };
                *(short4v*)dst = o;
            } else {
                short* dst = vt + (bh * HD + d0) * NSEQ + tok;
                #pragma unroll
                for (int r = 0; r < 4; ++r)
                    dst[(size_t)r * NSEQ] = f2b(acc[i][j][r]);
            }
        }
    }
}

// ---------------------------------------------------------------------------
// Flash attention v15 (byte-identical to round 7's HW-verified kernel):
// 2x2 hybrid split, 3 blocks/CU, counted-vmcnt barriers, setprio around PV.
// ---------------------------------------------------------------------------
#define STAGE_K(KT, BUF) do {                                                    \
    short* kb_ = (BUF);                                                          \
    _Pragma("unroll")                                                            \
    for (int j = 0; j < 4; ++j)                                                  \
        gll16(kp + (size_t)((KT) + rK[j]) * HD + cK[j]*8,                        \
              kb_ + wid*2048 + j*512);                                           \
} while (0)

#define STAGE_V(KT) do {                                                         \
    _Pragma("unroll")                                                            \
    for (int j = 0; j < 4; ++j)                                                  \
        gll16(vp + (size_t)dV[j] * NSEQ + (KT) + cV[j]*8,                        \
              Vb + wid*2048 + j*512);                                            \
} while (0)

#define QKBODY(KT, KBUF) do {                                                    \
    const short* KsB_ = (KBUF) + kg*4096;                                        \
    _Pragma("unroll")                                                            \
    for (int ks = 0; ks < 2; ++ks) {                                             \
        short4v mi0_ = *(const short4v*)&Msk[(KT) + kg*64 + ks*16 + qrow4];      \
        short4v mi1_ = *(const short4v*)&Msk[(KT) + kg*64 + 32 + ks*16 + qrow4]; \
        const int kro_ = (ks*16 + l16) * 64;                                     \
        bf16x8 kf00_ = *(const bf16x8*)&KsB_[kro_ + kc0];                        \
        bf16x8 kf01_ = *(const bf16x8*)&KsB_[kro_ + kc1];                        \
        bf16x8 kf10_ = *(const bf16x8*)&KsB_[2048 + kro_ + kc0];                 \
        bf16x8 kf11_ = *(const bf16x8*)&KsB_[2048 + kro_ + kc1];                 \
        f32x4 m0v_ = { b2f(mi0_[0]), b2f(mi0_[1]),                               \
                       b2f(mi0_[2]), b2f(mi0_[3]) };                             \
        f32x4 m1v_ = { b2f(mi1_[0]), b2f(mi1_[1]),                               \
                       b2f(mi1_[2]), b2f(mi1_[3]) };                             \
        _Pragma("unroll")                                                        \
        for (int jq = 0; jq < 2; ++jq) {                                         \
            f32x4 s0_ = m0v_, s1_ = m1v_;                                        \
            s0_ = MFMA16(kf00_, qf[jq][0], s0_);                                 \
            s0_ = MFMA16(kf01_, qf[jq][1], s0_);                                 \
            s1_ = MFMA16(kf10_, qf[jq][0], s1_);                                 \
            s1_ = MFMA16(kf11_, qf[jq][1], s1_);                                 \
            float e0 = fexp2(s0_[0]);                                            \
            float e1 = fexp2(s0_[1]);                                            \
            float e2 = fexp2(s0_[2]);                                            \
            float e3 = fexp2(s0_[3]);                                            \
            float f0 = fexp2(s1_[0]);                                            \
            float f1 = fexp2(s1_[1]);                                            \
            float f2 = fexp2(s1_[2]);                                            \
            float f3 = fexp2(s1_[3]);                                            \
            uint4v pk_ = { pack2(e0, e1), pack2(e2, e3),                         \
                           pack2(f0, f1), pack2(f2, f3) };                       \
            pb[jq][ks] = __builtin_bit_cast(bf16x8, pk_);                        \
        }                                                                        \
    }                                                                            \
} while (0)

#define PVBODY() do {                                                            \
    _Pragma("unroll")                                                            \
    for (int ks = 0; ks < 2; ++ks) {                                             \
        lacc[0] = MFMA16(onesv, pb[0][ks], lacc[0]);                             \
        lacc[1] = MFMA16(onesv, pb[1][ks], lacc[1]);                             \
    }                                                                            \
    _Pragma("unroll")                                                            \
    for (int it = 0; it < 4; ++it) {                                             \
        const int vrow_ = (it*16 + l16) * 128;                                   \
        _Pragma("unroll")                                                        \
        for (int ks = 0; ks < 2; ++ks) {                                         \
            const int gl_ = (((kg*8 + ks*2 + qh) ^ l16) << 3) + vsub;            \
            const int gh_ = (((kg*8 + 4 + ks*2 + qh) ^ l16) << 3) + vsub;        \
            bf16x4 lo_ = *(const bf16x4*)&Vb[vrow_ + gl_];                       \
            bf16x4 hi_ = *(const bf16x4*)&Vb[vrow_ + gh_];                       \
            bf16x8 vf_ = __builtin_shufflevector(lo_, hi_, 0,1,2,3,4,5,6,7);     \
            o_acc[0][it] = MFMA16(vf_, pb[0][ks], o_acc[0][it]);                 \
            o_acc[1][it] = MFMA16(vf_, pb[1][ks], o_acc[1][it]);                 \
        }                                                                        \
    }                                                                            \
} while (0)

#define WAITV_BAR() do {                                                         \
    asm volatile("s_waitcnt vmcnt(4)" ::: "memory");                             \
    __builtin_amdgcn_sched_barrier(0);                                           \
    __builtin_amdgcn_s_barrier();                                                \
} while (0)

#define WAITK_BAR() do {                                                         \
    asm volatile("s_waitcnt vmcnt(0)" ::: "memory");                             \
    __builtin_amdgcn_sched_barrier(0);                                           \
    __builtin_amdgcn_s_barrier();                                                \
} while (0)

__global__ __launch_bounds__(256, 3) void attn_kernel(
    const short* __restrict__ qb, const short* __restrict__ kb,
    const short* __restrict__ vt, const short* __restrict__ maskb,
    short* __restrict__ ao)
{
    __shared__ __align__(16) short Kb[2][8192];   // K tiles [128][64], dbuf
    __shared__ __align__(16) short Vb[8192];      // V tile  [64][128], single
    __shared__ __align__(16) short Msk[2048];     // bf16 log2-bias, this b

    const int t = threadIdx.x;
    const int lane = t & 63, wid = t >> 6;
    const int quad = lane >> 4, l16 = lane & 15;
    const int qg = wid >> 1, kg = wid & 1;        // 2x2 hybrid split
    // XCD swizzle: XCD = id%8 owns bh in {xcd, xcd+8, xcd+16}
    const int id = blockIdx.x;
    const int idx = id >> 3;
    const int bh = (id & 7) + ((idx % 3) << 3);
    const int q0 = (idx / 3) << 6;
    const int b = bh / NH, h = bh - b * NH;
    const size_t hoff = (size_t)bh * NSEQ * HD;
    const short* qp = qb + hoff;     // [N][64]  (q pre-scaled by 0.125*log2e)
    const short* kp = kb + hoff;     // [N][64]
    const short* vp = vt + hoff;     // [64][N]
    const int qrow4 = quad * 4;

    int rK[4], cK[4], dV[4], cV[4];
    #pragma unroll
    for (int j = 0; j < 4; ++j) {
        int o = wid * 4096 + j * 1024 + lane * 16;
        rK[j] = o >> 7;
        cK[j] = ((o >> 4) & 7) ^ (rK[j] & 7);
        dV[j] = o >> 8;
        cV[j] = ((o >> 4) & 15) ^ (dV[j] & 15);
    }
    const int r7 = l16 & 7;
    const int kc0 = ((quad     ^ r7) << 3);
    const int kc1 = (((quad+4) ^ r7) << 3);
    const int qh = quad >> 1;
    const int vsub = (quad & 1) * 4;

    // Wave's 32 q rows: q0 + qg*32 + jq*16 + l16
    bf16x8 qf[2][2];
    {
        const short* qr = qp + (size_t)(q0 + qg*32 + l16) * HD + quad*8;
        qf[0][0] = *(const bf16x8*)qr;
        qf[0][1] = *(const bf16x8*)(qr + 32);
        qf[1][0] = *(const bf16x8*)(qr + 16*HD);
        qf[1][1] = *(const bf16x8*)(qr + 16*HD + 32);
    }

    const short one_ = (short)0x3F80;             // bf16 1.0
    const bf16x8 onesv = { one_, one_, one_, one_, one_, one_, one_, one_ };

    f32x4 o_acc[2][4] = {};
    f32x4 lacc[2] = {};
    bf16x8 pb[2][2];

    // Prologue: K tile 0 + mask row; __syncthreads drains vmcnt(0).
    STAGE_K(0, Kb[0]);
    gll16(maskb + b * NSEQ + t * 8, Msk + wid * 512);
    __syncthreads();

    for (int kt = 0; kt < NSEQ; kt += 256) {
        STAGE_V(kt);
        __builtin_amdgcn_sched_barrier(0);
        STAGE_K(kt + 128, Kb[1]);
        __builtin_amdgcn_sched_barrier(0);
        QKBODY(kt, Kb[0]);
        WAITV_BAR();              // A: V(kt) visible; K(kt+128) floats
        __builtin_amdgcn_s_setprio(1);
        PVBODY();
        __builtin_amdgcn_s_setprio(0);
        WAITK_BAR();              // B: K(kt+128) visible; Vb free

        STAGE_V(kt + 128);
        __builtin_amdgcn_sched_barrier(0);
        STAGE_K((kt + 256) & (NSEQ - 1), Kb[0]);
        __builtin_amdgcn_sched_barrier(0);
        QKBODY(kt + 128, Kb[1]);
        WAITV_BAR();              // A'
        __builtin_amdgcn_s_setprio(1);
        PVBODY();
        __builtin_amdgcn_s_setprio(0);
        WAITK_BAR();              // B'
    }

    // Epilogue: combine kg=0/kg=1 partials (disjoint key halves) via LDS.
    // Barrier B' carried vmcnt(0) -> wraparound staging landed; Kb is free.
    f32x4* red = (f32x4*)Kb;
    const int rbase = (qg*64 + lane) * 9;
    if (kg == 1) {
        #pragma unroll
        for (int jq = 0; jq < 2; ++jq)
            #pragma unroll
            for (int it = 0; it < 4; ++it)
                red[rbase + jq*4 + it] = o_acc[jq][it];
        f32x4 lv = { lacc[0][0], lacc[1][0], 0.f, 0.f };
        red[rbase + 8] = lv;
    }
    __syncthreads();
    if (kg == 0) {
        f32x4 lv = red[rbase + 8];
        const float inv0 = 1.0f / (lacc[0][0] + lv[0]);
        const float inv1 = 1.0f / (lacc[1][0] + lv[1]);
        #pragma unroll
        for (int jq = 0; jq < 2; ++jq) {
            const float inv = jq ? inv1 : inv0;
            const int tok = b * NSEQ + q0 + qg*32 + jq*16 + l16;
            short* dst = ao + (size_t)tok * CDIM + h * HD + qrow4;
            #pragma unroll
            for (int it = 0; it < 4; ++it) {
                f32x4 o_ = o_acc[jq][it];
                f32x4 r_ = red[rbase + jq*4 + it];
                short4v o = { f2b((o_[0] + r_[0]) * inv),
                              f2b((o_[1] + r_[1]) * inv),
                              f2b((o_[2] + r_[2]) * inv),
                              f2b((o_[3] + r_[3]) * inv) };
                *(short4v*)(dst + it*16) = o;
            }
        }
    }
}

// ---------------------------------------------------------------------------
// GEMM2: same double-buffered K-loop (this kernel is the most latency-naked:
// 192 blocks = 0.75 blocks/CU, no cross-block TLP on most CUs).
// ---------------------------------------------------------------------------
__global__ __launch_bounds__(256) void gemm_proj(
    const short* __restrict__ A /*wpt[768][768]*/,
    const short* __restrict__ B /*ao [4096][768]*/,
    const float* __restrict__ bias, float* __restrict__ out)
{
    __shared__ short As[2 * 4096];
    __shared__ short Bs[2 * 4096];
    const int t = threadIdx.x;
    const int lane = t & 63, wid = t >> 6;
    const int quad = lane >> 4, l16 = lane & 15;
    const int wA = wid >> 1, wB = wid & 1;
    const int n0 = blockIdx.x * 128;
    const int m0 = blockIdx.y * 128;

    const int srow = wid * 16 + (lane >> 2), schunk = (lane & 3) * 8;
    const short* ag0 = A + (size_t)(n0 + srow) * CDIM + schunk;
    const short* ag1 = ag0 + (size_t)64 * CDIM;
    const short* bg0 = B + (size_t)(m0 + srow) * CDIM + schunk;
    const short* bg1 = bg0 + (size_t)64 * CDIM;

    f32x4 acc[4][4] = {};
    GSTAGE(0, 0);
    __syncthreads();
    int buf = 0;
    for (int k0 = 0; k0 < CDIM; k0 += 32) {
        if (k0 + 32 < CDIM) GSTAGE(k0 + 32, buf ^ 1);
        __builtin_amdgcn_sched_barrier(0);
        const short* As_ = As + buf * 4096;
        const short* Bs_ = Bs + buf * 4096;
        bf16x8 af[4], bf[4];
        #pragma unroll
        for (int i = 0; i < 4; ++i)
            af[i] = *(const bf16x8*)&As_[(wA*64 + i*16 + l16) * 32 + quad*8];
        #pragma unroll
        for (int j = 0; j < 4; ++j)
            bf[j] = *(const bf16x8*)&Bs_[(wB*64 + j*16 + l16) * 32 + quad*8];
        #pragma unroll
        for (int i = 0; i < 4; ++i)
            #pragma unroll
            for (int j = 0; j < 4; ++j)
                acc[i][j] = MFMA16(af[i], bf[j], acc[i][j]);
        __syncthreads();          // stage(next) had the whole MFMA phase
        buf ^= 1;
    }

    #pragma unroll
    for (int i = 0; i < 4; ++i) {
        int col0 = n0 + wA*64 + i*16 + quad*4;
        float4 bias4 = *(const float4*)&bias[col0];
        #pragma unroll
        for (int j = 0; j < 4; ++j) {
            int tok = m0 + wB*64 + j*16 + l16;
            float4 o = { acc[i][j][0] + bias4.x, acc[i][j][1] + bias4.y,
                         acc[i][j][2] + bias4.z, acc[i][j][3] + bias4.w };
            *(float4*)(out + (size_t)tok * CDIM + col0) = o;
        }
    }
}

extern "C" void kernel_launch(void* const* d_in, const int* in_sizes, int n_in,
                              void* d_out, int out_size, void* d_ws, size_t ws_size,
                              hipStream_t stream)
{
    const float* x      = (const float*)d_in[0];
    const int*   mask   = (const int*)d_in[1];
    const float* w_qkv  = (const float*)d_in[2];
    const float* w_proj = (const float*)d_in[3];
    const float* b_proj = (const float*)d_in[4];
    float* out = (float*)d_out;

    const size_t SZ = (size_t)NTOK * CDIM;       // 3,145,728
    short* xb  = (short*)d_ws;                   // [4096][768]
    short* wqt = xb  + SZ;                       // [2304][768]
    short* wpt = wqt + (size_t)QKV_COLS * CDIM;  // [768][768]
    short* qb  = wpt + (size_t)CDIM * CDIM;      // [BH][N][64]  (pre-scaled q)
    short* kb  = qb  + SZ;                       // [BH][N][64]
    short* vt  = kb  + SZ;                       // [BH][64][N]
    short* ao  = vt  + SZ;                       // [4096][768]
    short* maskb = ao + SZ;                      // [B][N] bf16 log2-bias

    dim3 blk(256);
    prep_kernel<<<dim3(5378), blk, 0, stream>>>(x, w_qkv, w_proj, mask,
                                                xb, wqt, wpt, maskb);
    gemm_qkv<<<dim3(QKV_COLS/128, NTOK/128), blk, 0, stream>>>(wqt, xb, qb, kb, vt);
    attn_kernel<<<dim3(NBLK), blk, 0, stream>>>(qb, kb, vt, maskb, ao);
    gemm_proj<<<dim3(CDIM/128, NTOK/128), blk, 0, stream>>>(wpt, ao, b_proj, out);
}

// Round 10
// 156.648 us; speedup vs baseline: 1.7486x; 1.0123x over previous
//
#include <hip/hip_runtime.h>
#include <cstdint>

#define NB 2
#define NSEQ 2048
#define CDIM 768
#define NH 12
#define HD 64
#define NTOK (NB*NSEQ)        // 4096
#define QKV_COLS (3*CDIM)     // 2304
#define NBLK ((NSEQ/64)*NH*NB) // 768 attn blocks

typedef short bf16x8 __attribute__((ext_vector_type(8)));
typedef short bf16x4 __attribute__((ext_vector_type(4)));
typedef float f32x4  __attribute__((ext_vector_type(4)));
typedef short short4v __attribute__((ext_vector_type(4)));
typedef unsigned int uint4v __attribute__((ext_vector_type(4)));

#define MFMA16(a,b,c) __builtin_amdgcn_mfma_f32_16x16x32_bf16(a,b,c,0,0,0)

__device__ __forceinline__ short f2b(float f) {
    uint32_t u = __builtin_bit_cast(uint32_t, f);
    u += 0x7fffu + ((u >> 16) & 1u);
    return (short)(u >> 16);
}
__device__ __forceinline__ float b2f(short s) {
    return __builtin_bit_cast(float, (uint32_t)((uint32_t)(unsigned short)s << 16));
}
__device__ __forceinline__ unsigned pack2(float a, float b) {
    unsigned ua = __builtin_bit_cast(unsigned, a) + 0x7fffu;
    unsigned ub = __builtin_bit_cast(unsigned, b) + 0x7fffu;
    return __builtin_amdgcn_perm(ub, ua, 0x07060302u);
}
// 2^x on the trans pipe; q is pre-scaled by 0.125*log2(e) so exp2(s)==exp(qk/8).
__device__ __forceinline__ float fexp2(float x) {
#if __has_builtin(__builtin_amdgcn_exp2f)
    return __builtin_amdgcn_exp2f(x);
#else
    return __expf(x * 0.69314718055994531f);
#endif
}
__device__ __forceinline__ void gll16(const short* g, short* l) {
    __builtin_amdgcn_global_load_lds(
        (const __attribute__((address_space(1))) unsigned int*)g,
        (__attribute__((address_space(3))) unsigned int*)l, 16, 0, 0);
}

// ---------------------------------------------------------------------------
// Merged prep: x fp32->bf16 (blocks 0..3071), w_qkv transpose (..4799),
// w_proj transpose (..5375), mask int->bf16 LOG2-BIAS (5376..5377).
// Transpose tile reads/writes vectorized (float4 in, short4 out).
// ---------------------------------------------------------------------------
__global__ __launch_bounds__(256) void prep_kernel(
    const float* __restrict__ x, const float* __restrict__ w_qkv,
    const float* __restrict__ w_proj, const int* __restrict__ mask,
    short* __restrict__ xb, short* __restrict__ wqt, short* __restrict__ wpt,
    short* __restrict__ maskb)
{
    __shared__ float tile[32][33];
    const int bid = blockIdx.x, t = threadIdx.x;
    if (bid < 3072) {
        int i = bid * 256 + t;
        float4 v = ((const float4*)x)[i];
        short4v o = { f2b(v.x), f2b(v.y), f2b(v.z), f2b(v.w) };
        ((short4v*)xb)[i] = o;
        return;
    }
    if (bid >= 5376) {
        int i = ((bid - 5376) << 11) + (t << 3);   // 2 blocks x 2048 values
        int4 a = *(const int4*)(mask + i);
        int4 c = *(const int4*)(mask + i + 4);
        const short NEG = (short)0xC680;           // bf16 -16384.0
        short4v o0 = { a.x ? (short)0 : NEG, a.y ? (short)0 : NEG,
                       a.z ? (short)0 : NEG, a.w ? (short)0 : NEG };
        short4v o1 = { c.x ? (short)0 : NEG, c.y ? (short)0 : NEG,
                       c.z ? (short)0 : NEG, c.w ? (short)0 : NEG };
        *(short4v*)(maskb + i) = o0;
        *(short4v*)(maskb + i + 4) = o1;
        return;
    }
    const float* w; short* wt; int K, NC, n0, k0;
    if (bid < 3072 + 1728) {
        int r = bid - 3072;
        w = w_qkv; wt = wqt; K = CDIM; NC = QKV_COLS;
        n0 = (r % 72) * 32; k0 = (r / 72) * 32;
    } else {
        int r = bid - 4800;
        w = w_proj; wt = wpt; K = CDIM; NC = CDIM;
        n0 = (r % 24) * 32; k0 = (r / 24) * 32;
    }
    const int r = t >> 3, c4 = (t & 7) * 4;
    {
        float4 v = *(const float4*)&w[(size_t)(k0 + r) * NC + n0 + c4];
        tile[r][c4 + 0] = v.x; tile[r][c4 + 1] = v.y;
        tile[r][c4 + 2] = v.z; tile[r][c4 + 3] = v.w;
    }
    __syncthreads();
    {
        short4v o = { f2b(tile[c4 + 0][r]), f2b(tile[c4 + 1][r]),
                      f2b(tile[c4 + 2][r]), f2b(tile[c4 + 3][r]) };
        *(short4v*)&wt[(size_t)(n0 + r) * K + k0 + c4] = o;
    }
}

// ---------------------------------------------------------------------------
// GEMM K-loop (round-9 structure, HW-verified): double-buffered staging,
// one barrier per K-step. v17 adds T1 XCD-AWARE GRID SWIZZLE: the default
// block order scatters A-panel reuse across all 8 XCD L2s (A 3.5MB + B
// 6.3MB >> 4MB/XCD). 1-D grid, id -> (xcd = id&7, j = id>>3, lin =
// xcd*(nwg/8)+j), n0 = (lin>>5)*128 (m fastest within an XCD's chunk) so
// each XCD owns a contiguous n-slice: its A-slice (~442KB) goes L2-resident.
// Bijective: 576 = 8*72, 192 = 8*24 (exactly divisible -- no m204 hazard).
// This is also the model-A/model-B discriminator for the stable ~114us
// non-attn residual: L2-bound GEMMs (model B) move -3..-6us; harness-fill-
// dominated timing (model A) moves ~0.
// ---------------------------------------------------------------------------
#define GSTAGE(K0V, B) do {                                                      \
    gll16(ag0 + (K0V), As + (B)*4096 + (wid*16)*32);                             \
    gll16(ag1 + (K0V), As + (B)*4096 + (wid*16 + 64)*32);                        \
    gll16(bg0 + (K0V), Bs + (B)*4096 + (wid*16)*32);                             \
    gll16(bg1 + (K0V), Bs + (B)*4096 + (wid*16 + 64)*32);                        \
} while (0)

// ---------------------------------------------------------------------------
// GEMM1. Epilogue: q is PRE-SCALED by 0.125*log2(e) (exp2-fold).
// Grid: 1-D 576 blocks, XCD-swizzled (72 blocks/XCD = 2.25 n-cols x 32 m).
// ---------------------------------------------------------------------------
__global__ __launch_bounds__(256) void gemm_qkv(
    const short* __restrict__ A /*wqt[2304][768]*/,
    const short* __restrict__ B /*xb [4096][768]*/,
    short* __restrict__ qb, short* __restrict__ kb, short* __restrict__ vt)
{
    __shared__ short As[2 * 4096];
    __shared__ short Bs[2 * 4096];
    const int t = threadIdx.x;
    const int lane = t & 63, wid = t >> 6;
    const int quad = lane >> 4, l16 = lane & 15;
    const int wA = wid >> 1, wB = wid & 1;
    // XCD swizzle: 576 = 8 XCDs x 72; within a chunk m varies fastest.
    const int id = blockIdx.x;
    const int lin = (id & 7) * 72 + (id >> 3);
    const int n0 = (lin >> 5) * 128;      // 0..17
    const int m0 = (lin & 31) * 128;      // 0..31

    const int srow = wid * 16 + (lane >> 2), schunk = (lane & 3) * 8;
    const short* ag0 = A + (size_t)(n0 + srow) * CDIM + schunk;
    const short* ag1 = ag0 + (size_t)64 * CDIM;
    const short* bg0 = B + (size_t)(m0 + srow) * CDIM + schunk;
    const short* bg1 = bg0 + (size_t)64 * CDIM;

    f32x4 acc[4][4] = {};
    GSTAGE(0, 0);
    __syncthreads();
    int buf = 0;
    for (int k0 = 0; k0 < CDIM; k0 += 32) {
        if (k0 + 32 < CDIM) GSTAGE(k0 + 32, buf ^ 1);
        __builtin_amdgcn_sched_barrier(0);
        const short* As_ = As + buf * 4096;
        const short* Bs_ = Bs + buf * 4096;
        bf16x8 af[4], bf[4];
        #pragma unroll
        for (int i = 0; i < 4; ++i)
            af[i] = *(const bf16x8*)&As_[(wA*64 + i*16 + l16) * 32 + quad*8];
        #pragma unroll
        for (int j = 0; j < 4; ++j)
            bf[j] = *(const bf16x8*)&Bs_[(wB*64 + j*16 + l16) * 32 + quad*8];
        #pragma unroll
        for (int i = 0; i < 4; ++i)
            #pragma unroll
            for (int j = 0; j < 4; ++j)
                acc[i][j] = MFMA16(af[i], bf[j], acc[i][j]);
        __syncthreads();          // stage(next) had the whole MFMA phase
        buf ^= 1;
    }

    const int colbase = n0 + wA * 64;
    const int s = colbase / CDIM;
    const int h = (colbase - s * CDIM) >> 6;
    const int b = m0 >> 11;
    const size_t bh = (size_t)(b * NH + h);
    // fold softmax scale AND log2(e) into q: exp(qk/8) == exp2(qk*qsc)
    const float qsc = (s == 0) ? 0.18033688011112042f : 1.0f;
    #pragma unroll
    for (int i = 0; i < 4; ++i) {
        const int d0 = i*16 + quad*4;
        #pragma unroll
        for (int j = 0; j < 4; ++j) {
            int tok = (m0 + wB*64 + j*16 + l16) & (NSEQ - 1);
            if (s < 2) {
                short* dst = (s == 0 ? qb : kb) + (bh * NSEQ + tok) * HD + d0;
                short4v o = { f2b(acc[i][j][0] * qsc), f2b(acc[i][j][1] * qsc),
                              f2b(acc[i][j][2] * qsc), f2b(acc[i][j][3] * qsc) };
                *(short4v*)dst = o;
            } else {
                short* dst = vt + (bh * HD + d0) * NSEQ + tok;
                #pragma unroll
                for (int r = 0; r < 4; ++r)
                    dst[(size_t)r * NSEQ] = f2b(acc[i][j][r]);
            }
        }
    }
}

// ---------------------------------------------------------------------------
// Flash attention v15 (byte-identical to round 7/9's HW-verified kernel):
// 2x2 hybrid split, 3 blocks/CU, counted-vmcnt barriers, setprio around PV.
// ---------------------------------------------------------------------------
#define STAGE_K(KT, BUF) do {                                                    \
    short* kb_ = (BUF);                                                          \
    _Pragma("unroll")                                                            \
    for (int j = 0; j < 4; ++j)                                                  \
        gll16(kp + (size_t)((KT) + rK[j]) * HD + cK[j]*8,                        \
              kb_ + wid*2048 + j*512);                                           \
} while (0)

#define STAGE_V(KT) do {                                                         \
    _Pragma("unroll")                                                            \
    for (int j = 0; j < 4; ++j)                                                  \
        gll16(vp + (size_t)dV[j] * NSEQ + (KT) + cV[j]*8,                        \
              Vb + wid*2048 + j*512);                                            \
} while (0)

#define QKBODY(KT, KBUF) do {                                                    \
    const short* KsB_ = (KBUF) + kg*4096;                                        \
    _Pragma("unroll")                                                            \
    for (int ks = 0; ks < 2; ++ks) {                                             \
        short4v mi0_ = *(const short4v*)&Msk[(KT) + kg*64 + ks*16 + qrow4];      \
        short4v mi1_ = *(const short4v*)&Msk[(KT) + kg*64 + 32 + ks*16 + qrow4]; \
        const int kro_ = (ks*16 + l16) * 64;                                     \
        bf16x8 kf00_ = *(const bf16x8*)&KsB_[kro_ + kc0];                        \
        bf16x8 kf01_ = *(const bf16x8*)&KsB_[kro_ + kc1];                        \
        bf16x8 kf10_ = *(const bf16x8*)&KsB_[2048 + kro_ + kc0];                 \
        bf16x8 kf11_ = *(const bf16x8*)&KsB_[2048 + kro_ + kc1];                 \
        f32x4 m0v_ = { b2f(mi0_[0]), b2f(mi0_[1]),                               \
                       b2f(mi0_[2]), b2f(mi0_[3]) };                             \
        f32x4 m1v_ = { b2f(mi1_[0]), b2f(mi1_[1]),                               \
                       b2f(mi1_[2]), b2f(mi1_[3]) };                             \
        _Pragma("unroll")                                                        \
        for (int jq = 0; jq < 2; ++jq) {                                         \
            f32x4 s0_ = m0v_, s1_ = m1v_;                                        \
            s0_ = MFMA16(kf00_, qf[jq][0], s0_);                                 \
            s0_ = MFMA16(kf01_, qf[jq][1], s0_);                                 \
            s1_ = MFMA16(kf10_, qf[jq][0], s1_);                                 \
            s1_ = MFMA16(kf11_, qf[jq][1], s1_);                                 \
            float e0 = fexp2(s0_[0]);                                            \
            float e1 = fexp2(s0_[1]);                                            \
            float e2 = fexp2(s0_[2]);                                            \
            float e3 = fexp2(s0_[3]);                                            \
            float f0 = fexp2(s1_[0]);                                            \
            float f1 = fexp2(s1_[1]);                                            \
            float f2 = fexp2(s1_[2]);                                            \
            float f3 = fexp2(s1_[3]);                                            \
            uint4v pk_ = { pack2(e0, e1), pack2(e2, e3),                         \
                           pack2(f0, f1), pack2(f2, f3) };                       \
            pb[jq][ks] = __builtin_bit_cast(bf16x8, pk_);                        \
        }                                                                        \
    }                                                                            \
} while (0)

#define PVBODY() do {                                                            \
    _Pragma("unroll")                                                            \
    for (int ks = 0; ks < 2; ++ks) {                                             \
        lacc[0] = MFMA16(onesv, pb[0][ks], lacc[0]);                             \
        lacc[1] = MFMA16(onesv, pb[1][ks], lacc[1]);                             \
    }                                                                            \
    _Pragma("unroll")                                                            \
    for (int it = 0; it < 4; ++it) {                                             \
        const int vrow_ = (it*16 + l16) * 128;                                   \
        _Pragma("unroll")                                                        \
        for (int ks = 0; ks < 2; ++ks) {                                         \
            const int gl_ = (((kg*8 + ks*2 + qh) ^ l16) << 3) + vsub;            \
            const int gh_ = (((kg*8 + 4 + ks*2 + qh) ^ l16) << 3) + vsub;        \
            bf16x4 lo_ = *(const bf16x4*)&Vb[vrow_ + gl_];                       \
            bf16x4 hi_ = *(const bf16x4*)&Vb[vrow_ + gh_];                       \
            bf16x8 vf_ = __builtin_shufflevector(lo_, hi_, 0,1,2,3,4,5,6,7);     \
            o_acc[0][it] = MFMA16(vf_, pb[0][ks], o_acc[0][it]);                 \
            o_acc[1][it] = MFMA16(vf_, pb[1][ks], o_acc[1][it]);                 \
        }                                                                        \
    }                                                                            \
} while (0)

#define WAITV_BAR() do {                                                         \
    asm volatile("s_waitcnt vmcnt(4)" ::: "memory");                             \
    __builtin_amdgcn_sched_barrier(0);                                           \
    __builtin_amdgcn_s_barrier();                                                \
} while (0)

#define WAITK_BAR() do {                                                         \
    asm volatile("s_waitcnt vmcnt(0)" ::: "memory");                             \
    __builtin_amdgcn_sched_barrier(0);                                           \
    __builtin_amdgcn_s_barrier();                                                \
} while (0)

__global__ __launch_bounds__(256, 3) void attn_kernel(
    const short* __restrict__ qb, const short* __restrict__ kb,
    const short* __restrict__ vt, const short* __restrict__ maskb,
    short* __restrict__ ao)
{
    __shared__ __align__(16) short Kb[2][8192];   // K tiles [128][64], dbuf
    __shared__ __align__(16) short Vb[8192];      // V tile  [64][128], single
    __shared__ __align__(16) short Msk[2048];     // bf16 log2-bias, this b

    const int t = threadIdx.x;
    const int lane = t & 63, wid = t >> 6;
    const int quad = lane >> 4, l16 = lane & 15;
    const int qg = wid >> 1, kg = wid & 1;        // 2x2 hybrid split
    // XCD swizzle: XCD = id%8 owns bh in {xcd, xcd+8, xcd+16}
    const int id = blockIdx.x;
    const int idx = id >> 3;
    const int bh = (id & 7) + ((idx % 3) << 3);
    const int q0 = (idx / 3) << 6;
    const int b = bh / NH, h = bh - b * NH;
    const size_t hoff = (size_t)bh * NSEQ * HD;
    const short* qp = qb + hoff;     // [N][64]  (q pre-scaled by 0.125*log2e)
    const short* kp = kb + hoff;     // [N][64]
    const short* vp = vt + hoff;     // [64][N]
    const int qrow4 = quad * 4;

    int rK[4], cK[4], dV[4], cV[4];
    #pragma unroll
    for (int j = 0; j < 4; ++j) {
        int o = wid * 4096 + j * 1024 + lane * 16;
        rK[j] = o >> 7;
        cK[j] = ((o >> 4) & 7) ^ (rK[j] & 7);
        dV[j] = o >> 8;
        cV[j] = ((o >> 4) & 15) ^ (dV[j] & 15);
    }
    const int r7 = l16 & 7;
    const int kc0 = ((quad     ^ r7) << 3);
    const int kc1 = (((quad+4) ^ r7) << 3);
    const int qh = quad >> 1;
    const int vsub = (quad & 1) * 4;

    // Wave's 32 q rows: q0 + qg*32 + jq*16 + l16
    bf16x8 qf[2][2];
    {
        const short* qr = qp + (size_t)(q0 + qg*32 + l16) * HD + quad*8;
        qf[0][0] = *(const bf16x8*)qr;
        qf[0][1] = *(const bf16x8*)(qr + 32);
        qf[1][0] = *(const bf16x8*)(qr + 16*HD);
        qf[1][1] = *(const bf16x8*)(qr + 16*HD + 32);
    }

    const short one_ = (short)0x3F80;             // bf16 1.0
    const bf16x8 onesv = { one_, one_, one_, one_, one_, one_, one_, one_ };

    f32x4 o_acc[2][4] = {};
    f32x4 lacc[2] = {};
    bf16x8 pb[2][2];

    // Prologue: K tile 0 + mask row; __syncthreads drains vmcnt(0).
    STAGE_K(0, Kb[0]);
    gll16(maskb + b * NSEQ + t * 8, Msk + wid * 512);
    __syncthreads();

    for (int kt = 0; kt < NSEQ; kt += 256) {
        STAGE_V(kt);
        __builtin_amdgcn_sched_barrier(0);
        STAGE_K(kt + 128, Kb[1]);
        __builtin_amdgcn_sched_barrier(0);
        QKBODY(kt, Kb[0]);
        WAITV_BAR();              // A: V(kt) visible; K(kt+128) floats
        __builtin_amdgcn_s_setprio(1);
        PVBODY();
        __builtin_amdgcn_s_setprio(0);
        WAITK_BAR();              // B: K(kt+128) visible; Vb free

        STAGE_V(kt + 128);
        __builtin_amdgcn_sched_barrier(0);
        STAGE_K((kt + 256) & (NSEQ - 1), Kb[0]);
        __builtin_amdgcn_sched_barrier(0);
        QKBODY(kt + 128, Kb[1]);
        WAITV_BAR();              // A'
        __builtin_amdgcn_s_setprio(1);
        PVBODY();
        __builtin_amdgcn_s_setprio(0);
        WAITK_BAR();              // B'
    }

    // Epilogue: combine kg=0/kg=1 partials (disjoint key halves) via LDS.
    // Barrier B' carried vmcnt(0) -> wraparound staging landed; Kb is free.
    f32x4* red = (f32x4*)Kb;
    const int rbase = (qg*64 + lane) * 9;
    if (kg == 1) {
        #pragma unroll
        for (int jq = 0; jq < 2; ++jq)
            #pragma unroll
            for (int it = 0; it < 4; ++it)
                red[rbase + jq*4 + it] = o_acc[jq][it];
        f32x4 lv = { lacc[0][0], lacc[1][0], 0.f, 0.f };
        red[rbase + 8] = lv;
    }
    __syncthreads();
    if (kg == 0) {
        f32x4 lv = red[rbase + 8];
        const float inv0 = 1.0f / (lacc[0][0] + lv[0]);
        const float inv1 = 1.0f / (lacc[1][0] + lv[1]);
        #pragma unroll
        for (int jq = 0; jq < 2; ++jq) {
            const float inv = jq ? inv1 : inv0;
            const int tok = b * NSEQ + q0 + qg*32 + jq*16 + l16;
            short* dst = ao + (size_t)tok * CDIM + h * HD + qrow4;
            #pragma unroll
            for (int it = 0; it < 4; ++it) {
                f32x4 o_ = o_acc[jq][it];
                f32x4 r_ = red[rbase + jq*4 + it];
                short4v o = { f2b((o_[0] + r_[0]) * inv),
                              f2b((o_[1] + r_[1]) * inv),
                              f2b((o_[2] + r_[2]) * inv),
                              f2b((o_[3] + r_[3]) * inv) };
                *(short4v*)(dst + it*16) = o;
            }
        }
    }
}

// ---------------------------------------------------------------------------
// GEMM2: XCD-swizzled 1-D grid (192 = 8 x 24; m fastest within chunk).
// ---------------------------------------------------------------------------
__global__ __launch_bounds__(256) void gemm_proj(
    const short* __restrict__ A /*wpt[768][768]*/,
    const short* __restrict__ B /*ao [4096][768]*/,
    const float* __restrict__ bias, float* __restrict__ out)
{
    __shared__ short As[2 * 4096];
    __shared__ short Bs[2 * 4096];
    const int t = threadIdx.x;
    const int lane = t & 63, wid = t >> 6;
    const int quad = lane >> 4, l16 = lane & 15;
    const int wA = wid >> 1, wB = wid & 1;
    // XCD swizzle: 192 = 8 XCDs x 24.
    const int id = blockIdx.x;
    const int lin = (id & 7) * 24 + (id >> 3);
    const int n0 = (lin >> 5) * 128;      // 0..5
    const int m0 = (lin & 31) * 128;      // 0..31

    const int srow = wid * 16 + (lane >> 2), schunk = (lane & 3) * 8;
    const short* ag0 = A + (size_t)(n0 + srow) * CDIM + schunk;
    const short* ag1 = ag0 + (size_t)64 * CDIM;
    const short* bg0 = B + (size_t)(m0 + srow) * CDIM + schunk;
    const short* bg1 = bg0 + (size_t)64 * CDIM;

    f32x4 acc[4][4] = {};
    GSTAGE(0, 0);
    __syncthreads();
    int buf = 0;
    for (int k0 = 0; k0 < CDIM; k0 += 32) {
        if (k0 + 32 < CDIM) GSTAGE(k0 + 32, buf ^ 1);
        __builtin_amdgcn_sched_barrier(0);
        const short* As_ = As + buf * 4096;
        const short* Bs_ = Bs + buf * 4096;
        bf16x8 af[4], bf[4];
        #pragma unroll
        for (int i = 0; i < 4; ++i)
            af[i] = *(const bf16x8*)&As_[(wA*64 + i*16 + l16) * 32 + quad*8];
        #pragma unroll
        for (int j = 0; j < 4; ++j)
            bf[j] = *(const bf16x8*)&Bs_[(wB*64 + j*16 + l16) * 32 + quad*8];
        #pragma unroll
        for (int i = 0; i < 4; ++i)
            #pragma unroll
            for (int j = 0; j < 4; ++j)
                acc[i][j] = MFMA16(af[i], bf[j], acc[i][j]);
        __syncthreads();          // stage(next) had the whole MFMA phase
        buf ^= 1;
    }

    #pragma unroll
    for (int i = 0; i < 4; ++i) {
        int col0 = n0 + wA*64 + i*16 + quad*4;
        float4 bias4 = *(const float4*)&bias[col0];
        #pragma unroll
        for (int j = 0; j < 4; ++j) {
            int tok = m0 + wB*64 + j*16 + l16;
            float4 o = { acc[i][j][0] + bias4.x, acc[i][j][1] + bias4.y,
                         acc[i][j][2] + bias4.z, acc[i][j][3] + bias4.w };
            *(float4*)(out + (size_t)tok * CDIM + col0) = o;
        }
    }
}

extern "C" void kernel_launch(void* const* d_in, const int* in_sizes, int n_in,
                              void* d_out, int out_size, void* d_ws, size_t ws_size,
                              hipStream_t stream)
{
    const float* x      = (const float*)d_in[0];
    const int*   mask   = (const int*)d_in[1];
    const float* w_qkv  = (const float*)d_in[2];
    const float* w_proj = (const float*)d_in[3];
    const float* b_proj = (const float*)d_in[4];
    float* out = (float*)d_out;

    const size_t SZ = (size_t)NTOK * CDIM;       // 3,145,728
    short* xb  = (short*)d_ws;                   // [4096][768]
    short* wqt = xb  + SZ;                       // [2304][768]
    short* wpt = wqt + (size_t)QKV_COLS * CDIM;  // [768][768]
    short* qb  = wpt + (size_t)CDIM * CDIM;      // [BH][N][64]  (pre-scaled q)
    short* kb  = qb  + SZ;                       // [BH][N][64]
    short* vt  = kb  + SZ;                       // [BH][64][N]
    short* ao  = vt  + SZ;                       // [4096][768]
    short* maskb = ao + SZ;                      // [B][N] bf16 log2-bias

    dim3 blk(256);
    prep_kernel<<<dim3(5378), blk, 0, stream>>>(x, w_qkv, w_proj, mask,
                                                xb, wqt, wpt, maskb);
    gemm_qkv<<<dim3(576), blk, 0, stream>>>(wqt, xb, qb, kb, vt);
    attn_kernel<<<dim3(NBLK), blk, 0, stream>>>(qb, kb, vt, maskb, ao);
    gemm_proj<<<dim3(192), blk, 0, stream>>>(wpt, ao, b_proj, out);
}

// Round 11
// 152.345 us; speedup vs baseline: 1.7980x; 1.0282x over previous
//
#include <hip/hip_runtime.h>
#include <cstdint>

#define NB 2
#define NSEQ 2048
#define CDIM 768
#define NH 12
#define HD 64
#define NTOK (NB*NSEQ)        // 4096
#define QKV_COLS (3*CDIM)     // 2304
#define NBLK ((NSEQ/64)*NH*NB) // 768 attn blocks

typedef short bf16x8 __attribute__((ext_vector_type(8)));
typedef short bf16x4 __attribute__((ext_vector_type(4)));
typedef float f32x4  __attribute__((ext_vector_type(4)));
typedef short short4v __attribute__((ext_vector_type(4)));
typedef unsigned int uint4v __attribute__((ext_vector_type(4)));

#define MFMA16(a,b,c) __builtin_amdgcn_mfma_f32_16x16x32_bf16(a,b,c,0,0,0)

__device__ __forceinline__ short f2b(float f) {
    uint32_t u = __builtin_bit_cast(uint32_t, f);
    u += 0x7fffu + ((u >> 16) & 1u);
    return (short)(u >> 16);
}
__device__ __forceinline__ float b2f(short s) {
    return __builtin_bit_cast(float, (uint32_t)((uint32_t)(unsigned short)s << 16));
}
__device__ __forceinline__ unsigned pack2(float a, float b) {
    unsigned ua = __builtin_bit_cast(unsigned, a) + 0x7fffu;
    unsigned ub = __builtin_bit_cast(unsigned, b) + 0x7fffu;
    return __builtin_amdgcn_perm(ub, ua, 0x07060302u);
}
// 2^x on the trans pipe; q is pre-scaled by 0.125*log2(e) so exp2(s)==exp(qk/8).
__device__ __forceinline__ float fexp2(float x) {
#if __has_builtin(__builtin_amdgcn_exp2f)
    return __builtin_amdgcn_exp2f(x);
#else
    return __expf(x * 0.69314718055994531f);
#endif
}
__device__ __forceinline__ void gll16(const short* g, short* l) {
    __builtin_amdgcn_global_load_lds(
        (const __attribute__((address_space(1))) unsigned int*)g,
        (__attribute__((address_space(3))) unsigned int*)l, 16, 0, 0);
}

// ---------------------------------------------------------------------------
// Merged prep: x fp32->bf16 (blocks 0..3071), w_qkv transpose (..4799),
// w_proj transpose (..5375), mask int->bf16 LOG2-BIAS (5376..5377).
// ---------------------------------------------------------------------------
__global__ __launch_bounds__(256) void prep_kernel(
    const float* __restrict__ x, const float* __restrict__ w_qkv,
    const float* __restrict__ w_proj, const int* __restrict__ mask,
    short* __restrict__ xb, short* __restrict__ wqt, short* __restrict__ wpt,
    short* __restrict__ maskb)
{
    __shared__ float tile[32][33];
    const int bid = blockIdx.x, t = threadIdx.x;
    if (bid < 3072) {
        int i = bid * 256 + t;
        float4 v = ((const float4*)x)[i];
        short4v o = { f2b(v.x), f2b(v.y), f2b(v.z), f2b(v.w) };
        ((short4v*)xb)[i] = o;
        return;
    }
    if (bid >= 5376) {
        int i = ((bid - 5376) << 11) + (t << 3);   // 2 blocks x 2048 values
        int4 a = *(const int4*)(mask + i);
        int4 c = *(const int4*)(mask + i + 4);
        const short NEG = (short)0xC680;           // bf16 -16384.0
        short4v o0 = { a.x ? (short)0 : NEG, a.y ? (short)0 : NEG,
                       a.z ? (short)0 : NEG, a.w ? (short)0 : NEG };
        short4v o1 = { c.x ? (short)0 : NEG, c.y ? (short)0 : NEG,
                       c.z ? (short)0 : NEG, c.w ? (short)0 : NEG };
        *(short4v*)(maskb + i) = o0;
        *(short4v*)(maskb + i + 4) = o1;
        return;
    }
    const float* w; short* wt; int K, NC, n0, k0;
    if (bid < 3072 + 1728) {
        int r = bid - 3072;
        w = w_qkv; wt = wqt; K = CDIM; NC = QKV_COLS;
        n0 = (r % 72) * 32; k0 = (r / 72) * 32;
    } else {
        int r = bid - 4800;
        w = w_proj; wt = wpt; K = CDIM; NC = CDIM;
        n0 = (r % 24) * 32; k0 = (r / 24) * 32;
    }
    const int r = t >> 3, c4 = (t & 7) * 4;
    {
        float4 v = *(const float4*)&w[(size_t)(k0 + r) * NC + n0 + c4];
        tile[r][c4 + 0] = v.x; tile[r][c4 + 1] = v.y;
        tile[r][c4 + 2] = v.z; tile[r][c4 + 3] = v.w;
    }
    __syncthreads();
    {
        short4v o = { f2b(tile[c4 + 0][r]), f2b(tile[c4 + 1][r]),
                      f2b(tile[c4 + 2][r]), f2b(tile[c4 + 3][r]) };
        *(short4v*)&wt[(size_t)(n0 + r) * K + k0 + c4] = o;
    }
}

// ---------------------------------------------------------------------------
// GEMM K-loop (HW-verified): double-buffered staging, one barrier per
// K-step, XCD-swizzled 1-D grid (T1).
// ---------------------------------------------------------------------------
#define GSTAGE(K0V, B) do {                                                      \
    gll16(ag0 + (K0V), As + (B)*4096 + (wid*16)*32);                             \
    gll16(ag1 + (K0V), As + (B)*4096 + (wid*16 + 64)*32);                        \
    gll16(bg0 + (K0V), Bs + (B)*4096 + (wid*16)*32);                             \
    gll16(bg1 + (K0V), Bs + (B)*4096 + (wid*16 + 64)*32);                        \
} while (0)

// ---------------------------------------------------------------------------
// GEMM1. Epilogue: q PRE-SCALED by 0.125*log2(e) (exp2-fold). V is written
// KEY-PERMUTED within each 64-group: key = g*64+h*32+c*4+r -> key' =
// g*64+c*8+h*4+r, so attn's PV A-fragment (keys {k0..k0+3, k0+32..k0+35})
// becomes 8 CONTIGUOUS bf16 -> single ds_read_b128, no shuffles.
// ---------------------------------------------------------------------------
__global__ __launch_bounds__(256) void gemm_qkv(
    const short* __restrict__ A /*wqt[2304][768]*/,
    const short* __restrict__ B /*xb [4096][768]*/,
    short* __restrict__ qb, short* __restrict__ kb, short* __restrict__ vt)
{
    __shared__ short As[2 * 4096];
    __shared__ short Bs[2 * 4096];
    const int t = threadIdx.x;
    const int lane = t & 63, wid = t >> 6;
    const int quad = lane >> 4, l16 = lane & 15;
    const int wA = wid >> 1, wB = wid & 1;
    // XCD swizzle: 576 = 8 XCDs x 72; within a chunk m varies fastest.
    const int id = blockIdx.x;
    const int lin = (id & 7) * 72 + (id >> 3);
    const int n0 = (lin >> 5) * 128;      // 0..17
    const int m0 = (lin & 31) * 128;      // 0..31

    const int srow = wid * 16 + (lane >> 2), schunk = (lane & 3) * 8;
    const short* ag0 = A + (size_t)(n0 + srow) * CDIM + schunk;
    const short* ag1 = ag0 + (size_t)64 * CDIM;
    const short* bg0 = B + (size_t)(m0 + srow) * CDIM + schunk;
    const short* bg1 = bg0 + (size_t)64 * CDIM;

    f32x4 acc[4][4] = {};
    GSTAGE(0, 0);
    __syncthreads();
    int buf = 0;
    for (int k0 = 0; k0 < CDIM; k0 += 32) {
        if (k0 + 32 < CDIM) GSTAGE(k0 + 32, buf ^ 1);
        __builtin_amdgcn_sched_barrier(0);
        const short* As_ = As + buf * 4096;
        const short* Bs_ = Bs + buf * 4096;
        bf16x8 af[4], bf[4];
        #pragma unroll
        for (int i = 0; i < 4; ++i)
            af[i] = *(const bf16x8*)&As_[(wA*64 + i*16 + l16) * 32 + quad*8];
        #pragma unroll
        for (int j = 0; j < 4; ++j)
            bf[j] = *(const bf16x8*)&Bs_[(wB*64 + j*16 + l16) * 32 + quad*8];
        #pragma unroll
        for (int i = 0; i < 4; ++i)
            #pragma unroll
            for (int j = 0; j < 4; ++j)
                acc[i][j] = MFMA16(af[i], bf[j], acc[i][j]);
        __syncthreads();          // stage(next) had the whole MFMA phase
        buf ^= 1;
    }

    const int colbase = n0 + wA * 64;
    const int s = colbase / CDIM;
    const int h = (colbase - s * CDIM) >> 6;
    const int b = m0 >> 11;
    const size_t bh = (size_t)(b * NH + h);
    // fold softmax scale AND log2(e) into q: exp(qk/8) == exp2(qk*qsc)
    const float qsc = (s == 0) ? 0.18033688011112042f : 1.0f;
    #pragma unroll
    for (int i = 0; i < 4; ++i) {
        const int d0 = i*16 + quad*4;
        #pragma unroll
        for (int j = 0; j < 4; ++j) {
            int tok = (m0 + wB*64 + j*16 + l16) & (NSEQ - 1);
            if (s < 2) {
                short* dst = (s == 0 ? qb : kb) + (bh * NSEQ + tok) * HD + d0;
                short4v o = { f2b(acc[i][j][0] * qsc), f2b(acc[i][j][1] * qsc),
                              f2b(acc[i][j][2] * qsc), f2b(acc[i][j][3] * qsc) };
                *(short4v*)dst = o;
            } else {
                // key-permute within 64-group: [g][h][c2c1c0][r1r0] ->
                // [g][c2c1c0][h][r1r0]
                int t6 = tok & 63;
                int tokp = (tok & ~63) | ((t6 & 28) << 1)
                         | ((t6 & 32) >> 3) | (t6 & 3);
                short* dst = vt + (bh * HD + d0) * NSEQ + tokp;
                #pragma unroll
                for (int r = 0; r < 4; ++r)
                    dst[(size_t)r * NSEQ] = f2b(acc[i][j][r]);
            }
        }
    }
}

// ---------------------------------------------------------------------------
// Flash attention v18 = v15 + single-b128 PV reads (V key-permuted by
// gemm_qkv). Per tile per wave: PV LDS 16xb64+8shuffle -> 8xb128, 0 shuffle.
// pb's pack2 order [e0..e3,f0..f3] already matches the permuted key' order,
// so the P<->V contraction stays consistent; mask/K/lsum are key-order-
// agnostic. Staging unchanged (linear copy, XOR chunk swizzle).
// ---------------------------------------------------------------------------
#define STAGE_K(KT, BUF) do {                                                    \
    short* kb_ = (BUF);                                                          \
    _Pragma("unroll")                                                            \
    for (int j = 0; j < 4; ++j)                                                  \
        gll16(kp + (size_t)((KT) + rK[j]) * HD + cK[j]*8,                        \
              kb_ + wid*2048 + j*512);                                           \
} while (0)

#define STAGE_V(KT) do {                                                         \
    _Pragma("unroll")                                                            \
    for (int j = 0; j < 4; ++j)                                                  \
        gll16(vp + (size_t)dV[j] * NSEQ + (KT) + cV[j]*8,                        \
              Vb + wid*2048 + j*512);                                            \
} while (0)

#define QKBODY(KT, KBUF) do {                                                    \
    const short* KsB_ = (KBUF) + kg*4096;                                        \
    _Pragma("unroll")                                                            \
    for (int ks = 0; ks < 2; ++ks) {                                             \
        short4v mi0_ = *(const short4v*)&Msk[(KT) + kg*64 + ks*16 + qrow4];      \
        short4v mi1_ = *(const short4v*)&Msk[(KT) + kg*64 + 32 + ks*16 + qrow4]; \
        const int kro_ = (ks*16 + l16) * 64;                                     \
        bf16x8 kf00_ = *(const bf16x8*)&KsB_[kro_ + kc0];                        \
        bf16x8 kf01_ = *(const bf16x8*)&KsB_[kro_ + kc1];                        \
        bf16x8 kf10_ = *(const bf16x8*)&KsB_[2048 + kro_ + kc0];                 \
        bf16x8 kf11_ = *(const bf16x8*)&KsB_[2048 + kro_ + kc1];                 \
        f32x4 m0v_ = { b2f(mi0_[0]), b2f(mi0_[1]),                               \
                       b2f(mi0_[2]), b2f(mi0_[3]) };                             \
        f32x4 m1v_ = { b2f(mi1_[0]), b2f(mi1_[1]),                               \
                       b2f(mi1_[2]), b2f(mi1_[3]) };                             \
        _Pragma("unroll")                                                        \
        for (int jq = 0; jq < 2; ++jq) {                                         \
            f32x4 s0_ = m0v_, s1_ = m1v_;                                        \
            s0_ = MFMA16(kf00_, qf[jq][0], s0_);                                 \
            s0_ = MFMA16(kf01_, qf[jq][1], s0_);                                 \
            s1_ = MFMA16(kf10_, qf[jq][0], s1_);                                 \
            s1_ = MFMA16(kf11_, qf[jq][1], s1_);                                 \
            float e0 = fexp2(s0_[0]);                                            \
            float e1 = fexp2(s0_[1]);                                            \
            float e2 = fexp2(s0_[2]);                                            \
            float e3 = fexp2(s0_[3]);                                            \
            float f0 = fexp2(s1_[0]);                                            \
            float f1 = fexp2(s1_[1]);                                            \
            float f2 = fexp2(s1_[2]);                                            \
            float f3 = fexp2(s1_[3]);                                            \
            uint4v pk_ = { pack2(e0, e1), pack2(e2, e3),                         \
                           pack2(f0, f1), pack2(f2, f3) };                       \
            pb[jq][ks] = __builtin_bit_cast(bf16x8, pk_);                        \
        }                                                                        \
    }                                                                            \
} while (0)

#define PVBODY() do {                                                            \
    _Pragma("unroll")                                                            \
    for (int ks = 0; ks < 2; ++ks) {                                             \
        lacc[0] = MFMA16(onesv, pb[0][ks], lacc[0]);                             \
        lacc[1] = MFMA16(onesv, pb[1][ks], lacc[1]);                             \
    }                                                                            \
    _Pragma("unroll")                                                            \
    for (int it = 0; it < 4; ++it) {                                             \
        const int vrow_ = (it*16 + l16) * 128;                                   \
        _Pragma("unroll")                                                        \
        for (int ks = 0; ks < 2; ++ks) {                                         \
            bf16x8 vf_ = *(const bf16x8*)&Vb[vrow_ +                             \
                (((kg*8 + ks*4 + quad) ^ l16) << 3)];                            \
            o_acc[0][it] = MFMA16(vf_, pb[0][ks], o_acc[0][it]);                 \
            o_acc[1][it] = MFMA16(vf_, pb[1][ks], o_acc[1][it]);                 \
        }                                                                        \
    }                                                                            \
} while (0)

#define WAITV_BAR() do {                                                         \
    asm volatile("s_waitcnt vmcnt(4)" ::: "memory");                             \
    __builtin_amdgcn_sched_barrier(0);                                           \
    __builtin_amdgcn_s_barrier();                                                \
} while (0)

#define WAITK_BAR() do {                                                         \
    asm volatile("s_waitcnt vmcnt(0)" ::: "memory");                             \
    __builtin_amdgcn_sched_barrier(0);                                           \
    __builtin_amdgcn_s_barrier();                                                \
} while (0)

__global__ __launch_bounds__(256, 3) void attn_kernel(
    const short* __restrict__ qb, const short* __restrict__ kb,
    const short* __restrict__ vt, const short* __restrict__ maskb,
    short* __restrict__ ao)
{
    __shared__ __align__(16) short Kb[2][8192];   // K tiles [128][64], dbuf
    __shared__ __align__(16) short Vb[8192];      // V tile  [64][128], single
    __shared__ __align__(16) short Msk[2048];     // bf16 log2-bias, this b

    const int t = threadIdx.x;
    const int lane = t & 63, wid = t >> 6;
    const int quad = lane >> 4, l16 = lane & 15;
    const int qg = wid >> 1, kg = wid & 1;        // 2x2 hybrid split
    // XCD swizzle: XCD = id%8 owns bh in {xcd, xcd+8, xcd+16}
    const int id = blockIdx.x;
    const int idx = id >> 3;
    const int bh = (id & 7) + ((idx % 3) << 3);
    const int q0 = (idx / 3) << 6;
    const int b = bh / NH, h = bh - b * NH;
    const size_t hoff = (size_t)bh * NSEQ * HD;
    const short* qp = qb + hoff;     // [N][64]  (q pre-scaled by 0.125*log2e)
    const short* kp = kb + hoff;     // [N][64]
    const short* vp = vt + hoff;     // [64][N]  (keys permuted within 64)
    const int qrow4 = quad * 4;

    int rK[4], cK[4], dV[4], cV[4];
    #pragma unroll
    for (int j = 0; j < 4; ++j) {
        int o = wid * 4096 + j * 1024 + lane * 16;
        rK[j] = o >> 7;
        cK[j] = ((o >> 4) & 7) ^ (rK[j] & 7);
        dV[j] = o >> 8;
        cV[j] = ((o >> 4) & 15) ^ (dV[j] & 15);
    }
    const int r7 = l16 & 7;
    const int kc0 = ((quad     ^ r7) << 3);
    const int kc1 = (((quad+4) ^ r7) << 3);

    // Wave's 32 q rows: q0 + qg*32 + jq*16 + l16
    bf16x8 qf[2][2];
    {
        const short* qr = qp + (size_t)(q0 + qg*32 + l16) * HD + quad*8;
        qf[0][0] = *(const bf16x8*)qr;
        qf[0][1] = *(const bf16x8*)(qr + 32);
        qf[1][0] = *(const bf16x8*)(qr + 16*HD);
        qf[1][1] = *(const bf16x8*)(qr + 16*HD + 32);
    }

    const short one_ = (short)0x3F80;             // bf16 1.0
    const bf16x8 onesv = { one_, one_, one_, one_, one_, one_, one_, one_ };

    f32x4 o_acc[2][4] = {};
    f32x4 lacc[2] = {};
    bf16x8 pb[2][2];

    // Prologue: K tile 0 + mask row; __syncthreads drains vmcnt(0).
    STAGE_K(0, Kb[0]);
    gll16(maskb + b * NSEQ + t * 8, Msk + wid * 512);
    __syncthreads();

    for (int kt = 0; kt < NSEQ; kt += 256) {
        STAGE_V(kt);
        __builtin_amdgcn_sched_barrier(0);
        STAGE_K(kt + 128, Kb[1]);
        __builtin_amdgcn_sched_barrier(0);
        QKBODY(kt, Kb[0]);
        WAITV_BAR();              // A: V(kt) visible; K(kt+128) floats
        __builtin_amdgcn_s_setprio(1);
        PVBODY();
        __builtin_amdgcn_s_setprio(0);
        WAITK_BAR();              // B: K(kt+128) visible; Vb free

        STAGE_V(kt + 128);
        __builtin_amdgcn_sched_barrier(0);
        STAGE_K((kt + 256) & (NSEQ - 1), Kb[0]);
        __builtin_amdgcn_sched_barrier(0);
        QKBODY(kt + 128, Kb[1]);
        WAITV_BAR();              // A'
        __builtin_amdgcn_s_setprio(1);
        PVBODY();
        __builtin_amdgcn_s_setprio(0);
        WAITK_BAR();              // B'
    }

    // Epilogue: combine kg=0/kg=1 partials (disjoint key halves) via LDS.
    // Barrier B' carried vmcnt(0) -> wraparound staging landed; Kb is free.
    f32x4* red = (f32x4*)Kb;
    const int rbase = (qg*64 + lane) * 9;
    if (kg == 1) {
        #pragma unroll
        for (int jq = 0; jq < 2; ++jq)
            #pragma unroll
            for (int it = 0; it < 4; ++it)
                red[rbase + jq*4 + it] = o_acc[jq][it];
        f32x4 lv = { lacc[0][0], lacc[1][0], 0.f, 0.f };
        red[rbase + 8] = lv;
    }
    __syncthreads();
    if (kg == 0) {
        f32x4 lv = red[rbase + 8];
        const float inv0 = 1.0f / (lacc[0][0] + lv[0]);
        const float inv1 = 1.0f / (lacc[1][0] + lv[1]);
        #pragma unroll
        for (int jq = 0; jq < 2; ++jq) {
            const float inv = jq ? inv1 : inv0;
            const int tok = b * NSEQ + q0 + qg*32 + jq*16 + l16;
            short* dst = ao + (size_t)tok * CDIM + h * HD + qrow4;
            #pragma unroll
            for (int it = 0; it < 4; ++it) {
                f32x4 o_ = o_acc[jq][it];
                f32x4 r_ = red[rbase + jq*4 + it];
                short4v o = { f2b((o_[0] + r_[0]) * inv),
                              f2b((o_[1] + r_[1]) * inv),
                              f2b((o_[2] + r_[2]) * inv),
                              f2b((o_[3] + r_[3]) * inv) };
                *(short4v*)(dst + it*16) = o;
            }
        }
    }
}

// ---------------------------------------------------------------------------
// GEMM2: XCD-swizzled 1-D grid (192 = 8 x 24; m fastest within chunk).
// ---------------------------------------------------------------------------
__global__ __launch_bounds__(256) void gemm_proj(
    const short* __restrict__ A /*wpt[768][768]*/,
    const short* __restrict__ B /*ao [4096][768]*/,
    const float* __restrict__ bias, float* __restrict__ out)
{
    __shared__ short As[2 * 4096];
    __shared__ short Bs[2 * 4096];
    const int t = threadIdx.x;
    const int lane = t & 63, wid = t >> 6;
    const int quad = lane >> 4, l16 = lane & 15;
    const int wA = wid >> 1, wB = wid & 1;
    // XCD swizzle: 192 = 8 XCDs x 24.
    const int id = blockIdx.x;
    const int lin = (id & 7) * 24 + (id >> 3);
    const int n0 = (lin >> 5) * 128;      // 0..5
    const int m0 = (lin & 31) * 128;      // 0..31

    const int srow = wid * 16 + (lane >> 2), schunk = (lane & 3) * 8;
    const short* ag0 = A + (size_t)(n0 + srow) * CDIM + schunk;
    const short* ag1 = ag0 + (size_t)64 * CDIM;
    const short* bg0 = B + (size_t)(m0 + srow) * CDIM + schunk;
    const short* bg1 = bg0 + (size_t)64 * CDIM;

    f32x4 acc[4][4] = {};
    GSTAGE(0, 0);
    __syncthreads();
    int buf = 0;
    for (int k0 = 0; k0 < CDIM; k0 += 32) {
        if (k0 + 32 < CDIM) GSTAGE(k0 + 32, buf ^ 1);
        __builtin_amdgcn_sched_barrier(0);
        const short* As_ = As + buf * 4096;
        const short* Bs_ = Bs + buf * 4096;
        bf16x8 af[4], bf[4];
        #pragma unroll
        for (int i = 0; i < 4; ++i)
            af[i] = *(const bf16x8*)&As_[(wA*64 + i*16 + l16) * 32 + quad*8];
        #pragma unroll
        for (int j = 0; j < 4; ++j)
            bf[j] = *(const bf16x8*)&Bs_[(wB*64 + j*16 + l16) * 32 + quad*8];
        #pragma unroll
        for (int i = 0; i < 4; ++i)
            #pragma unroll
            for (int j = 0; j < 4; ++j)
                acc[i][j] = MFMA16(af[i], bf[j], acc[i][j]);
        __syncthreads();          // stage(next) had the whole MFMA phase
        buf ^= 1;
    }

    #pragma unroll
    for (int i = 0; i < 4; ++i) {
        int col0 = n0 + wA*64 + i*16 + quad*4;
        float4 bias4 = *(const float4*)&bias[col0];
        #pragma unroll
        for (int j = 0; j < 4; ++j) {
            int tok = m0 + wB*64 + j*16 + l16;
            float4 o = { acc[i][j][0] + bias4.x, acc[i][j][1] + bias4.y,
                         acc[i][j][2] + bias4.z, acc[i][j][3] + bias4.w };
            *(float4*)(out + (size_t)tok * CDIM + col0) = o;
        }
    }
}

extern "C" void kernel_launch(void* const* d_in, const int* in_sizes, int n_in,
                              void* d_out, int out_size, void* d_ws, size_t ws_size,
                              hipStream_t stream)
{
    const float* x      = (const float*)d_in[0];
    const int*   mask   = (const int*)d_in[1];
    const float* w_qkv  = (const float*)d_in[2];
    const float* w_proj = (const float*)d_in[3];
    const float* b_proj = (const float*)d_in[4];
    float* out = (float*)d_out;

    const size_t SZ = (size_t)NTOK * CDIM;       // 3,145,728
    short* xb  = (short*)d_ws;                   // [4096][768]
    short* wqt = xb  + SZ;                       // [2304][768]
    short* wpt = wqt + (size_t)QKV_COLS * CDIM;  // [768][768]
    short* qb  = wpt + (size_t)CDIM * CDIM;      // [BH][N][64]  (pre-scaled q)
    short* kb  = qb  + SZ;                       // [BH][N][64]
    short* vt  = kb  + SZ;                       // [BH][64][N]  (key-permuted)
    short* ao  = vt  + SZ;                       // [4096][768]
    short* maskb = ao + SZ;                      // [B][N] bf16 log2-bias

    dim3 blk(256);
    prep_kernel<<<dim3(5378), blk, 0, stream>>>(x, w_qkv, w_proj, mask,
                                                xb, wqt, wpt, maskb);
    gemm_qkv<<<dim3(576), blk, 0, stream>>>(wqt, xb, qb, kb, vt);
    attn_kernel<<<dim3(NBLK), blk, 0, stream>>>(qb, kb, vt, maskb, ao);
    gemm_proj<<<dim3(192), blk, 0, stream>>>(wpt, ao, b_proj, out);
}